// Round 7
// baseline (673.198 us; speedup 1.0000x reference)
//
#include <hip/hip_runtime.h>
#include <hip/hip_bf16.h>

#define LRELU(x) ((x) >= 0.f ? (x) : 0.01f * (x))

typedef __attribute__((ext_vector_type(8))) short short8v;
typedef __attribute__((ext_vector_type(4))) float f32x4;

__device__ inline unsigned fenc(float x) {
    unsigned u = __float_as_uint(x);
    return (u & 0x80000000u) ? ~u : (u | 0x80000000u);
}
__device__ inline float fdec(unsigned e) {
    return __uint_as_float((e & 0x80000000u) ? (e ^ 0x80000000u) : ~e);
}

__device__ inline float wred(float v) {
#pragma unroll
    for (int o = 32; o > 0; o >>= 1) v += __shfl_xor(v, o, 64);
    return v;
}
__device__ inline float wredmax(float v) {
#pragma unroll
    for (int o = 32; o > 0; o >>= 1) v = fmaxf(v, __shfl_xor(v, o, 64));
    return v;
}

__device__ inline unsigned short f2bu(float x) {
    __hip_bfloat16 b = __float2bfloat16(x);
    return *reinterpret_cast<unsigned short*>(&b);
}
__device__ inline float bu2f(unsigned short u) {
    return __uint_as_float((unsigned)u << 16);
}

__device__ inline f32x4 mfma16(short8v a, short8v b, f32x4 c) {
    return __builtin_amdgcn_mfma_f32_16x16x32_bf16(a, b, c, 0, 0, 0);
}

// ---- convert W matrices to transposed hi/lo bf16: Wt[n][k] = W[k][n] ----
__global__ __launch_bounds__(256) void k_convW(
    const float* __restrict__ wh, const float* __restrict__ wt,
    const float* __restrict__ hww, unsigned short* __restrict__ wtb_hi,
    unsigned short* __restrict__ wtb_lo, unsigned short* __restrict__ hwt_hi,
    unsigned short* __restrict__ hwt_lo) {
    int id = blockIdx.x * 256 + threadIdx.x;
    if (id < 256 * 256) {
        int n = id >> 8, k = id & 255;
        float v = (n < 128) ? wh[(size_t)k * 128 + n] : wt[(size_t)k * 128 + (n - 128)];
        unsigned short h = f2bu(v);
        float r = v - bu2f(h);
        wtb_hi[(size_t)n * 256 + k] = h;
        wtb_lo[(size_t)n * 256 + k] = f2bu(r);
    } else {
        int id2 = id - 256 * 256;
        if (id2 < 128 * 128) {
            int n = id2 >> 7, k = id2 & 127;
            float v = hww[(size_t)k * 128 + n];
            unsigned short h = f2bu(v);
            float r = v - bu2f(h);
            hwt_hi[(size_t)n * 128 + k] = h;
            hwt_lo[(size_t)n * 128 + k] = f2bu(r);
        }
    }
}

// ---- convert A (x_e) to split hi/lo bf16, row-major [NE][KD] ----
__global__ __launch_bounds__(256) void k_convA(const float* __restrict__ x,
                                               unsigned short* __restrict__ hi,
                                               unsigned short* __restrict__ lo,
                                               long n8) {
    long i = (long)blockIdx.x * 256 + threadIdx.x;
    if (i >= n8) return;
    const float4* xp = (const float4*)(x + i * 8);
    float4 a = xp[0], b = xp[1];
    float xs[8] = {a.x, a.y, a.z, a.w, b.x, b.y, b.z, b.w};
    short8v vh, vl;
#pragma unroll
    for (int j = 0; j < 8; j++) {
        unsigned short h = f2bu(xs[j]);
        vh[j] = (short)h;
        vl[j] = (short)f2bu(xs[j] - bu2f(h));
    }
    *(short8v*)(hi + i * 8) = vh;
    *(short8v*)(lo + i * 8) = vl;
}

// ---- bf16 MFMA GEMM, pre-converted A, reg double-buffered A+B ----
// Block = 64 rows x 128 cols, 4 waves = 2 rowgroups x 2 col-halves(64).
// EPI 0 (proj, KD=256, split A, 3 mfma/cell): blockIdx.x = mblk*2 + half;
//   half 0 -> o0=xrh (+ oh bf16-hi mirror), half 1 -> o1=xrt. relu + fused dots.
// EPI 1 (highway, KD=128, A=bf16-hi only, 2 mfma/cell):
//   gate = sigmoid(C+bias); o0 = g*xeh + (1-g)*Af.
template <int KD, int EPI>
__global__ __launch_bounds__(256) void k_gemm(
    const unsigned short* __restrict__ Ah, const unsigned short* __restrict__ Al,
    const float* __restrict__ Af, const unsigned short* __restrict__ Bh,
    const unsigned short* __restrict__ Bl, float* __restrict__ o0,
    float* __restrict__ o1, unsigned short* __restrict__ oh,
    const float* __restrict__ bias, const float* __restrict__ xeh, int M,
    const float* __restrict__ av1, const float* __restrict__ av2,
    const float* __restrict__ av3, const float* __restrict__ av4,
    const float* __restrict__ bv1, const float* __restrict__ bv2,
    const float* __restrict__ bv3, float* __restrict__ d1o,
    float* __restrict__ d2o, float* __restrict__ d3o, float* __restrict__ d4o,
    float* __restrict__ e1o, float* __restrict__ e2o, float* __restrict__ e3o,
    float* __restrict__ nrmo) {
    __shared__ float pd[2][64][4];
    int bx = blockIdx.x;
    int half = (EPI == 0) ? (bx & 1) : 0;
    int mblk = (EPI == 0) ? (bx >> 1) : bx;
    int row0 = mblk * 64;
    if (row0 + 64 > M) row0 = M - 64;
    int tid = threadIdx.x;
    int w = tid >> 6, l = tid & 63;
    int rg = w >> 1, ch = w & 1;
    int lr = l & 15, hi4 = l >> 4;
    int lk = hi4 * 8;

    f32x4 acc[2][4];
#pragma unroll
    for (int i = 0; i < 2; i++)
#pragma unroll
        for (int j = 0; j < 4; j++) acc[i][j] = (f32x4){0.f, 0.f, 0.f, 0.f};

    const unsigned short* ap_h = Ah + (size_t)(row0 + rg * 32 + lr) * KD + lk;
    const unsigned short* ap_l = (EPI == 0) ? Al + (size_t)(row0 + rg * 32 + lr) * KD + lk : nullptr;
    const unsigned short* bp_h = Bh + (size_t)(half * 128 + ch * 64 + lr) * KD + lk;
    const unsigned short* bp_l = Bl + (size_t)(half * 128 + ch * 64 + lr) * KD + lk;

    auto loadB = [&](short8v* dh, short8v* dl, int koff) {
#pragma unroll
        for (int cf = 0; cf < 4; cf++) {
            dh[cf] = *(const short8v*)(bp_h + (size_t)(cf * 16) * KD + koff);
            dl[cf] = *(const short8v*)(bp_l + (size_t)(cf * 16) * KD + koff);
        }
    };
    auto loadA = [&](short8v* dh, short8v* dl, int koff) {
#pragma unroll
        for (int rf = 0; rf < 2; rf++) {
            dh[rf] = *(const short8v*)(ap_h + (size_t)(rf * 16) * KD + koff);
            if constexpr (EPI == 0)
                dl[rf] = *(const short8v*)(ap_l + (size_t)(rf * 16) * KD + koff);
        }
    };
    auto step = [&](short8v* ah, short8v* al, short8v* bh, short8v* bl) {
#pragma unroll
        for (int cf = 0; cf < 4; cf++)
#pragma unroll
            for (int rf = 0; rf < 2; rf++) {
                acc[rf][cf] = mfma16(ah[rf], bh[cf], acc[rf][cf]);
                if constexpr (EPI == 0)
                    acc[rf][cf] = mfma16(al[rf], bh[cf], acc[rf][cf]);
                acc[rf][cf] = mfma16(ah[rf], bl[cf], acc[rf][cf]);
            }
    };

    short8v B0h[4], B0l[4], B1h[4], B1l[4];
    short8v A0h[2], A0l[2], A1h[2], A1l[2];
    loadB(B0h, B0l, 0);
    loadA(A0h, A0l, 0);
#pragma unroll
    for (int k0 = 0; k0 < KD; k0 += 64) {
        loadB(B1h, B1l, k0 + 32);
        loadA(A1h, A1l, k0 + 32);
        step(A0h, A0l, B0h, B0l);
        if (k0 + 64 < KD) {
            loadB(B0h, B0l, k0 + 64);
            loadA(A0h, A0l, k0 + 64);
        }
        step(A1h, A1l, B1h, B1l);
    }

    if (EPI == 0) {
        float* O = half ? o1 : o0;
        const float* v1 = half ? bv1 : av1;
        const float* v2 = half ? bv2 : av2;
        const float* v3 = half ? bv3 : av3;
#pragma unroll
        for (int rf = 0; rf < 2; rf++)
#pragma unroll
            for (int r = 0; r < 4; r++) {
                int rl = rg * 32 + rf * 16 + hi4 * 4 + r;
                int row = row0 + rl;
                float d0 = 0.f, d1 = 0.f, d2 = 0.f, d3 = 0.f;
#pragma unroll
                for (int cf = 0; cf < 4; cf++) {
                    float v = fmaxf(acc[rf][cf][r], 0.f);
                    int col = ch * 64 + cf * 16 + lr;
                    O[(size_t)row * 128 + col] = v;
                    if (half == 0) oh[(size_t)row * 128 + col] = f2bu(v);
                    d0 = fmaf(v, v1[col], d0);
                    d1 = fmaf(v, v2[col], d1);
                    d2 = fmaf(v, v3[col], d2);
                    d3 = fmaf(v, half ? v : av4[col], d3);
                }
#pragma unroll
                for (int o = 1; o <= 8; o <<= 1) {
                    d0 += __shfl_xor(d0, o, 64);
                    d1 += __shfl_xor(d1, o, 64);
                    d2 += __shfl_xor(d2, o, 64);
                    d3 += __shfl_xor(d3, o, 64);
                }
                if (lr == 0) {
                    pd[ch][rl][0] = d0; pd[ch][rl][1] = d1;
                    pd[ch][rl][2] = d2; pd[ch][rl][3] = d3;
                }
            }
        __syncthreads();
        if (ch == 0) {
#pragma unroll
            for (int rf = 0; rf < 2; rf++)
#pragma unroll
                for (int r = 0; r < 4; r++) {
                    int rl = rg * 32 + rf * 16 + hi4 * 4 + r;
                    int row = row0 + rl;
                    if (lr == 0) {
                        float s0 = pd[0][rl][0] + pd[1][rl][0];
                        float s1 = pd[0][rl][1] + pd[1][rl][1];
                        float s2 = pd[0][rl][2] + pd[1][rl][2];
                        float s3 = pd[0][rl][3] + pd[1][rl][3];
                        if (half == 0) {
                            d1o[row] = s0; d2o[row] = s1; d3o[row] = s2; d4o[row] = s3;
                        } else {
                            e1o[row] = s0; e2o[row] = s1; e3o[row] = s2;
                            nrmo[row] = sqrtf(s3);
                        }
                    }
                }
        }
    } else {
#pragma unroll
        for (int rf = 0; rf < 2; rf++)
#pragma unroll
            for (int cf = 0; cf < 4; cf++)
#pragma unroll
                for (int r = 0; r < 4; r++) {
                    int row = row0 + rg * 32 + rf * 16 + hi4 * 4 + r;
                    int col = ch * 64 + cf * 16 + lr;
                    float a = acc[rf][cf][r] + bias[col];
                    float g = 1.f / (1.f + expf(-a));
                    size_t o = (size_t)row * 128 + col;
                    o0[o] = g * xeh[o] + (1.f - g) * Af[o];
                }
    }
}

// ---- relation dots ----
__global__ __launch_bounds__(256) void k_rel(const float* __restrict__ remb,
                                             const float* __restrict__ ar1,
                                             const float* __restrict__ ar2,
                                             float* __restrict__ er1,
                                             float* __restrict__ er2, int NR) {
    int lane = threadIdx.x & 63;
    int r = blockIdx.x * 4 + (threadIdx.x >> 6);
    if (r >= NR) return;
    float v0 = remb[(size_t)r * 128 + lane];
    float v1 = remb[(size_t)r * 128 + 64 + lane];
    float p1 = v0 * ar1[lane] + v1 * ar1[64 + lane];
    float p2 = v0 * ar2[lane] + v1 * ar2[64 + lane];
    p1 = wred(p1);
    p2 = wred(p2);
    if (lane == 0) { er1[r] = p1; er2[r] = p2; }
}

// ---- level 1 softmax over triple_num segments ----
__global__ __launch_bounds__(256) void k_edge1(
    const int* __restrict__ hidx, const int* __restrict__ tidx,
    const int* __restrict__ rel, const int* __restrict__ tnum,
    const float* __restrict__ eh1, const float* __restrict__ et1,
    const float* __restrict__ er1, float* __restrict__ zbuf,
    unsigned* __restrict__ m1, int E) {
    int i = blockIdx.x * 256 + threadIdx.x;
    if (i >= E) return;
    float e1 = 0.5f * (eh1[hidx[i]] + et1[tidx[i]]) + er1[rel[i]];
    float z = LRELU(e1);
    zbuf[i] = z;
    atomicMax(&m1[tnum[i]], fenc(z));
}

__global__ __launch_bounds__(256) void k_edge2(const int* __restrict__ tnum,
                                               float* __restrict__ zbuf,
                                               const unsigned* __restrict__ m1,
                                               float* __restrict__ s1, int E) {
    int i = blockIdx.x * 256 + threadIdx.x;
    if (i >= E) return;
    int tn = tnum[i];
    float ex = expf(zbuf[i] - fdec(m1[tn]));
    zbuf[i] = ex;
    atomicAdd(&s1[tn], ex);
}

// ---- alpha -> per-edge scale s, level-2 logit z2 (no atomics) ----
__global__ __launch_bounds__(256) void k_edge3(
    const int* __restrict__ hidx, const int* __restrict__ tidx,
    const int* __restrict__ rel, const int* __restrict__ tnum,
    const float* __restrict__ zbuf, const float* __restrict__ s1,
    const float* __restrict__ nrm, const float* __restrict__ eh2,
    const float* __restrict__ eh3, const float* __restrict__ et2,
    const float* __restrict__ et3, const float* __restrict__ er2,
    float* __restrict__ sbuf, float* __restrict__ e2buf, int E) {
    int i = blockIdx.x * 256 + threadIdx.x;
    if (i >= E) return;
    float alpha = zbuf[i] / (s1[tnum[i]] + 1e-16f);
    int t = tidx[i];
    float s = alpha / fmaxf(alpha * nrm[t], 1e-12f);
    sbuf[i] = s;
    int h = hidx[i];
    float z2 = s * et2[t] + eh2[h] + 0.5f * (er2[rel[i]] + 0.5f * (eh3[h] + s * et3[t]));
    e2buf[i] = LRELU(z2);
}

// ---- counting sort by class_index ----
__global__ __launch_bounds__(256) void k_hist(const int* __restrict__ cidx,
                                              int* __restrict__ cnt, int E) {
    int i = blockIdx.x * 256 + threadIdx.x;
    if (i >= E) return;
    atomicAdd(&cnt[cidx[i]], 1);
}

__global__ __launch_bounds__(1024) void k_scan(const int* __restrict__ cnt,
                                               int* __restrict__ off,
                                               int* __restrict__ cur, int NC) {
    __shared__ int wt[16];
    __shared__ int sbase;
    int tid = threadIdx.x, w = tid >> 6, lane = tid & 63;
    if (tid == 0) sbase = 0;
    __syncthreads();
    for (int c0 = 0; c0 < NC; c0 += 1024) {
        int c = c0 + tid;
        int v = (c < NC) ? cnt[c] : 0;
        int x = v;
#pragma unroll
        for (int o = 1; o < 64; o <<= 1) {
            int t = __shfl_up(x, o, 64);
            if (lane >= o) x += t;
        }
        if (lane == 63) wt[w] = x;
        __syncthreads();
        int pre = 0, tot = 0;
#pragma unroll
        for (int i = 0; i < 16; i++) {
            int t = wt[i];
            tot += t;
            if (i < w) pre += t;
        }
        int excl = sbase + pre + x - v;
        if (c < NC) { off[c] = excl; cur[c] = excl; }
        __syncthreads();
        if (tid == 0) sbase += tot;
        __syncthreads();
    }
}

__global__ __launch_bounds__(256) void k_scatter(const int* __restrict__ cidx,
                                                 int* __restrict__ cur,
                                                 int* __restrict__ elist, int E) {
    int i = blockIdx.x * 256 + threadIdx.x;
    if (i >= E) return;
    int pos = atomicAdd(&cur[cidx[i]], 1);
    elist[pos] = i;
}

// ---- fused level-2 softmax + spmm, one wave per class, batched gathers ----
__global__ __launch_bounds__(256) void k_spmm2(
    const int* __restrict__ elist, const int* __restrict__ off,
    const int* __restrict__ cnt, const int* __restrict__ tidx,
    const float* __restrict__ e2buf, const float* __restrict__ sbuf,
    const float* __restrict__ xrt, float* __restrict__ xclass, int NC) {
    int lane = threadIdx.x & 63;
    int c = blockIdx.x * 4 + (threadIdx.x >> 6);
    if (c >= NC) return;
    int n = cnt[c];
    if (n == 0) {
        xclass[(size_t)c * 128 + lane] = 0.f;
        xclass[(size_t)c * 128 + 64 + lane] = 0.f;
        return;
    }
    int base = off[c];
    float m = -3.4e38f;
    for (int j = lane; j < n; j += 64) m = fmaxf(m, e2buf[elist[base + j]]);
    m = wredmax(m);
    float s = 0.f;
    for (int j = lane; j < n; j += 64) s += expf(e2buf[elist[base + j]] - m);
    s = wred(s);
    float inv = 1.f / (s + 1e-16f);
    float a0 = 0.f, a1 = 0.f;
    for (int j0 = 0; j0 < n; j0 += 64) {
        int lim = n - j0;
        if (lim > 64) lim = 64;
        float wv = 0.f;
        int g = 0;
        if (lane < lim) {
            int e = elist[base + j0 + lane];
            wv = expf(e2buf[e] - m) * inv;
            int te = tidx[e];
            wv *= sbuf[te];
            g = tidx[te];
        }
        int jj = 0;
        for (; jj + 8 <= lim; jj += 8) {  // 16 outstanding gathers
            float w0 = __shfl(wv, jj + 0), w1 = __shfl(wv, jj + 1);
            float w2 = __shfl(wv, jj + 2), w3 = __shfl(wv, jj + 3);
            float w4 = __shfl(wv, jj + 4), w5 = __shfl(wv, jj + 5);
            float w6 = __shfl(wv, jj + 6), w7 = __shfl(wv, jj + 7);
            const float* p0 = xrt + (size_t)__shfl(g, jj + 0) * 128 + lane;
            const float* p1 = xrt + (size_t)__shfl(g, jj + 1) * 128 + lane;
            const float* p2 = xrt + (size_t)__shfl(g, jj + 2) * 128 + lane;
            const float* p3 = xrt + (size_t)__shfl(g, jj + 3) * 128 + lane;
            const float* p4 = xrt + (size_t)__shfl(g, jj + 4) * 128 + lane;
            const float* p5 = xrt + (size_t)__shfl(g, jj + 5) * 128 + lane;
            const float* p6 = xrt + (size_t)__shfl(g, jj + 6) * 128 + lane;
            const float* p7 = xrt + (size_t)__shfl(g, jj + 7) * 128 + lane;
            float x0 = p0[0], y0 = p0[64], x1 = p1[0], y1 = p1[64];
            float x2 = p2[0], y2 = p2[64], x3 = p3[0], y3 = p3[64];
            float x4 = p4[0], y4 = p4[64], x5 = p5[0], y5 = p5[64];
            float x6 = p6[0], y6 = p6[64], x7 = p7[0], y7 = p7[64];
            a0 = fmaf(w0, x0, a0); a1 = fmaf(w0, y0, a1);
            a0 = fmaf(w1, x1, a0); a1 = fmaf(w1, y1, a1);
            a0 = fmaf(w2, x2, a0); a1 = fmaf(w2, y2, a1);
            a0 = fmaf(w3, x3, a0); a1 = fmaf(w3, y3, a1);
            a0 = fmaf(w4, x4, a0); a1 = fmaf(w4, y4, a1);
            a0 = fmaf(w5, x5, a0); a1 = fmaf(w5, y5, a1);
            a0 = fmaf(w6, x6, a0); a1 = fmaf(w6, y6, a1);
            a0 = fmaf(w7, x7, a0); a1 = fmaf(w7, y7, a1);
        }
        for (; jj < lim; jj++) {
            float wj = __shfl(wv, jj);
            int gj = __shfl(g, jj);
            a0 = fmaf(wj, xrt[(size_t)gj * 128 + lane], a0);
            a1 = fmaf(wj, xrt[(size_t)gj * 128 + 64 + lane], a1);
        }
    }
    xclass[(size_t)c * 128 + lane] = a0;
    xclass[(size_t)c * 128 + 64 + lane] = a1;
}

// ---- level 3: class -> head entity ----
__global__ __launch_bounds__(256) void k_class1(
    const float* __restrict__ xclass, const float* __restrict__ ac,
    const float* __restrict__ eh4, const int* __restrict__ hclass,
    float* __restrict__ zc, unsigned* __restrict__ m3, int NC) {
    int lane = threadIdx.x & 63;
    int c = blockIdx.x * 4 + (threadIdx.x >> 6);
    if (c >= NC) return;
    float v0 = xclass[(size_t)c * 128 + lane], v1 = xclass[(size_t)c * 128 + 64 + lane];
    float p = wred(v0 * ac[lane] + v1 * ac[64 + lane]);
    if (lane == 0) {
        int hc = hclass[c];
        float z = LRELU(p + eh4[hc]);
        zc[c] = z;
        atomicMax(&m3[hc], fenc(z));
    }
}

__global__ __launch_bounds__(256) void k_class2(const int* __restrict__ hclass,
                                                float* __restrict__ zc,
                                                const unsigned* __restrict__ m3,
                                                float* __restrict__ s3, int NC) {
    int c = blockIdx.x * 256 + threadIdx.x;
    if (c >= NC) return;
    int hc = hclass[c];
    float ex = expf(zc[c] - fdec(m3[hc]));
    zc[c] = ex;
    atomicAdd(&s3[hc], ex);
}

__global__ __launch_bounds__(256) void k_class3(
    const int* __restrict__ hclass, const float* __restrict__ zc,
    const float* __restrict__ s3, const float* __restrict__ xclass,
    float* __restrict__ xeh, int NC) {
    int lane = threadIdx.x & 63;
    int c = blockIdx.x * 4 + (threadIdx.x >> 6);
    if (c >= NC) return;
    int hc = hclass[c];
    float gama = zc[c] / (s3[hc] + 1e-16f);
    float v0 = xclass[(size_t)c * 128 + lane], v1 = xclass[(size_t)c * 128 + 64 + lane];
    atomicAdd(&xeh[(size_t)hc * 128 + lane], gama * v0);
    atomicAdd(&xeh[(size_t)hc * 128 + 64 + lane], gama * v1);
}

extern "C" void kernel_launch(void* const* d_in, const int* in_sizes, int n_in,
                              void* d_out, int out_size, void* d_ws, size_t ws_size,
                              hipStream_t stream) {
    (void)n_in; (void)out_size; (void)ws_size;
    const float* xe   = (const float*)d_in[0];
    const int*   eidx = (const int*)d_in[1];
    const int*   rel  = (const int*)d_in[2];
    const int*   tnum = (const int*)d_in[3];
    const float* remb = (const float*)d_in[4];
    const int*   cidx = (const int*)d_in[5];
    const int*   hcls = (const int*)d_in[6];
    const float* ah1  = (const float*)d_in[7];
    const float* ah2  = (const float*)d_in[8];
    const float* ah3  = (const float*)d_in[9];
    const float* ah4  = (const float*)d_in[10];
    const float* at1  = (const float*)d_in[11];
    const float* at2  = (const float*)d_in[12];
    const float* at3  = (const float*)d_in[13];
    const float* ar1  = (const float*)d_in[14];
    const float* ar2  = (const float*)d_in[15];
    const float* ac   = (const float*)d_in[16];
    const float* wh   = (const float*)d_in[17];
    const float* wt   = (const float*)d_in[18];
    const float* hww  = (const float*)d_in[19];
    const float* hwb  = (const float*)d_in[20];
    float* out = (float*)d_out;

    const int NE = in_sizes[0] / 256;
    const int E  = in_sizes[2];
    const int NR = in_sizes[4] / 128;
    const int NC = in_sizes[6];
    const int* hidx = eidx;
    const int* tidx = eidx + E;

    char* base = (char*)d_ws;
    size_t off0 = 0;
    auto alloc = [&](size_t bytes) -> char* {
        char* r = base + off0;
        off0 = (off0 + bytes + 255) & ~(size_t)255;
        return r;
    };
    float* xrh  = (float*)alloc((size_t)NE * 128 * 4);
    float* xrt  = (float*)alloc((size_t)NE * 128 * 4);
    float* eh1  = (float*)alloc((size_t)NE * 4);
    float* eh2  = (float*)alloc((size_t)NE * 4);
    float* eh3  = (float*)alloc((size_t)NE * 4);
    float* eh4  = (float*)alloc((size_t)NE * 4);
    float* et1b = (float*)alloc((size_t)NE * 4);
    float* et2b = (float*)alloc((size_t)NE * 4);
    float* et3b = (float*)alloc((size_t)NE * 4);
    float* nrmb = (float*)alloc((size_t)NE * 4);
    float* er1b = (float*)alloc((size_t)NR * 4);
    float* er2b = (float*)alloc((size_t)NR * 4);
    float* zbuf  = (float*)alloc((size_t)E * 4);
    float* e2buf = (float*)alloc((size_t)E * 4);
    float* sbuf  = (float*)alloc((size_t)E * 4);
    float* zc    = (float*)alloc((size_t)NC * 4);
    unsigned short* wtb_hi = (unsigned short*)alloc((size_t)256 * 256 * 2);
    unsigned short* wtb_lo = (unsigned short*)alloc((size_t)256 * 256 * 2);
    unsigned short* hwt_hi = (unsigned short*)alloc((size_t)128 * 128 * 2);
    unsigned short* hwt_lo = (unsigned short*)alloc((size_t)128 * 128 * 2);
    unsigned short* a_hi   = (unsigned short*)alloc((size_t)NE * 256 * 2);
    unsigned short* a_lo   = (unsigned short*)alloc((size_t)NE * 256 * 2);
    unsigned short* xrh_hi = (unsigned short*)alloc((size_t)NE * 128 * 2);
    int* offb  = (int*)alloc((size_t)NC * 4);
    int* curb  = (int*)alloc((size_t)NC * 4);
    int* elist = (int*)alloc((size_t)E * 4);
    float* xclass = (float*)alloc((size_t)NC * 128 * 4);
    size_t zoff = off0;  // everything below is zero-initialized per launch
    unsigned* m1 = (unsigned*)alloc((size_t)NE * 4);
    float* s1    = (float*)alloc((size_t)NE * 4);
    unsigned* m3 = (unsigned*)alloc((size_t)NE * 4);
    float* s3    = (float*)alloc((size_t)NE * 4);
    int* cntb    = (int*)alloc((size_t)NC * 4);
    float* xeh   = (float*)alloc((size_t)NE * 128 * 4);
    size_t zbytes = off0 - zoff;

    hipMemsetAsync(base + zoff, 0, zbytes, stream);

    k_convW<<<(256 * 256 + 128 * 128 + 255) / 256, 256, 0, stream>>>(
        wh, wt, hww, wtb_hi, wtb_lo, hwt_hi, hwt_lo);
    long n8 = (long)NE * 256 / 8;
    k_convA<<<(int)((n8 + 255) / 256), 256, 0, stream>>>(xe, a_hi, a_lo, n8);
    k_rel<<<(NR + 3) / 4, 256, 0, stream>>>(remb, ar1, ar2, er1b, er2b, NR);

    // projection GEMM with fused per-entity dots + norm (2 blocks per 64 rows)
    k_gemm<256, 0><<<((NE + 63) / 64) * 2, 256, 0, stream>>>(
        a_hi, a_lo, nullptr, wtb_hi, wtb_lo, xrh, xrt, xrh_hi, nullptr, nullptr, NE,
        ah1, ah2, ah3, ah4, at1, at2, at3,
        eh1, eh2, eh3, eh4, et1b, et2b, et3b, nrmb);

    // class-CSR build (independent of edge kernels)
    k_hist<<<(E + 255) / 256, 256, 0, stream>>>(cidx, cntb, E);
    k_scan<<<1, 1024, 0, stream>>>(cntb, offb, curb, NC);
    k_scatter<<<(E + 255) / 256, 256, 0, stream>>>(cidx, curb, elist, E);

    k_edge1<<<(E + 255) / 256, 256, 0, stream>>>(hidx, tidx, rel, tnum, eh1, et1b, er1b, zbuf, m1, E);
    k_edge2<<<(E + 255) / 256, 256, 0, stream>>>(tnum, zbuf, m1, s1, E);
    k_edge3<<<(E + 255) / 256, 256, 0, stream>>>(hidx, tidx, rel, tnum, zbuf, s1, nrmb,
                                                 eh2, eh3, et2b, et3b, er2b, sbuf, e2buf, E);
    k_spmm2<<<(NC + 3) / 4, 256, 0, stream>>>(elist, offb, cntb, tidx, e2buf, sbuf,
                                              xrt, xclass, NC);
    k_class1<<<(NC + 3) / 4, 256, 0, stream>>>(xclass, ac, eh4, hcls, zc, m3, NC);
    k_class2<<<(NC + 255) / 256, 256, 0, stream>>>(hcls, zc, m3, s3, NC);
    k_class3<<<(NC + 3) / 4, 256, 0, stream>>>(hcls, zc, s3, xclass, xeh, NC);

    k_gemm<128, 1><<<(NE + 63) / 64, 256, 0, stream>>>(
        xrh_hi, nullptr, xrh, hwt_hi, hwt_lo, out, nullptr, nullptr, hwb, xeh, NE,
        nullptr, nullptr, nullptr, nullptr, nullptr, nullptr, nullptr,
        nullptr, nullptr, nullptr, nullptr, nullptr, nullptr, nullptr, nullptr);
}

// Round 8
// 588.204 us; speedup vs baseline: 1.1445x; 1.1445x over previous
//
#include <hip/hip_runtime.h>
#include <hip/hip_bf16.h>

#define LRELU(x) ((x) >= 0.f ? (x) : 0.01f * (x))

typedef __attribute__((ext_vector_type(8))) short short8v;
typedef __attribute__((ext_vector_type(4))) float f32x4;

__device__ inline unsigned fenc(float x) {
    unsigned u = __float_as_uint(x);
    return (u & 0x80000000u) ? ~u : (u | 0x80000000u);
}
__device__ inline float fdec(unsigned e) {
    return __uint_as_float((e & 0x80000000u) ? (e ^ 0x80000000u) : ~e);
}

__device__ inline float wred(float v) {
#pragma unroll
    for (int o = 32; o > 0; o >>= 1) v += __shfl_xor(v, o, 64);
    return v;
}
__device__ inline float wredmax(float v) {
#pragma unroll
    for (int o = 32; o > 0; o >>= 1) v = fmaxf(v, __shfl_xor(v, o, 64));
    return v;
}

__device__ inline unsigned short f2bu(float x) {
    __hip_bfloat16 b = __float2bfloat16(x);
    return *reinterpret_cast<unsigned short*>(&b);
}
__device__ inline float bu2f(unsigned short u) {
    return __uint_as_float((unsigned)u << 16);
}

__device__ inline f32x4 mfma16(short8v a, short8v b, f32x4 c) {
    return __builtin_amdgcn_mfma_f32_16x16x32_bf16(a, b, c, 0, 0, 0);
}

// async global->LDS, 16B per lane, dest = (wave-uniform base) + lane*16
__device__ inline void gload16(const void* g, void* l) {
    __builtin_amdgcn_global_load_lds(
        (const __attribute__((address_space(1))) void*)g,
        (__attribute__((address_space(3))) void*)l, 16, 0, 0);
}

// ---- convert W matrices to transposed hi/lo bf16: Wt[n][k] = W[k][n] ----
__global__ __launch_bounds__(256) void k_convW(
    const float* __restrict__ wh, const float* __restrict__ wt,
    const float* __restrict__ hww, unsigned short* __restrict__ wtb_hi,
    unsigned short* __restrict__ wtb_lo, unsigned short* __restrict__ hwt_hi,
    unsigned short* __restrict__ hwt_lo) {
    int id = blockIdx.x * 256 + threadIdx.x;
    if (id < 256 * 256) {
        int n = id >> 8, k = id & 255;
        float v = (n < 128) ? wh[(size_t)k * 128 + n] : wt[(size_t)k * 128 + (n - 128)];
        unsigned short h = f2bu(v);
        float r = v - bu2f(h);
        wtb_hi[(size_t)n * 256 + k] = h;
        wtb_lo[(size_t)n * 256 + k] = f2bu(r);
    } else {
        int id2 = id - 256 * 256;
        if (id2 < 128 * 128) {
            int n = id2 >> 7, k = id2 & 127;
            float v = hww[(size_t)k * 128 + n];
            unsigned short h = f2bu(v);
            float r = v - bu2f(h);
            hwt_hi[(size_t)n * 128 + k] = h;
            hwt_lo[(size_t)n * 128 + k] = f2bu(r);
        }
    }
}

// ---- convert A (x_e) to split hi/lo bf16, row-major [NE][256] ----
__global__ __launch_bounds__(256) void k_convA(const float* __restrict__ x,
                                               unsigned short* __restrict__ hi,
                                               unsigned short* __restrict__ lo,
                                               long n8) {
    long i = (long)blockIdx.x * 256 + threadIdx.x;
    if (i >= n8) return;
    const float4* xp = (const float4*)(x + i * 8);
    float4 a = xp[0], b = xp[1];
    float xs[8] = {a.x, a.y, a.z, a.w, b.x, b.y, b.z, b.w};
    short8v vh, vl;
#pragma unroll
    for (int j = 0; j < 8; j++) {
        unsigned short h = f2bu(xs[j]);
        vh[j] = (short)h;
        vl[j] = (short)f2bu(xs[j] - bu2f(h));
    }
    *(short8v*)(hi + i * 8) = vh;
    *(short8v*)(lo + i * 8) = vl;
}

// ---- m97-style LDS-staged split-bf16 MFMA GEMM ----
// Block 128x128, 4 waves in 2x2 quadrants, acc[4][4], BK=32, 2 barriers/step.
// LDS tiles [128][32] bf16, staged via async global_load_lds (linear dest),
// k-slot XOR swizzle (slot ^ (row>>1)&3) applied to source + ds_read.
// EPI 0 (proj, KD=256): blockIdx = mblk*2+half; half0 -> o0=xrh (+oh bf16
//   mirror) with dots(ah1..ah4)->ehv; half1 -> o1=xrt with dots(at1..at3,norm)->etv.
// EPI 1 (highway, KD=128): A=bf16 hi only; gate=sigmoid(C+bias);
//   o0 = g*xeh + (1-g)*Af.
template <int EPI>
__device__ __forceinline__ void mm_body(
    const unsigned short* __restrict__ Ah, const unsigned short* __restrict__ Al,
    const unsigned short* __restrict__ Bh, const unsigned short* __restrict__ Bl,
    float* __restrict__ o0, float* __restrict__ o1, unsigned short* __restrict__ oh,
    const float* __restrict__ Af, const float* __restrict__ bias,
    const float* __restrict__ xeh, int M,
    const float* __restrict__ av1, const float* __restrict__ av2,
    const float* __restrict__ av3, const float* __restrict__ av4,
    const float* __restrict__ bv1, const float* __restrict__ bv2,
    const float* __restrict__ bv3,
    float4* __restrict__ ehv, float4* __restrict__ etv) {
    constexpr int KD = (EPI == 0) ? 256 : 128;
    constexpr int NSTEP = KD / 32;
    __shared__ unsigned short As_h[128 * 32];
    __shared__ unsigned short As_l[(EPI == 0) ? 128 * 32 : 64];
    __shared__ unsigned short Bs_h[128 * 32];
    __shared__ unsigned short Bs_l[128 * 32];
    __shared__ float pd[(EPI == 0) ? 2 : 1][(EPI == 0) ? 128 : 1][4];

    int bx = blockIdx.x;
    int half = (EPI == 0) ? (bx & 1) : 0;
    int mblk = (EPI == 0) ? (bx >> 1) : bx;
    int row0 = mblk * 128;
    if (row0 + 128 > M) row0 = M - 128;
    int tid = threadIdx.x, w = tid >> 6, l = tid & 63;
    int qr = w >> 1, qc = w & 1;
    int lr = l & 15, hi4 = l >> 4;
    int srow = l >> 2, sslot = l & 3;  // staging: row-in-unit, 16B slot

    f32x4 acc[4][4];
#pragma unroll
    for (int i = 0; i < 4; i++)
#pragma unroll
        for (int j = 0; j < 4; j++) acc[i][j] = (f32x4){0.f, 0.f, 0.f, 0.f};

    constexpr int NU = (EPI == 0) ? 8 : 6;  // 1KB staging units per wave

    for (int s = 0; s < NSTEP; s++) {
        int k0 = s * 32;
        __syncthreads();  // previous step's reads complete before overwrite
#pragma unroll
        for (int i = 0; i < NU; i++) {
            int u = w * NU + i;
            int arr = u >> 3, ld = u & 7;
            int row = ld * 16 + srow;
            int klog = (sslot ^ ((row >> 1) & 3)) * 8;  // swizzled source k
            const unsigned short* src;
            unsigned short* dst;
            if constexpr (EPI == 0) {
                if (arr == 0)      { src = Ah + (size_t)(row0 + row) * KD;       dst = As_h; }
                else if (arr == 1) { src = Al + (size_t)(row0 + row) * KD;       dst = As_l; }
                else if (arr == 2) { src = Bh + (size_t)(half * 128 + row) * KD; dst = Bs_h; }
                else               { src = Bl + (size_t)(half * 128 + row) * KD; dst = Bs_l; }
            } else {
                if (arr == 0)      { src = Ah + (size_t)(row0 + row) * KD; dst = As_h; }
                else if (arr == 1) { src = Bh + (size_t)row * KD;          dst = Bs_h; }
                else               { src = Bl + (size_t)row * KD;          dst = Bs_l; }
            }
            gload16(src + k0 + klog, dst + ld * 512);
        }
        __syncthreads();  // drain global_load_lds

        short8v am_h[4], am_l[4], bn_h[4], bn_l[4];
#pragma unroll
        for (int mr = 0; mr < 4; mr++) {
            int r = qr * 64 + mr * 16 + lr;
            int ko = (hi4 ^ ((r >> 1) & 3)) * 8;
            am_h[mr] = *(const short8v*)&As_h[r * 32 + ko];
            if constexpr (EPI == 0) am_l[mr] = *(const short8v*)&As_l[r * 32 + ko];
        }
#pragma unroll
        for (int nc = 0; nc < 4; nc++) {
            int n = qc * 64 + nc * 16 + lr;
            int ko = (hi4 ^ ((n >> 1) & 3)) * 8;
            bn_h[nc] = *(const short8v*)&Bs_h[n * 32 + ko];
            bn_l[nc] = *(const short8v*)&Bs_l[n * 32 + ko];
        }
#pragma unroll
        for (int mr = 0; mr < 4; mr++)
#pragma unroll
            for (int nc = 0; nc < 4; nc++) {
                acc[mr][nc] = mfma16(am_h[mr], bn_h[nc], acc[mr][nc]);
                if constexpr (EPI == 0)
                    acc[mr][nc] = mfma16(am_l[mr], bn_h[nc], acc[mr][nc]);
                acc[mr][nc] = mfma16(am_h[mr], bn_l[nc], acc[mr][nc]);
            }
    }

    if constexpr (EPI == 0) {
        float* O = half ? o1 : o0;
        const float* v1 = half ? bv1 : av1;
        const float* v2 = half ? bv2 : av2;
        const float* v3 = half ? bv3 : av3;
#pragma unroll
        for (int mr = 0; mr < 4; mr++)
#pragma unroll
            for (int rr = 0; rr < 4; rr++) {
                int rl = qr * 64 + mr * 16 + hi4 * 4 + rr;
                int row = row0 + rl;
                float d0 = 0.f, d1 = 0.f, d2 = 0.f, d3 = 0.f;
#pragma unroll
                for (int nc = 0; nc < 4; nc++) {
                    float v = fmaxf(acc[mr][nc][rr], 0.f);
                    int col = qc * 64 + nc * 16 + lr;
                    O[(size_t)row * 128 + col] = v;
                    if (half == 0) oh[(size_t)row * 128 + col] = f2bu(v);
                    d0 = fmaf(v, v1[col], d0);
                    d1 = fmaf(v, v2[col], d1);
                    d2 = fmaf(v, v3[col], d2);
                    d3 = fmaf(v, half ? v : av4[col], d3);
                }
#pragma unroll
                for (int o = 1; o <= 8; o <<= 1) {
                    d0 += __shfl_xor(d0, o, 64);
                    d1 += __shfl_xor(d1, o, 64);
                    d2 += __shfl_xor(d2, o, 64);
                    d3 += __shfl_xor(d3, o, 64);
                }
                if (lr == 0) {
                    pd[qc][rl][0] = d0; pd[qc][rl][1] = d1;
                    pd[qc][rl][2] = d2; pd[qc][rl][3] = d3;
                }
            }
        __syncthreads();
        if (qc == 0) {
#pragma unroll
            for (int mr = 0; mr < 4; mr++)
#pragma unroll
                for (int rr = 0; rr < 4; rr++) {
                    if (lr == 0) {
                        int rl = qr * 64 + mr * 16 + hi4 * 4 + rr;
                        int row = row0 + rl;
                        float s0 = pd[0][rl][0] + pd[1][rl][0];
                        float s1 = pd[0][rl][1] + pd[1][rl][1];
                        float s2 = pd[0][rl][2] + pd[1][rl][2];
                        float s3 = pd[0][rl][3] + pd[1][rl][3];
                        if (half == 0) ehv[row] = make_float4(s0, s1, s2, s3);
                        else           etv[row] = make_float4(s0, s1, s2, sqrtf(s3));
                    }
                }
        }
    } else {
#pragma unroll
        for (int mr = 0; mr < 4; mr++)
#pragma unroll
            for (int rr = 0; rr < 4; rr++) {
                int row = row0 + qr * 64 + mr * 16 + hi4 * 4 + rr;
#pragma unroll
                for (int nc = 0; nc < 4; nc++) {
                    int col = qc * 64 + nc * 16 + lr;
                    float a = acc[mr][nc][rr] + bias[col];
                    float g = 1.f / (1.f + expf(-a));
                    size_t o = (size_t)row * 128 + col;
                    o0[o] = g * xeh[o] + (1.f - g) * Af[o];
                }
            }
    }
}

__global__ __launch_bounds__(256) void k_mm_proj(
    const unsigned short* Ah, const unsigned short* Al,
    const unsigned short* Bh, const unsigned short* Bl,
    float* o0, float* o1, unsigned short* oh, int M,
    const float* av1, const float* av2, const float* av3, const float* av4,
    const float* bv1, const float* bv2, const float* bv3,
    float4* ehv, float4* etv) {
    mm_body<0>(Ah, Al, Bh, Bl, o0, o1, oh, nullptr, nullptr, nullptr, M,
               av1, av2, av3, av4, bv1, bv2, bv3, ehv, etv);
}

__global__ __launch_bounds__(256) void k_mm_hw(
    const unsigned short* Ah, const unsigned short* Bh, const unsigned short* Bl,
    float* o0, const float* Af, const float* bias, const float* xeh, int M) {
    mm_body<1>(Ah, nullptr, Bh, Bl, o0, nullptr, nullptr, Af, bias, xeh, M,
               nullptr, nullptr, nullptr, nullptr, nullptr, nullptr, nullptr,
               nullptr, nullptr);
}

// ---- relation dots -> packed float2 (er1, er2) ----
__global__ __launch_bounds__(256) void k_rel(const float* __restrict__ remb,
                                             const float* __restrict__ ar1,
                                             const float* __restrict__ ar2,
                                             float2* __restrict__ erv, int NR) {
    int lane = threadIdx.x & 63;
    int r = blockIdx.x * 4 + (threadIdx.x >> 6);
    if (r >= NR) return;
    float v0 = remb[(size_t)r * 128 + lane];
    float v1 = remb[(size_t)r * 128 + 64 + lane];
    float p1 = v0 * ar1[lane] + v1 * ar1[64 + lane];
    float p2 = v0 * ar2[lane] + v1 * ar2[64 + lane];
    p1 = wred(p1);
    p2 = wred(p2);
    if (lane == 0) erv[r] = make_float2(p1, p2);
}

// ---- level 1 softmax over triple_num segments ----
__global__ __launch_bounds__(256) void k_edge1(
    const int* __restrict__ hidx, const int* __restrict__ tidx,
    const int* __restrict__ rel, const int* __restrict__ tnum,
    const float4* __restrict__ ehv, const float4* __restrict__ etv,
    const float2* __restrict__ erv, float* __restrict__ zbuf,
    unsigned* __restrict__ m1, int E) {
    int i = blockIdx.x * 256 + threadIdx.x;
    if (i >= E) return;
    float e1 = 0.5f * (ehv[hidx[i]].x + etv[tidx[i]].x) + erv[rel[i]].x;
    float z = LRELU(e1);
    zbuf[i] = z;
    atomicMax(&m1[tnum[i]], fenc(z));
}

__global__ __launch_bounds__(256) void k_edge2(const int* __restrict__ tnum,
                                               float* __restrict__ zbuf,
                                               const unsigned* __restrict__ m1,
                                               float* __restrict__ s1, int E) {
    int i = blockIdx.x * 256 + threadIdx.x;
    if (i >= E) return;
    int tn = tnum[i];
    float ex = expf(zbuf[i] - fdec(m1[tn]));
    zbuf[i] = ex;
    atomicAdd(&s1[tn], ex);
}

// ---- alpha -> per-edge scale s, level-2 logit z2 (no atomics) ----
__global__ __launch_bounds__(256) void k_edge3(
    const int* __restrict__ hidx, const int* __restrict__ tidx,
    const int* __restrict__ rel, const int* __restrict__ tnum,
    const float* __restrict__ zbuf, const float* __restrict__ s1,
    const float4* __restrict__ ehv, const float4* __restrict__ etv,
    const float2* __restrict__ erv, float* __restrict__ sbuf,
    float* __restrict__ e2buf, int E) {
    int i = blockIdx.x * 256 + threadIdx.x;
    if (i >= E) return;
    float alpha = zbuf[i] / (s1[tnum[i]] + 1e-16f);
    int t = tidx[i];
    float4 ev = etv[t];
    float4 hv = ehv[hidx[i]];
    float s = alpha / fmaxf(alpha * ev.w, 1e-12f);
    sbuf[i] = s;
    float z2 = s * ev.y + hv.y + 0.5f * (erv[rel[i]].y + 0.5f * (hv.z + s * ev.z));
    e2buf[i] = LRELU(z2);
}

// ---- counting sort by class_index ----
__global__ __launch_bounds__(256) void k_hist(const int* __restrict__ cidx,
                                              int* __restrict__ cnt, int E) {
    int i = blockIdx.x * 256 + threadIdx.x;
    if (i >= E) return;
    atomicAdd(&cnt[cidx[i]], 1);
}

__global__ __launch_bounds__(1024) void k_scan(const int* __restrict__ cnt,
                                               int* __restrict__ off,
                                               int* __restrict__ cur, int NC) {
    __shared__ int wt[16];
    __shared__ int sbase;
    int tid = threadIdx.x, w = tid >> 6, lane = tid & 63;
    if (tid == 0) sbase = 0;
    __syncthreads();
    for (int c0 = 0; c0 < NC; c0 += 1024) {
        int c = c0 + tid;
        int v = (c < NC) ? cnt[c] : 0;
        int x = v;
#pragma unroll
        for (int o = 1; o < 64; o <<= 1) {
            int t = __shfl_up(x, o, 64);
            if (lane >= o) x += t;
        }
        if (lane == 63) wt[w] = x;
        __syncthreads();
        int pre = 0, tot = 0;
#pragma unroll
        for (int i = 0; i < 16; i++) {
            int t = wt[i];
            tot += t;
            if (i < w) pre += t;
        }
        int excl = sbase + pre + x - v;
        if (c < NC) { off[c] = excl; cur[c] = excl; }
        __syncthreads();
        if (tid == 0) sbase += tot;
        __syncthreads();
    }
}

__global__ __launch_bounds__(256) void k_scatter(const int* __restrict__ cidx,
                                                 int* __restrict__ cur,
                                                 int* __restrict__ elist, int E) {
    int i = blockIdx.x * 256 + threadIdx.x;
    if (i >= E) return;
    int pos = atomicAdd(&cur[cidx[i]], 1);
    elist[pos] = i;
}

// ---- fused level-2 softmax + spmm, one wave per class, batched gathers ----
__global__ __launch_bounds__(256) void k_spmm2(
    const int* __restrict__ elist, const int* __restrict__ off,
    const int* __restrict__ cnt, const int* __restrict__ tidx,
    const float* __restrict__ e2buf, const float* __restrict__ sbuf,
    const float* __restrict__ xrt, float* __restrict__ xclass, int NC) {
    int lane = threadIdx.x & 63;
    int c = blockIdx.x * 4 + (threadIdx.x >> 6);
    if (c >= NC) return;
    int n = cnt[c];
    if (n == 0) {
        xclass[(size_t)c * 128 + lane] = 0.f;
        xclass[(size_t)c * 128 + 64 + lane] = 0.f;
        return;
    }
    int base = off[c];
    float m = -3.4e38f;
    for (int j = lane; j < n; j += 64) m = fmaxf(m, e2buf[elist[base + j]]);
    m = wredmax(m);
    float s = 0.f;
    for (int j = lane; j < n; j += 64) s += expf(e2buf[elist[base + j]] - m);
    s = wred(s);
    float inv = 1.f / (s + 1e-16f);
    float a0 = 0.f, a1 = 0.f;
    for (int j0 = 0; j0 < n; j0 += 64) {
        int lim = n - j0;
        if (lim > 64) lim = 64;
        float wv = 0.f;
        int g = 0;
        if (lane < lim) {
            int e = elist[base + j0 + lane];
            wv = expf(e2buf[e] - m) * inv;
            int te = tidx[e];
            wv *= sbuf[te];
            g = tidx[te];
        }
        int jj = 0;
        for (; jj + 8 <= lim; jj += 8) {
            float w0 = __shfl(wv, jj + 0), w1 = __shfl(wv, jj + 1);
            float w2 = __shfl(wv, jj + 2), w3 = __shfl(wv, jj + 3);
            float w4 = __shfl(wv, jj + 4), w5 = __shfl(wv, jj + 5);
            float w6 = __shfl(wv, jj + 6), w7 = __shfl(wv, jj + 7);
            const float* p0 = xrt + (size_t)__shfl(g, jj + 0) * 128 + lane;
            const float* p1 = xrt + (size_t)__shfl(g, jj + 1) * 128 + lane;
            const float* p2 = xrt + (size_t)__shfl(g, jj + 2) * 128 + lane;
            const float* p3 = xrt + (size_t)__shfl(g, jj + 3) * 128 + lane;
            const float* p4 = xrt + (size_t)__shfl(g, jj + 4) * 128 + lane;
            const float* p5 = xrt + (size_t)__shfl(g, jj + 5) * 128 + lane;
            const float* p6 = xrt + (size_t)__shfl(g, jj + 6) * 128 + lane;
            const float* p7 = xrt + (size_t)__shfl(g, jj + 7) * 128 + lane;
            float x0 = p0[0], y0 = p0[64], x1 = p1[0], y1 = p1[64];
            float x2 = p2[0], y2 = p2[64], x3 = p3[0], y3 = p3[64];
            float x4 = p4[0], y4 = p4[64], x5 = p5[0], y5 = p5[64];
            float x6 = p6[0], y6 = p6[64], x7 = p7[0], y7 = p7[64];
            a0 = fmaf(w0, x0, a0); a1 = fmaf(w0, y0, a1);
            a0 = fmaf(w1, x1, a0); a1 = fmaf(w1, y1, a1);
            a0 = fmaf(w2, x2, a0); a1 = fmaf(w2, y2, a1);
            a0 = fmaf(w3, x3, a0); a1 = fmaf(w3, y3, a1);
            a0 = fmaf(w4, x4, a0); a1 = fmaf(w4, y4, a1);
            a0 = fmaf(w5, x5, a0); a1 = fmaf(w5, y5, a1);
            a0 = fmaf(w6, x6, a0); a1 = fmaf(w6, y6, a1);
            a0 = fmaf(w7, x7, a0); a1 = fmaf(w7, y7, a1);
        }
        for (; jj < lim; jj++) {
            float wj = __shfl(wv, jj);
            int gj = __shfl(g, jj);
            a0 = fmaf(wj, xrt[(size_t)gj * 128 + lane], a0);
            a1 = fmaf(wj, xrt[(size_t)gj * 128 + 64 + lane], a1);
        }
    }
    xclass[(size_t)c * 128 + lane] = a0;
    xclass[(size_t)c * 128 + 64 + lane] = a1;
}

// ---- level 3: class -> head entity ----
__global__ __launch_bounds__(256) void k_class1(
    const float* __restrict__ xclass, const float* __restrict__ ac,
    const float4* __restrict__ ehv, const int* __restrict__ hclass,
    float* __restrict__ zc, unsigned* __restrict__ m3, int NC) {
    int lane = threadIdx.x & 63;
    int c = blockIdx.x * 4 + (threadIdx.x >> 6);
    if (c >= NC) return;
    float v0 = xclass[(size_t)c * 128 + lane], v1 = xclass[(size_t)c * 128 + 64 + lane];
    float p = wred(v0 * ac[lane] + v1 * ac[64 + lane]);
    if (lane == 0) {
        int hc = hclass[c];
        float z = LRELU(p + ehv[hc].w);
        zc[c] = z;
        atomicMax(&m3[hc], fenc(z));
    }
}

__global__ __launch_bounds__(256) void k_class2(const int* __restrict__ hclass,
                                                float* __restrict__ zc,
                                                const unsigned* __restrict__ m3,
                                                float* __restrict__ s3, int NC) {
    int c = blockIdx.x * 256 + threadIdx.x;
    if (c >= NC) return;
    int hc = hclass[c];
    float ex = expf(zc[c] - fdec(m3[hc]));
    zc[c] = ex;
    atomicAdd(&s3[hc], ex);
}

__global__ __launch_bounds__(256) void k_class3(
    const int* __restrict__ hclass, const float* __restrict__ zc,
    const float* __restrict__ s3, const float* __restrict__ xclass,
    float* __restrict__ xeh, int NC) {
    int lane = threadIdx.x & 63;
    int c = blockIdx.x * 4 + (threadIdx.x >> 6);
    if (c >= NC) return;
    int hc = hclass[c];
    float gama = zc[c] / (s3[hc] + 1e-16f);
    float v0 = xclass[(size_t)c * 128 + lane], v1 = xclass[(size_t)c * 128 + 64 + lane];
    atomicAdd(&xeh[(size_t)hc * 128 + lane], gama * v0);
    atomicAdd(&xeh[(size_t)hc * 128 + 64 + lane], gama * v1);
}

extern "C" void kernel_launch(void* const* d_in, const int* in_sizes, int n_in,
                              void* d_out, int out_size, void* d_ws, size_t ws_size,
                              hipStream_t stream) {
    (void)n_in; (void)out_size; (void)ws_size;
    const float* xe   = (const float*)d_in[0];
    const int*   eidx = (const int*)d_in[1];
    const int*   rel  = (const int*)d_in[2];
    const int*   tnum = (const int*)d_in[3];
    const float* remb = (const float*)d_in[4];
    const int*   cidx = (const int*)d_in[5];
    const int*   hcls = (const int*)d_in[6];
    const float* ah1  = (const float*)d_in[7];
    const float* ah2  = (const float*)d_in[8];
    const float* ah3  = (const float*)d_in[9];
    const float* ah4  = (const float*)d_in[10];
    const float* at1  = (const float*)d_in[11];
    const float* at2  = (const float*)d_in[12];
    const float* at3  = (const float*)d_in[13];
    const float* ar1  = (const float*)d_in[14];
    const float* ar2  = (const float*)d_in[15];
    const float* ac   = (const float*)d_in[16];
    const float* wh   = (const float*)d_in[17];
    const float* wt   = (const float*)d_in[18];
    const float* hww  = (const float*)d_in[19];
    const float* hwb  = (const float*)d_in[20];
    float* out = (float*)d_out;

    const int NE = in_sizes[0] / 256;
    const int E  = in_sizes[2];
    const int NR = in_sizes[4] / 128;
    const int NC = in_sizes[6];
    const int* hidx = eidx;
    const int* tidx = eidx + E;

    char* base = (char*)d_ws;
    size_t off0 = 0;
    auto alloc = [&](size_t bytes) -> char* {
        char* r = base + off0;
        off0 = (off0 + bytes + 255) & ~(size_t)255;
        return r;
    };
    float* xrh  = (float*)alloc((size_t)NE * 128 * 4);
    float* xrt  = (float*)alloc((size_t)NE * 128 * 4);
    float4* ehv = (float4*)alloc((size_t)NE * 16);
    float4* etv = (float4*)alloc((size_t)NE * 16);
    float2* erv = (float2*)alloc((size_t)NR * 8);
    float* zbuf  = (float*)alloc((size_t)E * 4);
    float* e2buf = (float*)alloc((size_t)E * 4);
    float* sbuf  = (float*)alloc((size_t)E * 4);
    float* zc    = (float*)alloc((size_t)NC * 4);
    unsigned short* wtb_hi = (unsigned short*)alloc((size_t)256 * 256 * 2);
    unsigned short* wtb_lo = (unsigned short*)alloc((size_t)256 * 256 * 2);
    unsigned short* hwt_hi = (unsigned short*)alloc((size_t)128 * 128 * 2);
    unsigned short* hwt_lo = (unsigned short*)alloc((size_t)128 * 128 * 2);
    unsigned short* a_hi   = (unsigned short*)alloc((size_t)NE * 256 * 2);
    unsigned short* a_lo   = (unsigned short*)alloc((size_t)NE * 256 * 2);
    unsigned short* xrh_hi = (unsigned short*)alloc((size_t)NE * 128 * 2);
    int* offb  = (int*)alloc((size_t)NC * 4);
    int* curb  = (int*)alloc((size_t)NC * 4);
    int* elist = (int*)alloc((size_t)E * 4);
    float* xclass = (float*)alloc((size_t)NC * 128 * 4);
    size_t zoff = off0;  // everything below is zero-initialized per launch
    unsigned* m1 = (unsigned*)alloc((size_t)NE * 4);
    float* s1    = (float*)alloc((size_t)NE * 4);
    unsigned* m3 = (unsigned*)alloc((size_t)NE * 4);
    float* s3    = (float*)alloc((size_t)NE * 4);
    int* cntb    = (int*)alloc((size_t)NC * 4);
    float* xeh   = (float*)alloc((size_t)NE * 128 * 4);
    size_t zbytes = off0 - zoff;

    hipMemsetAsync(base + zoff, 0, zbytes, stream);

    k_convW<<<(256 * 256 + 128 * 128 + 255) / 256, 256, 0, stream>>>(
        wh, wt, hww, wtb_hi, wtb_lo, hwt_hi, hwt_lo);
    long n8 = (long)NE * 256 / 8;
    k_convA<<<(int)((n8 + 255) / 256), 256, 0, stream>>>(xe, a_hi, a_lo, n8);
    k_rel<<<(NR + 3) / 4, 256, 0, stream>>>(remb, ar1, ar2, erv, NR);

    // projection GEMM (128x128 LDS-staged) with fused per-entity dots + norm
    k_mm_proj<<<((NE + 127) / 128) * 2, 256, 0, stream>>>(
        a_hi, a_lo, wtb_hi, wtb_lo, xrh, xrt, xrh_hi, NE,
        ah1, ah2, ah3, ah4, at1, at2, at3, ehv, etv);

    // class-CSR build (independent of edge kernels)
    k_hist<<<(E + 255) / 256, 256, 0, stream>>>(cidx, cntb, E);
    k_scan<<<1, 1024, 0, stream>>>(cntb, offb, curb, NC);
    k_scatter<<<(E + 255) / 256, 256, 0, stream>>>(cidx, curb, elist, E);

    k_edge1<<<(E + 255) / 256, 256, 0, stream>>>(hidx, tidx, rel, tnum, ehv, etv, erv, zbuf, m1, E);
    k_edge2<<<(E + 255) / 256, 256, 0, stream>>>(tnum, zbuf, m1, s1, E);
    k_edge3<<<(E + 255) / 256, 256, 0, stream>>>(hidx, tidx, rel, tnum, zbuf, s1,
                                                 ehv, etv, erv, sbuf, e2buf, E);
    k_spmm2<<<(NC + 3) / 4, 256, 0, stream>>>(elist, offb, cntb, tidx, e2buf, sbuf,
                                              xrt, xclass, NC);
    k_class1<<<(NC + 3) / 4, 256, 0, stream>>>(xclass, ac, ehv, hcls, zc, m3, NC);
    k_class2<<<(NC + 255) / 256, 256, 0, stream>>>(hcls, zc, m3, s3, NC);
    k_class3<<<(NC + 3) / 4, 256, 0, stream>>>(hcls, zc, s3, xclass, xeh, NC);

    k_mm_hw<<<(NE + 127) / 128, 256, 0, stream>>>(
        xrh_hi, hwt_hi, hwt_lo, out, xrh, hwb, xeh, NE);
}

// Round 9
// 544.902 us; speedup vs baseline: 1.2354x; 1.0795x over previous
//
#include <hip/hip_runtime.h>
#include <hip/hip_bf16.h>

#define LRELU(x) ((x) >= 0.f ? (x) : 0.01f * (x))

typedef __attribute__((ext_vector_type(8))) short short8v;
typedef __attribute__((ext_vector_type(4))) float f32x4;

__device__ inline unsigned fenc(float x) {
    unsigned u = __float_as_uint(x);
    return (u & 0x80000000u) ? ~u : (u | 0x80000000u);
}
__device__ inline float fdec(unsigned e) {
    return __uint_as_float((e & 0x80000000u) ? (e ^ 0x80000000u) : ~e);
}

__device__ inline float wred(float v) {
#pragma unroll
    for (int o = 32; o > 0; o >>= 1) v += __shfl_xor(v, o, 64);
    return v;
}
__device__ inline float wredmax(float v) {
#pragma unroll
    for (int o = 32; o > 0; o >>= 1) v = fmaxf(v, __shfl_xor(v, o, 64));
    return v;
}

__device__ inline unsigned short f2bu(float x) {
    __hip_bfloat16 b = __float2bfloat16(x);
    return *reinterpret_cast<unsigned short*>(&b);
}
__device__ inline float bu2f(unsigned short u) {
    return __uint_as_float((unsigned)u << 16);
}

__device__ inline f32x4 mfma16(short8v a, short8v b, f32x4 c) {
    return __builtin_amdgcn_mfma_f32_16x16x32_bf16(a, b, c, 0, 0, 0);
}

// async global->LDS, 16B per lane, dest = (wave-uniform base) + lane*16
__device__ inline void gload16(const void* g, void* l) {
    __builtin_amdgcn_global_load_lds(
        (const __attribute__((address_space(1))) void*)g,
        (__attribute__((address_space(3))) void*)l, 16, 0, 0);
}

// ---- convert W matrices to transposed hi/lo bf16: Wt[n][k] = W[k][n] ----
__global__ __launch_bounds__(256) void k_convW(
    const float* __restrict__ wh, const float* __restrict__ wt,
    const float* __restrict__ hww, unsigned short* __restrict__ wtb_hi,
    unsigned short* __restrict__ wtb_lo, unsigned short* __restrict__ hwt_hi,
    unsigned short* __restrict__ hwt_lo) {
    int id = blockIdx.x * 256 + threadIdx.x;
    if (id < 256 * 256) {
        int n = id >> 8, k = id & 255;
        float v = (n < 128) ? wh[(size_t)k * 128 + n] : wt[(size_t)k * 128 + (n - 128)];
        unsigned short h = f2bu(v);
        float r = v - bu2f(h);
        wtb_hi[(size_t)n * 256 + k] = h;
        wtb_lo[(size_t)n * 256 + k] = f2bu(r);
    } else {
        int id2 = id - 256 * 256;
        if (id2 < 128 * 128) {
            int n = id2 >> 7, k = id2 & 127;
            float v = hww[(size_t)k * 128 + n];
            unsigned short h = f2bu(v);
            float r = v - bu2f(h);
            hwt_hi[(size_t)n * 128 + k] = h;
            hwt_lo[(size_t)n * 128 + k] = f2bu(r);
        }
    }
}

// ---- convert A (x_e) to split hi/lo bf16, row-major [NE][256] ----
__global__ __launch_bounds__(256) void k_convA(const float* __restrict__ x,
                                               unsigned short* __restrict__ hi,
                                               unsigned short* __restrict__ lo,
                                               long n8) {
    long i = (long)blockIdx.x * 256 + threadIdx.x;
    if (i >= n8) return;
    const float4* xp = (const float4*)(x + i * 8);
    float4 a = xp[0], b = xp[1];
    float xs[8] = {a.x, a.y, a.z, a.w, b.x, b.y, b.z, b.w};
    short8v vh, vl;
#pragma unroll
    for (int j = 0; j < 8; j++) {
        unsigned short h = f2bu(xs[j]);
        vh[j] = (short)h;
        vl[j] = (short)f2bu(xs[j] - bu2f(h));
    }
    *(short8v*)(hi + i * 8) = vh;
    *(short8v*)(lo + i * 8) = vl;
}

// ---- m97-style LDS-staged split-bf16 MFMA GEMM ----
// Block 128x128, 4 waves in 2x2 quadrants, acc[4][4], BK=32, 2 barriers/step.
// EPI 0 (proj, KD=256): half0 -> o0=xrh (+oh0 bf16 mirror), dots->ehv;
//   half1 -> o1=xrt (+oh1 bf16 mirror), dots+norm->etv.
// EPI 1 (highway, KD=128): A=bf16 hi only; gate=sigmoid(C+bias);
//   o0 = g*xeh + (1-g)*Af.
template <int EPI>
__device__ __forceinline__ void mm_body(
    const unsigned short* __restrict__ Ah, const unsigned short* __restrict__ Al,
    const unsigned short* __restrict__ Bh, const unsigned short* __restrict__ Bl,
    float* __restrict__ o0, float* __restrict__ o1,
    unsigned short* __restrict__ oh0, unsigned short* __restrict__ oh1,
    const float* __restrict__ Af, const float* __restrict__ bias,
    const float* __restrict__ xeh, int M,
    const float* __restrict__ av1, const float* __restrict__ av2,
    const float* __restrict__ av3, const float* __restrict__ av4,
    const float* __restrict__ bv1, const float* __restrict__ bv2,
    const float* __restrict__ bv3,
    float4* __restrict__ ehv, float4* __restrict__ etv) {
    constexpr int KD = (EPI == 0) ? 256 : 128;
    constexpr int NSTEP = KD / 32;
    __shared__ unsigned short As_h[128 * 32];
    __shared__ unsigned short As_l[(EPI == 0) ? 128 * 32 : 64];
    __shared__ unsigned short Bs_h[128 * 32];
    __shared__ unsigned short Bs_l[128 * 32];
    __shared__ float pd[(EPI == 0) ? 2 : 1][(EPI == 0) ? 128 : 1][4];

    int bx = blockIdx.x;
    int half = (EPI == 0) ? (bx & 1) : 0;
    int mblk = (EPI == 0) ? (bx >> 1) : bx;
    int row0 = mblk * 128;
    if (row0 + 128 > M) row0 = M - 128;
    int tid = threadIdx.x, w = tid >> 6, l = tid & 63;
    int qr = w >> 1, qc = w & 1;
    int lr = l & 15, hi4 = l >> 4;
    int srow = l >> 2, sslot = l & 3;

    f32x4 acc[4][4];
#pragma unroll
    for (int i = 0; i < 4; i++)
#pragma unroll
        for (int j = 0; j < 4; j++) acc[i][j] = (f32x4){0.f, 0.f, 0.f, 0.f};

    constexpr int NU = (EPI == 0) ? 8 : 6;

    for (int s = 0; s < NSTEP; s++) {
        int k0 = s * 32;
        __syncthreads();
#pragma unroll
        for (int i = 0; i < NU; i++) {
            int u = w * NU + i;
            int arr = u >> 3, ld = u & 7;
            int row = ld * 16 + srow;
            int klog = (sslot ^ ((row >> 1) & 3)) * 8;
            const unsigned short* src;
            unsigned short* dst;
            if constexpr (EPI == 0) {
                if (arr == 0)      { src = Ah + (size_t)(row0 + row) * KD;       dst = As_h; }
                else if (arr == 1) { src = Al + (size_t)(row0 + row) * KD;       dst = As_l; }
                else if (arr == 2) { src = Bh + (size_t)(half * 128 + row) * KD; dst = Bs_h; }
                else               { src = Bl + (size_t)(half * 128 + row) * KD; dst = Bs_l; }
            } else {
                if (arr == 0)      { src = Ah + (size_t)(row0 + row) * KD; dst = As_h; }
                else if (arr == 1) { src = Bh + (size_t)row * KD;          dst = Bs_h; }
                else               { src = Bl + (size_t)row * KD;          dst = Bs_l; }
            }
            gload16(src + k0 + klog, dst + ld * 512);
        }
        __syncthreads();

        short8v am_h[4], am_l[4], bn_h[4], bn_l[4];
#pragma unroll
        for (int mr = 0; mr < 4; mr++) {
            int r = qr * 64 + mr * 16 + lr;
            int ko = (hi4 ^ ((r >> 1) & 3)) * 8;
            am_h[mr] = *(const short8v*)&As_h[r * 32 + ko];
            if constexpr (EPI == 0) am_l[mr] = *(const short8v*)&As_l[r * 32 + ko];
        }
#pragma unroll
        for (int nc = 0; nc < 4; nc++) {
            int n = qc * 64 + nc * 16 + lr;
            int ko = (hi4 ^ ((n >> 1) & 3)) * 8;
            bn_h[nc] = *(const short8v*)&Bs_h[n * 32 + ko];
            bn_l[nc] = *(const short8v*)&Bs_l[n * 32 + ko];
        }
#pragma unroll
        for (int mr = 0; mr < 4; mr++)
#pragma unroll
            for (int nc = 0; nc < 4; nc++) {
                acc[mr][nc] = mfma16(am_h[mr], bn_h[nc], acc[mr][nc]);
                if constexpr (EPI == 0)
                    acc[mr][nc] = mfma16(am_l[mr], bn_h[nc], acc[mr][nc]);
                acc[mr][nc] = mfma16(am_h[mr], bn_l[nc], acc[mr][nc]);
            }
    }

    if constexpr (EPI == 0) {
        float* O = half ? o1 : o0;
        unsigned short* OH = half ? oh1 : oh0;
        const float* v1 = half ? bv1 : av1;
        const float* v2 = half ? bv2 : av2;
        const float* v3 = half ? bv3 : av3;
#pragma unroll
        for (int mr = 0; mr < 4; mr++)
#pragma unroll
            for (int rr = 0; rr < 4; rr++) {
                int rl = qr * 64 + mr * 16 + hi4 * 4 + rr;
                int row = row0 + rl;
                float d0 = 0.f, d1 = 0.f, d2 = 0.f, d3 = 0.f;
#pragma unroll
                for (int nc = 0; nc < 4; nc++) {
                    float v = fmaxf(acc[mr][nc][rr], 0.f);
                    int col = qc * 64 + nc * 16 + lr;
                    O[(size_t)row * 128 + col] = v;
                    OH[(size_t)row * 128 + col] = f2bu(v);
                    d0 = fmaf(v, v1[col], d0);
                    d1 = fmaf(v, v2[col], d1);
                    d2 = fmaf(v, v3[col], d2);
                    d3 = fmaf(v, half ? v : av4[col], d3);
                }
#pragma unroll
                for (int o = 1; o <= 8; o <<= 1) {
                    d0 += __shfl_xor(d0, o, 64);
                    d1 += __shfl_xor(d1, o, 64);
                    d2 += __shfl_xor(d2, o, 64);
                    d3 += __shfl_xor(d3, o, 64);
                }
                if (lr == 0) {
                    pd[qc][rl][0] = d0; pd[qc][rl][1] = d1;
                    pd[qc][rl][2] = d2; pd[qc][rl][3] = d3;
                }
            }
        __syncthreads();
        if (qc == 0) {
#pragma unroll
            for (int mr = 0; mr < 4; mr++)
#pragma unroll
                for (int rr = 0; rr < 4; rr++) {
                    if (lr == 0) {
                        int rl = qr * 64 + mr * 16 + hi4 * 4 + rr;
                        int row = row0 + rl;
                        float s0 = pd[0][rl][0] + pd[1][rl][0];
                        float s1 = pd[0][rl][1] + pd[1][rl][1];
                        float s2 = pd[0][rl][2] + pd[1][rl][2];
                        float s3 = pd[0][rl][3] + pd[1][rl][3];
                        if (half == 0) ehv[row] = make_float4(s0, s1, s2, s3);
                        else           etv[row] = make_float4(s0, s1, s2, sqrtf(s3));
                    }
                }
        }
    } else {
#pragma unroll
        for (int mr = 0; mr < 4; mr++)
#pragma unroll
            for (int rr = 0; rr < 4; rr++) {
                int row = row0 + qr * 64 + mr * 16 + hi4 * 4 + rr;
#pragma unroll
                for (int nc = 0; nc < 4; nc++) {
                    int col = qc * 64 + nc * 16 + lr;
                    float a = acc[mr][nc][rr] + bias[col];
                    float g = 1.f / (1.f + expf(-a));
                    size_t o = (size_t)row * 128 + col;
                    o0[o] = g * xeh[o] + (1.f - g) * Af[o];
                }
            }
    }
}

__global__ __launch_bounds__(256) void k_mm_proj(
    const unsigned short* Ah, const unsigned short* Al,
    const unsigned short* Bh, const unsigned short* Bl,
    float* o0, float* o1, unsigned short* oh0, unsigned short* oh1, int M,
    const float* av1, const float* av2, const float* av3, const float* av4,
    const float* bv1, const float* bv2, const float* bv3,
    float4* ehv, float4* etv) {
    mm_body<0>(Ah, Al, Bh, Bl, o0, o1, oh0, oh1, nullptr, nullptr, nullptr, M,
               av1, av2, av3, av4, bv1, bv2, bv3, ehv, etv);
}

__global__ __launch_bounds__(256) void k_mm_hw(
    const unsigned short* Ah, const unsigned short* Bh, const unsigned short* Bl,
    float* o0, const float* Af, const float* bias, const float* xeh, int M) {
    mm_body<1>(Ah, nullptr, Bh, Bl, o0, nullptr, nullptr, nullptr, Af, bias, xeh, M,
               nullptr, nullptr, nullptr, nullptr, nullptr, nullptr, nullptr,
               nullptr, nullptr);
}

// ---- relation dots -> packed float2 (er1, er2) ----
__global__ __launch_bounds__(256) void k_rel(const float* __restrict__ remb,
                                             const float* __restrict__ ar1,
                                             const float* __restrict__ ar2,
                                             float2* __restrict__ erv, int NR) {
    int lane = threadIdx.x & 63;
    int r = blockIdx.x * 4 + (threadIdx.x >> 6);
    if (r >= NR) return;
    float v0 = remb[(size_t)r * 128 + lane];
    float v1 = remb[(size_t)r * 128 + 64 + lane];
    float p1 = v0 * ar1[lane] + v1 * ar1[64 + lane];
    float p2 = v0 * ar2[lane] + v1 * ar2[64 + lane];
    p1 = wred(p1);
    p2 = wred(p2);
    if (lane == 0) erv[r] = make_float2(p1, p2);
}

// ---- level 1 softmax over triple_num segments ----
__global__ __launch_bounds__(256) void k_edge1(
    const int* __restrict__ hidx, const int* __restrict__ tidx,
    const int* __restrict__ rel, const int* __restrict__ tnum,
    const float4* __restrict__ ehv, const float4* __restrict__ etv,
    const float2* __restrict__ erv, float* __restrict__ zbuf,
    unsigned* __restrict__ m1, int E) {
    int i = blockIdx.x * 256 + threadIdx.x;
    if (i >= E) return;
    float e1 = 0.5f * (ehv[hidx[i]].x + etv[tidx[i]].x) + erv[rel[i]].x;
    float z = LRELU(e1);
    zbuf[i] = z;
    atomicMax(&m1[tnum[i]], fenc(z));
}

__global__ __launch_bounds__(256) void k_edge2(const int* __restrict__ tnum,
                                               float* __restrict__ zbuf,
                                               const unsigned* __restrict__ m1,
                                               float* __restrict__ s1, int E) {
    int i = blockIdx.x * 256 + threadIdx.x;
    if (i >= E) return;
    int tn = tnum[i];
    float ex = expf(zbuf[i] - fdec(m1[tn]));
    zbuf[i] = ex;
    atomicAdd(&s1[tn], ex);
}

// ---- alpha -> per-edge scale s, level-2 logit z2 (no atomics) ----
__global__ __launch_bounds__(256) void k_edge3(
    const int* __restrict__ hidx, const int* __restrict__ tidx,
    const int* __restrict__ rel, const int* __restrict__ tnum,
    const float* __restrict__ zbuf, const float* __restrict__ s1,
    const float4* __restrict__ ehv, const float4* __restrict__ etv,
    const float2* __restrict__ erv, float* __restrict__ sbuf,
    float* __restrict__ e2buf, int E) {
    int i = blockIdx.x * 256 + threadIdx.x;
    if (i >= E) return;
    float alpha = zbuf[i] / (s1[tnum[i]] + 1e-16f);
    int t = tidx[i];
    float4 ev = etv[t];
    float4 hv = ehv[hidx[i]];
    float s = alpha / fmaxf(alpha * ev.w, 1e-12f);
    sbuf[i] = s;
    float z2 = s * ev.y + hv.y + 0.5f * (erv[rel[i]].y + 0.5f * (hv.z + s * ev.z));
    e2buf[i] = LRELU(z2);
}

// ---- counting sort by class_index ----
__global__ __launch_bounds__(256) void k_hist(const int* __restrict__ cidx,
                                              int* __restrict__ cnt, int E) {
    int i = blockIdx.x * 256 + threadIdx.x;
    if (i >= E) return;
    atomicAdd(&cnt[cidx[i]], 1);
}

__global__ __launch_bounds__(1024) void k_scan(const int* __restrict__ cnt,
                                               int* __restrict__ off,
                                               int* __restrict__ cur, int NC) {
    __shared__ int wt[16];
    __shared__ int sbase;
    int tid = threadIdx.x, w = tid >> 6, lane = tid & 63;
    if (tid == 0) sbase = 0;
    __syncthreads();
    for (int c0 = 0; c0 < NC; c0 += 1024) {
        int c = c0 + tid;
        int v = (c < NC) ? cnt[c] : 0;
        int x = v;
#pragma unroll
        for (int o = 1; o < 64; o <<= 1) {
            int t = __shfl_up(x, o, 64);
            if (lane >= o) x += t;
        }
        if (lane == 63) wt[w] = x;
        __syncthreads();
        int pre = 0, tot = 0;
#pragma unroll
        for (int i = 0; i < 16; i++) {
            int t = wt[i];
            tot += t;
            if (i < w) pre += t;
        }
        int excl = sbase + pre + x - v;
        if (c < NC) { off[c] = excl; cur[c] = excl; }
        __syncthreads();
        if (tid == 0) sbase += tot;
        __syncthreads();
    }
}

__global__ __launch_bounds__(256) void k_scatter(const int* __restrict__ cidx,
                                                 int* __restrict__ cur,
                                                 int* __restrict__ elist, int E) {
    int i = blockIdx.x * 256 + threadIdx.x;
    if (i >= E) return;
    int pos = atomicAdd(&cur[cidx[i]], 1);
    elist[pos] = i;
}

// ---- gather per-edge scalars into class-sorted order (one random pass) ----
__global__ __launch_bounds__(256) void k_prep(
    const int* __restrict__ elist, const int* __restrict__ tidx,
    const float* __restrict__ e2buf, const float* __restrict__ sbuf,
    float* __restrict__ e2s, float* __restrict__ ws, int* __restrict__ gs, int E) {
    int p = blockIdx.x * 256 + threadIdx.x;
    if (p >= E) return;
    int e = elist[p];
    e2s[p] = e2buf[e];
    int te = tidx[e];
    ws[p] = sbuf[te];
    gs[p] = tidx[te];
}

// ---- fused level-2 softmax + spmm, one wave/class, bf16 row gathers ----
__global__ __launch_bounds__(256) void k_spmm2(
    const int* __restrict__ off, const int* __restrict__ cnt,
    const float* __restrict__ e2s, const float* __restrict__ ws,
    const int* __restrict__ gs, const unsigned* __restrict__ xrt_b,
    float* __restrict__ xclass, int NC) {
    int lane = threadIdx.x & 63;
    int c = blockIdx.x * 4 + (threadIdx.x >> 6);
    if (c >= NC) return;
    int n = cnt[c];
    float2* outp = (float2*)&xclass[(size_t)c * 128 + 2 * lane];
    if (n == 0) { *outp = make_float2(0.f, 0.f); return; }
    int base = off[c];
    // single coalesced pass: per-lane online max/sum, then cross-lane merge
    float m = -3.4e38f, s = 0.f;
    for (int j = lane; j < n; j += 64) {
        float z = e2s[base + j];
        if (z > m) { s = s * __expf(m - z) + 1.f; m = z; }
        else s += __expf(z - m);
    }
    float M = wredmax(m);
    s = wred(s * __expf(m - M));
    float inv = 1.f / (s + 1e-16f);
    // weighted row accumulation: coalesced scalars + bf16 row gathers
    float a0 = 0.f, a1 = 0.f;
    for (int j0 = 0; j0 < n; j0 += 64) {
        int lim = n - j0;
        if (lim > 64) lim = 64;
        float wv = 0.f;
        int g = 0;
        if (lane < lim) {
            int p = base + j0 + lane;
            wv = __expf(e2s[p] - M) * inv * ws[p];
            g = gs[p];
        }
        int jj = 0;
        for (; jj + 8 <= lim; jj += 8) {  // 8 rows in flight, 256B each
            float w0 = __shfl(wv, jj + 0), w1 = __shfl(wv, jj + 1);
            float w2 = __shfl(wv, jj + 2), w3 = __shfl(wv, jj + 3);
            float w4 = __shfl(wv, jj + 4), w5 = __shfl(wv, jj + 5);
            float w6 = __shfl(wv, jj + 6), w7 = __shfl(wv, jj + 7);
            unsigned u0 = xrt_b[(size_t)__shfl(g, jj + 0) * 64 + lane];
            unsigned u1 = xrt_b[(size_t)__shfl(g, jj + 1) * 64 + lane];
            unsigned u2 = xrt_b[(size_t)__shfl(g, jj + 2) * 64 + lane];
            unsigned u3 = xrt_b[(size_t)__shfl(g, jj + 3) * 64 + lane];
            unsigned u4 = xrt_b[(size_t)__shfl(g, jj + 4) * 64 + lane];
            unsigned u5 = xrt_b[(size_t)__shfl(g, jj + 5) * 64 + lane];
            unsigned u6 = xrt_b[(size_t)__shfl(g, jj + 6) * 64 + lane];
            unsigned u7 = xrt_b[(size_t)__shfl(g, jj + 7) * 64 + lane];
            a0 = fmaf(w0, bu2f((unsigned short)(u0 & 0xffff)), a0);
            a1 = fmaf(w0, bu2f((unsigned short)(u0 >> 16)), a1);
            a0 = fmaf(w1, bu2f((unsigned short)(u1 & 0xffff)), a0);
            a1 = fmaf(w1, bu2f((unsigned short)(u1 >> 16)), a1);
            a0 = fmaf(w2, bu2f((unsigned short)(u2 & 0xffff)), a0);
            a1 = fmaf(w2, bu2f((unsigned short)(u2 >> 16)), a1);
            a0 = fmaf(w3, bu2f((unsigned short)(u3 & 0xffff)), a0);
            a1 = fmaf(w3, bu2f((unsigned short)(u3 >> 16)), a1);
            a0 = fmaf(w4, bu2f((unsigned short)(u4 & 0xffff)), a0);
            a1 = fmaf(w4, bu2f((unsigned short)(u4 >> 16)), a1);
            a0 = fmaf(w5, bu2f((unsigned short)(u5 & 0xffff)), a0);
            a1 = fmaf(w5, bu2f((unsigned short)(u5 >> 16)), a1);
            a0 = fmaf(w6, bu2f((unsigned short)(u6 & 0xffff)), a0);
            a1 = fmaf(w6, bu2f((unsigned short)(u6 >> 16)), a1);
            a0 = fmaf(w7, bu2f((unsigned short)(u7 & 0xffff)), a0);
            a1 = fmaf(w7, bu2f((unsigned short)(u7 >> 16)), a1);
        }
        for (; jj < lim; jj++) {
            float wj = __shfl(wv, jj);
            unsigned u = xrt_b[(size_t)__shfl(g, jj) * 64 + lane];
            a0 = fmaf(wj, bu2f((unsigned short)(u & 0xffff)), a0);
            a1 = fmaf(wj, bu2f((unsigned short)(u >> 16)), a1);
        }
    }
    *outp = make_float2(a0, a1);  // cols 2*lane, 2*lane+1 (standard layout)
}

// ---- level 3: class -> head entity ----
__global__ __launch_bounds__(256) void k_class1(
    const float* __restrict__ xclass, const float* __restrict__ ac,
    const float4* __restrict__ ehv, const int* __restrict__ hclass,
    float* __restrict__ zc, unsigned* __restrict__ m3, int NC) {
    int lane = threadIdx.x & 63;
    int c = blockIdx.x * 4 + (threadIdx.x >> 6);
    if (c >= NC) return;
    float v0 = xclass[(size_t)c * 128 + lane], v1 = xclass[(size_t)c * 128 + 64 + lane];
    float p = wred(v0 * ac[lane] + v1 * ac[64 + lane]);
    if (lane == 0) {
        int hc = hclass[c];
        float z = LRELU(p + ehv[hc].w);
        zc[c] = z;
        atomicMax(&m3[hc], fenc(z));
    }
}

__global__ __launch_bounds__(256) void k_class2(const int* __restrict__ hclass,
                                                float* __restrict__ zc,
                                                const unsigned* __restrict__ m3,
                                                float* __restrict__ s3, int NC) {
    int c = blockIdx.x * 256 + threadIdx.x;
    if (c >= NC) return;
    int hc = hclass[c];
    float ex = expf(zc[c] - fdec(m3[hc]));
    zc[c] = ex;
    atomicAdd(&s3[hc], ex);
}

__global__ __launch_bounds__(256) void k_class3(
    const int* __restrict__ hclass, const float* __restrict__ zc,
    const float* __restrict__ s3, const float* __restrict__ xclass,
    float* __restrict__ xeh, int NC) {
    int lane = threadIdx.x & 63;
    int c = blockIdx.x * 4 + (threadIdx.x >> 6);
    if (c >= NC) return;
    int hc = hclass[c];
    float gama = zc[c] / (s3[hc] + 1e-16f);
    float v0 = xclass[(size_t)c * 128 + lane], v1 = xclass[(size_t)c * 128 + 64 + lane];
    atomicAdd(&xeh[(size_t)hc * 128 + lane], gama * v0);
    atomicAdd(&xeh[(size_t)hc * 128 + 64 + lane], gama * v1);
}

extern "C" void kernel_launch(void* const* d_in, const int* in_sizes, int n_in,
                              void* d_out, int out_size, void* d_ws, size_t ws_size,
                              hipStream_t stream) {
    (void)n_in; (void)out_size; (void)ws_size;
    const float* xe   = (const float*)d_in[0];
    const int*   eidx = (const int*)d_in[1];
    const int*   rel  = (const int*)d_in[2];
    const int*   tnum = (const int*)d_in[3];
    const float* remb = (const float*)d_in[4];
    const int*   cidx = (const int*)d_in[5];
    const int*   hcls = (const int*)d_in[6];
    const float* ah1  = (const float*)d_in[7];
    const float* ah2  = (const float*)d_in[8];
    const float* ah3  = (const float*)d_in[9];
    const float* ah4  = (const float*)d_in[10];
    const float* at1  = (const float*)d_in[11];
    const float* at2  = (const float*)d_in[12];
    const float* at3  = (const float*)d_in[13];
    const float* ar1  = (const float*)d_in[14];
    const float* ar2  = (const float*)d_in[15];
    const float* ac   = (const float*)d_in[16];
    const float* wh   = (const float*)d_in[17];
    const float* wt   = (const float*)d_in[18];
    const float* hww  = (const float*)d_in[19];
    const float* hwb  = (const float*)d_in[20];
    float* out = (float*)d_out;

    const int NE = in_sizes[0] / 256;
    const int E  = in_sizes[2];
    const int NR = in_sizes[4] / 128;
    const int NC = in_sizes[6];
    const int* hidx = eidx;
    const int* tidx = eidx + E;

    char* base = (char*)d_ws;
    size_t off0 = 0;
    auto alloc = [&](size_t bytes) -> char* {
        char* r = base + off0;
        off0 = (off0 + bytes + 255) & ~(size_t)255;
        return r;
    };
    float* xrh  = (float*)alloc((size_t)NE * 128 * 4);
    float* xrt  = (float*)alloc((size_t)NE * 128 * 4);
    float4* ehv = (float4*)alloc((size_t)NE * 16);
    float4* etv = (float4*)alloc((size_t)NE * 16);
    float2* erv = (float2*)alloc((size_t)NR * 8);
    float* zbuf  = (float*)alloc((size_t)E * 4);
    float* e2buf = (float*)alloc((size_t)E * 4);
    float* sbuf  = (float*)alloc((size_t)E * 4);
    float* e2s   = (float*)alloc((size_t)E * 4);
    float* ws    = (float*)alloc((size_t)E * 4);
    int*   gs    = (int*)alloc((size_t)E * 4);
    float* zc    = (float*)alloc((size_t)NC * 4);
    unsigned short* wtb_hi = (unsigned short*)alloc((size_t)256 * 256 * 2);
    unsigned short* wtb_lo = (unsigned short*)alloc((size_t)256 * 256 * 2);
    unsigned short* hwt_hi = (unsigned short*)alloc((size_t)128 * 128 * 2);
    unsigned short* hwt_lo = (unsigned short*)alloc((size_t)128 * 128 * 2);
    unsigned short* a_hi   = (unsigned short*)alloc((size_t)NE * 256 * 2);
    unsigned short* a_lo   = (unsigned short*)alloc((size_t)NE * 256 * 2);
    unsigned short* xrh_hi = (unsigned short*)alloc((size_t)NE * 128 * 2);
    unsigned short* xrt_hi = (unsigned short*)alloc((size_t)NE * 128 * 2);
    int* offb  = (int*)alloc((size_t)NC * 4);
    int* curb  = (int*)alloc((size_t)NC * 4);
    int* elist = (int*)alloc((size_t)E * 4);
    float* xclass = (float*)alloc((size_t)NC * 128 * 4);
    size_t zoff = off0;  // everything below is zero-initialized per launch
    unsigned* m1 = (unsigned*)alloc((size_t)NE * 4);
    float* s1    = (float*)alloc((size_t)NE * 4);
    unsigned* m3 = (unsigned*)alloc((size_t)NE * 4);
    float* s3    = (float*)alloc((size_t)NE * 4);
    int* cntb    = (int*)alloc((size_t)NC * 4);
    float* xeh   = (float*)alloc((size_t)NE * 128 * 4);
    size_t zbytes = off0 - zoff;

    hipMemsetAsync(base + zoff, 0, zbytes, stream);

    k_convW<<<(256 * 256 + 128 * 128 + 255) / 256, 256, 0, stream>>>(
        wh, wt, hww, wtb_hi, wtb_lo, hwt_hi, hwt_lo);
    long n8 = (long)NE * 256 / 8;
    k_convA<<<(int)((n8 + 255) / 256), 256, 0, stream>>>(xe, a_hi, a_lo, n8);
    k_rel<<<(NR + 3) / 4, 256, 0, stream>>>(remb, ar1, ar2, erv, NR);

    // projection GEMM (128x128 LDS-staged) with fused dots/norm + bf16 mirrors
    k_mm_proj<<<((NE + 127) / 128) * 2, 256, 0, stream>>>(
        a_hi, a_lo, wtb_hi, wtb_lo, xrh, xrt, xrh_hi, xrt_hi, NE,
        ah1, ah2, ah3, ah4, at1, at2, at3, ehv, etv);

    // class-CSR build (independent of edge kernels)
    k_hist<<<(E + 255) / 256, 256, 0, stream>>>(cidx, cntb, E);
    k_scan<<<1, 1024, 0, stream>>>(cntb, offb, curb, NC);
    k_scatter<<<(E + 255) / 256, 256, 0, stream>>>(cidx, curb, elist, E);

    k_edge1<<<(E + 255) / 256, 256, 0, stream>>>(hidx, tidx, rel, tnum, ehv, etv, erv, zbuf, m1, E);
    k_edge2<<<(E + 255) / 256, 256, 0, stream>>>(tnum, zbuf, m1, s1, E);
    k_edge3<<<(E + 255) / 256, 256, 0, stream>>>(hidx, tidx, rel, tnum, zbuf, s1,
                                                 ehv, etv, erv, sbuf, e2buf, E);
    k_prep<<<(E + 255) / 256, 256, 0, stream>>>(elist, tidx, e2buf, sbuf, e2s, ws, gs, E);
    k_spmm2<<<(NC + 3) / 4, 256, 0, stream>>>(offb, cntb, e2s, ws, gs,
                                              (const unsigned*)xrt_hi, xclass, NC);
    k_class1<<<(NC + 3) / 4, 256, 0, stream>>>(xclass, ac, ehv, hcls, zc, m3, NC);
    k_class2<<<(NC + 255) / 256, 256, 0, stream>>>(hcls, zc, m3, s3, NC);
    k_class3<<<(NC + 3) / 4, 256, 0, stream>>>(hcls, zc, s3, xclass, xeh, NC);

    k_mm_hw<<<(NE + 127) / 128, 256, 0, stream>>>(
        xrh_hi, hwt_hi, hwt_lo, out, xrh, hwb, xeh, NE);
}

// Round 10
// 498.943 us; speedup vs baseline: 1.3492x; 1.0921x over previous
//
#include <hip/hip_runtime.h>
#include <hip/hip_bf16.h>

#define LRELU(x) ((x) >= 0.f ? (x) : 0.01f * (x))

typedef __attribute__((ext_vector_type(8))) short short8v;
typedef __attribute__((ext_vector_type(4))) float f32x4;

__device__ inline unsigned fenc(float x) {
    unsigned u = __float_as_uint(x);
    return (u & 0x80000000u) ? ~u : (u | 0x80000000u);
}
__device__ inline float fdec(unsigned e) {
    return __uint_as_float((e & 0x80000000u) ? (e ^ 0x80000000u) : ~e);
}

__device__ inline float wred(float v) {
#pragma unroll
    for (int o = 32; o > 0; o >>= 1) v += __shfl_xor(v, o, 64);
    return v;
}
__device__ inline float wredmax(float v) {
#pragma unroll
    for (int o = 32; o > 0; o >>= 1) v = fmaxf(v, __shfl_xor(v, o, 64));
    return v;
}

__device__ inline unsigned short f2bu(float x) {
    __hip_bfloat16 b = __float2bfloat16(x);
    return *reinterpret_cast<unsigned short*>(&b);
}
__device__ inline float bu2f(unsigned short u) {
    return __uint_as_float((unsigned)u << 16);
}

__device__ inline f32x4 mfma16(short8v a, short8v b, f32x4 c) {
    return __builtin_amdgcn_mfma_f32_16x16x32_bf16(a, b, c, 0, 0, 0);
}

// async global->LDS, 16B per lane, dest = (wave-uniform base) + lane*16
__device__ inline void gload16(const void* g, void* l) {
    __builtin_amdgcn_global_load_lds(
        (const __attribute__((address_space(1))) void*)g,
        (__attribute__((address_space(3))) void*)l, 16, 0, 0);
}

// ---- convert W matrices to transposed hi/lo bf16: Wt[n][k] = W[k][n] ----
__global__ __launch_bounds__(256) void k_convW(
    const float* __restrict__ wh, const float* __restrict__ wt,
    const float* __restrict__ hww, unsigned short* __restrict__ wtb_hi,
    unsigned short* __restrict__ wtb_lo, unsigned short* __restrict__ hwt_hi,
    unsigned short* __restrict__ hwt_lo) {
    int id = blockIdx.x * 256 + threadIdx.x;
    if (id < 256 * 256) {
        int n = id >> 8, k = id & 255;
        float v = (n < 128) ? wh[(size_t)k * 128 + n] : wt[(size_t)k * 128 + (n - 128)];
        unsigned short h = f2bu(v);
        float r = v - bu2f(h);
        wtb_hi[(size_t)n * 256 + k] = h;
        wtb_lo[(size_t)n * 256 + k] = f2bu(r);
    } else {
        int id2 = id - 256 * 256;
        if (id2 < 128 * 128) {
            int n = id2 >> 7, k = id2 & 127;
            float v = hww[(size_t)k * 128 + n];
            unsigned short h = f2bu(v);
            float r = v - bu2f(h);
            hwt_hi[(size_t)n * 128 + k] = h;
            hwt_lo[(size_t)n * 128 + k] = f2bu(r);
        }
    }
}

// ---- convert A (x_e) to bf16 (hi only), row-major [NE][256] ----
__global__ __launch_bounds__(256) void k_convA(const float* __restrict__ x,
                                               unsigned short* __restrict__ hi,
                                               long n8) {
    long i = (long)blockIdx.x * 256 + threadIdx.x;
    if (i >= n8) return;
    const float4* xp = (const float4*)(x + i * 8);
    float4 a = xp[0], b = xp[1];
    float xs[8] = {a.x, a.y, a.z, a.w, b.x, b.y, b.z, b.w};
    short8v vh;
#pragma unroll
    for (int j = 0; j < 8; j++) vh[j] = (short)f2bu(xs[j]);
    *(short8v*)(hi + i * 8) = vh;
}

// ---- m97-style LDS-staged MFMA GEMM: A bf16, B split hi/lo, 2 mfma/cell ----
// Block 128x128, 4 waves in 2x2 quadrants, acc[4][4], BK=32, 2 barriers/step.
// EPI 0 (proj, KD=256): half0 -> o0=xrh f32 + oh0 bf16, dots->ehv;
//   half1 -> oh1 bf16 only, dots+norm->etv.
// EPI 1 (highway, KD=128): gate=sigmoid(C+bias); o0 = g*xeh + (1-g)*Af.
template <int EPI>
__device__ __forceinline__ void mm_body(
    const unsigned short* __restrict__ Ah,
    const unsigned short* __restrict__ Bh, const unsigned short* __restrict__ Bl,
    float* __restrict__ o0,
    unsigned short* __restrict__ oh0, unsigned short* __restrict__ oh1,
    const float* __restrict__ Af, const float* __restrict__ bias,
    const float* __restrict__ xeh, int M,
    const float* __restrict__ av1, const float* __restrict__ av2,
    const float* __restrict__ av3, const float* __restrict__ av4,
    const float* __restrict__ bv1, const float* __restrict__ bv2,
    const float* __restrict__ bv3,
    float4* __restrict__ ehv, float4* __restrict__ etv) {
    constexpr int KD = (EPI == 0) ? 256 : 128;
    constexpr int NSTEP = KD / 32;
    __shared__ unsigned short As_h[128 * 32];
    __shared__ unsigned short Bs_h[128 * 32];
    __shared__ unsigned short Bs_l[128 * 32];
    __shared__ float pd[(EPI == 0) ? 2 : 1][(EPI == 0) ? 128 : 1][4];

    int bx = blockIdx.x;
    int half = (EPI == 0) ? (bx & 1) : 0;
    int mblk = (EPI == 0) ? (bx >> 1) : bx;
    int row0 = mblk * 128;
    if (row0 + 128 > M) row0 = M - 128;
    int tid = threadIdx.x, w = tid >> 6, l = tid & 63;
    int qr = w >> 1, qc = w & 1;
    int lr = l & 15, hi4 = l >> 4;
    int srow = l >> 2, sslot = l & 3;

    f32x4 acc[4][4];
#pragma unroll
    for (int i = 0; i < 4; i++)
#pragma unroll
        for (int j = 0; j < 4; j++) acc[i][j] = (f32x4){0.f, 0.f, 0.f, 0.f};

    for (int s = 0; s < NSTEP; s++) {
        int k0 = s * 32;
        __syncthreads();
#pragma unroll
        for (int i = 0; i < 6; i++) {            // 24 units of 1KB, 6/wave
            int u = w * 6 + i;
            int arr = u >> 3, ld = u & 7;
            int row = ld * 16 + srow;
            int klog = (sslot ^ ((row >> 1) & 3)) * 8;
            const unsigned short* src;
            unsigned short* dst;
            if (arr == 0)      { src = Ah + (size_t)(row0 + row) * KD; dst = As_h; }
            else if (arr == 1) {
                src = Bh + (size_t)((EPI == 0 ? half * 128 : 0) + row) * KD;
                dst = Bs_h;
            } else {
                src = Bl + (size_t)((EPI == 0 ? half * 128 : 0) + row) * KD;
                dst = Bs_l;
            }
            gload16(src + k0 + klog, dst + ld * 512);
        }
        __syncthreads();

        short8v am_h[4], bn_h[4], bn_l[4];
#pragma unroll
        for (int mr = 0; mr < 4; mr++) {
            int r = qr * 64 + mr * 16 + lr;
            int ko = (hi4 ^ ((r >> 1) & 3)) * 8;
            am_h[mr] = *(const short8v*)&As_h[r * 32 + ko];
        }
#pragma unroll
        for (int nc = 0; nc < 4; nc++) {
            int n = qc * 64 + nc * 16 + lr;
            int ko = (hi4 ^ ((n >> 1) & 3)) * 8;
            bn_h[nc] = *(const short8v*)&Bs_h[n * 32 + ko];
            bn_l[nc] = *(const short8v*)&Bs_l[n * 32 + ko];
        }
#pragma unroll
        for (int mr = 0; mr < 4; mr++)
#pragma unroll
            for (int nc = 0; nc < 4; nc++) {
                acc[mr][nc] = mfma16(am_h[mr], bn_h[nc], acc[mr][nc]);
                acc[mr][nc] = mfma16(am_h[mr], bn_l[nc], acc[mr][nc]);
            }
    }

    if constexpr (EPI == 0) {
        unsigned short* OH = half ? oh1 : oh0;
        const float* v1 = half ? bv1 : av1;
        const float* v2 = half ? bv2 : av2;
        const float* v3 = half ? bv3 : av3;
#pragma unroll
        for (int mr = 0; mr < 4; mr++)
#pragma unroll
            for (int rr = 0; rr < 4; rr++) {
                int rl = qr * 64 + mr * 16 + hi4 * 4 + rr;
                int row = row0 + rl;
                float d0 = 0.f, d1 = 0.f, d2 = 0.f, d3 = 0.f;
#pragma unroll
                for (int nc = 0; nc < 4; nc++) {
                    float v = fmaxf(acc[mr][nc][rr], 0.f);
                    int col = qc * 64 + nc * 16 + lr;
                    if (half == 0) o0[(size_t)row * 128 + col] = v;
                    OH[(size_t)row * 128 + col] = f2bu(v);
                    d0 = fmaf(v, v1[col], d0);
                    d1 = fmaf(v, v2[col], d1);
                    d2 = fmaf(v, v3[col], d2);
                    d3 = fmaf(v, half ? v : av4[col], d3);
                }
#pragma unroll
                for (int o = 1; o <= 8; o <<= 1) {
                    d0 += __shfl_xor(d0, o, 64);
                    d1 += __shfl_xor(d1, o, 64);
                    d2 += __shfl_xor(d2, o, 64);
                    d3 += __shfl_xor(d3, o, 64);
                }
                if (lr == 0) {
                    pd[qc][rl][0] = d0; pd[qc][rl][1] = d1;
                    pd[qc][rl][2] = d2; pd[qc][rl][3] = d3;
                }
            }
        __syncthreads();
        if (qc == 0) {
#pragma unroll
            for (int mr = 0; mr < 4; mr++)
#pragma unroll
                for (int rr = 0; rr < 4; rr++) {
                    if (lr == 0) {
                        int rl = qr * 64 + mr * 16 + hi4 * 4 + rr;
                        int row = row0 + rl;
                        float s0 = pd[0][rl][0] + pd[1][rl][0];
                        float s1 = pd[0][rl][1] + pd[1][rl][1];
                        float s2 = pd[0][rl][2] + pd[1][rl][2];
                        float s3 = pd[0][rl][3] + pd[1][rl][3];
                        if (half == 0) ehv[row] = make_float4(s0, s1, s2, s3);
                        else           etv[row] = make_float4(s0, s1, s2, sqrtf(s3));
                    }
                }
        }
    } else {
#pragma unroll
        for (int mr = 0; mr < 4; mr++)
#pragma unroll
            for (int rr = 0; rr < 4; rr++) {
                int row = row0 + qr * 64 + mr * 16 + hi4 * 4 + rr;
#pragma unroll
                for (int nc = 0; nc < 4; nc++) {
                    int col = qc * 64 + nc * 16 + lr;
                    float a = acc[mr][nc][rr] + bias[col];
                    float g = 1.f / (1.f + expf(-a));
                    size_t o = (size_t)row * 128 + col;
                    o0[o] = g * xeh[o] + (1.f - g) * Af[o];
                }
            }
    }
}

__global__ __launch_bounds__(256) void k_mm_proj(
    const unsigned short* Ah, const unsigned short* Bh, const unsigned short* Bl,
    float* o0, unsigned short* oh0, unsigned short* oh1, int M,
    const float* av1, const float* av2, const float* av3, const float* av4,
    const float* bv1, const float* bv2, const float* bv3,
    float4* ehv, float4* etv) {
    mm_body<0>(Ah, Bh, Bl, o0, oh0, oh1, nullptr, nullptr, nullptr, M,
               av1, av2, av3, av4, bv1, bv2, bv3, ehv, etv);
}

__global__ __launch_bounds__(256) void k_mm_hw(
    const unsigned short* Ah, const unsigned short* Bh, const unsigned short* Bl,
    float* o0, const float* Af, const float* bias, const float* xeh, int M) {
    mm_body<1>(Ah, Bh, Bl, o0, nullptr, nullptr, Af, bias, xeh, M,
               nullptr, nullptr, nullptr, nullptr, nullptr, nullptr, nullptr,
               nullptr, nullptr);
}

// ---- relation dots -> packed float2 (er1, er2) ----
__global__ __launch_bounds__(256) void k_rel(const float* __restrict__ remb,
                                             const float* __restrict__ ar1,
                                             const float* __restrict__ ar2,
                                             float2* __restrict__ erv, int NR) {
    int lane = threadIdx.x & 63;
    int r = blockIdx.x * 4 + (threadIdx.x >> 6);
    if (r >= NR) return;
    float v0 = remb[(size_t)r * 128 + lane];
    float v1 = remb[(size_t)r * 128 + 64 + lane];
    float p1 = v0 * ar1[lane] + v1 * ar1[64 + lane];
    float p2 = v0 * ar2[lane] + v1 * ar2[64 + lane];
    p1 = wred(p1);
    p2 = wred(p2);
    if (lane == 0) erv[r] = make_float2(p1, p2);
}

// ---- level 1 softmax over triple_num segments ----
__global__ __launch_bounds__(256) void k_edge1(
    const int* __restrict__ hidx, const int* __restrict__ tidx,
    const int* __restrict__ rel, const int* __restrict__ tnum,
    const float4* __restrict__ ehv, const float4* __restrict__ etv,
    const float2* __restrict__ erv, float* __restrict__ zbuf,
    unsigned* __restrict__ m1, int E) {
    int i = blockIdx.x * 256 + threadIdx.x;
    if (i >= E) return;
    float e1 = 0.5f * (ehv[hidx[i]].x + etv[tidx[i]].x) + erv[rel[i]].x;
    float z = LRELU(e1);
    zbuf[i] = z;
    atomicMax(&m1[tnum[i]], fenc(z));
}

__global__ __launch_bounds__(256) void k_edge2(const int* __restrict__ tnum,
                                               float* __restrict__ zbuf,
                                               const unsigned* __restrict__ m1,
                                               float* __restrict__ s1, int E) {
    int i = blockIdx.x * 256 + threadIdx.x;
    if (i >= E) return;
    int tn = tnum[i];
    float ex = expf(zbuf[i] - fdec(m1[tn]));
    zbuf[i] = ex;
    atomicAdd(&s1[tn], ex);
}

// ---- alpha -> per-edge scale s, level-2 logit z2 (no atomics) ----
__global__ __launch_bounds__(256) void k_edge3(
    const int* __restrict__ hidx, const int* __restrict__ tidx,
    const int* __restrict__ rel, const int* __restrict__ tnum,
    const float* __restrict__ zbuf, const float* __restrict__ s1,
    const float4* __restrict__ ehv, const float4* __restrict__ etv,
    const float2* __restrict__ erv, float* __restrict__ sbuf,
    float* __restrict__ e2buf, int E) {
    int i = blockIdx.x * 256 + threadIdx.x;
    if (i >= E) return;
    float alpha = zbuf[i] / (s1[tnum[i]] + 1e-16f);
    int t = tidx[i];
    float4 ev = etv[t];
    float4 hv = ehv[hidx[i]];
    float s = alpha / fmaxf(alpha * ev.w, 1e-12f);
    sbuf[i] = s;
    float z2 = s * ev.y + hv.y + 0.5f * (erv[rel[i]].y + 0.5f * (hv.z + s * ev.z));
    e2buf[i] = LRELU(z2);
}

// ---- counting sort by class_index ----
__global__ __launch_bounds__(256) void k_hist(const int* __restrict__ cidx,
                                              int* __restrict__ cnt, int E) {
    int i = blockIdx.x * 256 + threadIdx.x;
    if (i >= E) return;
    atomicAdd(&cnt[cidx[i]], 1);
}

__global__ __launch_bounds__(1024) void k_scan(const int* __restrict__ cnt,
                                               int* __restrict__ off,
                                               int* __restrict__ cur, int NC) {
    __shared__ int wt[16];
    __shared__ int sbase;
    int tid = threadIdx.x, w = tid >> 6, lane = tid & 63;
    if (tid == 0) sbase = 0;
    __syncthreads();
    for (int c0 = 0; c0 < NC; c0 += 1024) {
        int c = c0 + tid;
        int v = (c < NC) ? cnt[c] : 0;
        int x = v;
#pragma unroll
        for (int o = 1; o < 64; o <<= 1) {
            int t = __shfl_up(x, o, 64);
            if (lane >= o) x += t;
        }
        if (lane == 63) wt[w] = x;
        __syncthreads();
        int pre = 0, tot = 0;
#pragma unroll
        for (int i = 0; i < 16; i++) {
            int t = wt[i];
            tot += t;
            if (i < w) pre += t;
        }
        int excl = sbase + pre + x - v;
        if (c < NC) { off[c] = excl; cur[c] = excl; }
        __syncthreads();
        if (tid == 0) sbase += tot;
        __syncthreads();
    }
}

// ---- scatter edges to class-sorted order, fused scalar gather (ex-k_prep) ----
__global__ __launch_bounds__(256) void k_scatter(
    const int* __restrict__ cidx, int* __restrict__ cur,
    const int* __restrict__ tidx, const float* __restrict__ e2buf,
    const float* __restrict__ sbuf, float* __restrict__ e2s,
    float* __restrict__ ws, int* __restrict__ gs, int E) {
    int i = blockIdx.x * 256 + threadIdx.x;
    if (i >= E) return;
    int pos = atomicAdd(&cur[cidx[i]], 1);
    e2s[pos] = e2buf[i];
    int te = tidx[i];
    ws[pos] = sbuf[te];
    gs[pos] = tidx[te];
}

// ---- fused level-2 softmax + spmm + class-dot (ex-k_class1) ----
__global__ __launch_bounds__(256) void k_spmm2(
    const int* __restrict__ off, const int* __restrict__ cnt,
    const float* __restrict__ e2s, const float* __restrict__ ws,
    const int* __restrict__ gs, const unsigned* __restrict__ xrt_b,
    float* __restrict__ xclass, const float* __restrict__ ac,
    const float4* __restrict__ ehv, const int* __restrict__ hclass,
    float* __restrict__ zc, unsigned* __restrict__ m3, int NC) {
    int lane = threadIdx.x & 63;
    int c = blockIdx.x * 4 + (threadIdx.x >> 6);
    if (c >= NC) return;
    int n = cnt[c];
    float a0 = 0.f, a1 = 0.f;
    if (n > 0) {
        int base = off[c];
        float m = -3.4e38f, s = 0.f;
        for (int j = lane; j < n; j += 64) {
            float z = e2s[base + j];
            if (z > m) { s = s * __expf(m - z) + 1.f; m = z; }
            else s += __expf(z - m);
        }
        float M = wredmax(m);
        s = wred(s * __expf(m - M));
        float inv = 1.f / (s + 1e-16f);
        for (int j0 = 0; j0 < n; j0 += 64) {
            int lim = n - j0;
            if (lim > 64) lim = 64;
            float wv = 0.f;
            int g = 0;
            if (lane < lim) {
                int p = base + j0 + lane;
                wv = __expf(e2s[p] - M) * inv * ws[p];
                g = gs[p];
            }
            int jj = 0;
            for (; jj + 8 <= lim; jj += 8) {  // 8 rows in flight, 256B each
                float w0 = __shfl(wv, jj + 0), w1 = __shfl(wv, jj + 1);
                float w2 = __shfl(wv, jj + 2), w3 = __shfl(wv, jj + 3);
                float w4 = __shfl(wv, jj + 4), w5 = __shfl(wv, jj + 5);
                float w6 = __shfl(wv, jj + 6), w7 = __shfl(wv, jj + 7);
                unsigned u0 = xrt_b[(size_t)__shfl(g, jj + 0) * 64 + lane];
                unsigned u1 = xrt_b[(size_t)__shfl(g, jj + 1) * 64 + lane];
                unsigned u2 = xrt_b[(size_t)__shfl(g, jj + 2) * 64 + lane];
                unsigned u3 = xrt_b[(size_t)__shfl(g, jj + 3) * 64 + lane];
                unsigned u4 = xrt_b[(size_t)__shfl(g, jj + 4) * 64 + lane];
                unsigned u5 = xrt_b[(size_t)__shfl(g, jj + 5) * 64 + lane];
                unsigned u6 = xrt_b[(size_t)__shfl(g, jj + 6) * 64 + lane];
                unsigned u7 = xrt_b[(size_t)__shfl(g, jj + 7) * 64 + lane];
                a0 = fmaf(w0, bu2f((unsigned short)(u0 & 0xffff)), a0);
                a1 = fmaf(w0, bu2f((unsigned short)(u0 >> 16)), a1);
                a0 = fmaf(w1, bu2f((unsigned short)(u1 & 0xffff)), a0);
                a1 = fmaf(w1, bu2f((unsigned short)(u1 >> 16)), a1);
                a0 = fmaf(w2, bu2f((unsigned short)(u2 & 0xffff)), a0);
                a1 = fmaf(w2, bu2f((unsigned short)(u2 >> 16)), a1);
                a0 = fmaf(w3, bu2f((unsigned short)(u3 & 0xffff)), a0);
                a1 = fmaf(w3, bu2f((unsigned short)(u3 >> 16)), a1);
                a0 = fmaf(w4, bu2f((unsigned short)(u4 & 0xffff)), a0);
                a1 = fmaf(w4, bu2f((unsigned short)(u4 >> 16)), a1);
                a0 = fmaf(w5, bu2f((unsigned short)(u5 & 0xffff)), a0);
                a1 = fmaf(w5, bu2f((unsigned short)(u5 >> 16)), a1);
                a0 = fmaf(w6, bu2f((unsigned short)(u6 & 0xffff)), a0);
                a1 = fmaf(w6, bu2f((unsigned short)(u6 >> 16)), a1);
                a0 = fmaf(w7, bu2f((unsigned short)(u7 & 0xffff)), a0);
                a1 = fmaf(w7, bu2f((unsigned short)(u7 >> 16)), a1);
            }
            for (; jj < lim; jj++) {
                float wj = __shfl(wv, jj);
                unsigned u = xrt_b[(size_t)__shfl(g, jj) * 64 + lane];
                a0 = fmaf(wj, bu2f((unsigned short)(u & 0xffff)), a0);
                a1 = fmaf(wj, bu2f((unsigned short)(u >> 16)), a1);
            }
        }
    }
    *(float2*)&xclass[(size_t)c * 128 + 2 * lane] = make_float2(a0, a1);
    // fused class-level dot (ex-k_class1): e_c = xclass[c]·ac + eh4[hclass[c]]
    float p = wred(a0 * ac[2 * lane] + a1 * ac[2 * lane + 1]);
    if (lane == 0) {
        int hc = hclass[c];
        float z = LRELU(p + ehv[hc].w);
        zc[c] = z;
        atomicMax(&m3[hc], fenc(z));
    }
}

// ---- level 3: class -> head entity ----
__global__ __launch_bounds__(256) void k_class2(const int* __restrict__ hclass,
                                                float* __restrict__ zc,
                                                const unsigned* __restrict__ m3,
                                                float* __restrict__ s3, int NC) {
    int c = blockIdx.x * 256 + threadIdx.x;
    if (c >= NC) return;
    int hc = hclass[c];
    float ex = expf(zc[c] - fdec(m3[hc]));
    zc[c] = ex;
    atomicAdd(&s3[hc], ex);
}

__global__ __launch_bounds__(256) void k_class3(
    const int* __restrict__ hclass, const float* __restrict__ zc,
    const float* __restrict__ s3, const float* __restrict__ xclass,
    float* __restrict__ xeh, int NC) {
    int lane = threadIdx.x & 63;
    int c = blockIdx.x * 4 + (threadIdx.x >> 6);
    if (c >= NC) return;
    int hc = hclass[c];
    float gama = zc[c] / (s3[hc] + 1e-16f);
    float v0 = xclass[(size_t)c * 128 + lane], v1 = xclass[(size_t)c * 128 + 64 + lane];
    atomicAdd(&xeh[(size_t)hc * 128 + lane], gama * v0);
    atomicAdd(&xeh[(size_t)hc * 128 + 64 + lane], gama * v1);
}

extern "C" void kernel_launch(void* const* d_in, const int* in_sizes, int n_in,
                              void* d_out, int out_size, void* d_ws, size_t ws_size,
                              hipStream_t stream) {
    (void)n_in; (void)out_size; (void)ws_size;
    const float* xe   = (const float*)d_in[0];
    const int*   eidx = (const int*)d_in[1];
    const int*   rel  = (const int*)d_in[2];
    const int*   tnum = (const int*)d_in[3];
    const float* remb = (const float*)d_in[4];
    const int*   cidx = (const int*)d_in[5];
    const int*   hcls = (const int*)d_in[6];
    const float* ah1  = (const float*)d_in[7];
    const float* ah2  = (const float*)d_in[8];
    const float* ah3  = (const float*)d_in[9];
    const float* ah4  = (const float*)d_in[10];
    const float* at1  = (const float*)d_in[11];
    const float* at2  = (const float*)d_in[12];
    const float* at3  = (const float*)d_in[13];
    const float* ar1  = (const float*)d_in[14];
    const float* ar2  = (const float*)d_in[15];
    const float* ac   = (const float*)d_in[16];
    const float* wh   = (const float*)d_in[17];
    const float* wt   = (const float*)d_in[18];
    const float* hww  = (const float*)d_in[19];
    const float* hwb  = (const float*)d_in[20];
    float* out = (float*)d_out;

    const int NE = in_sizes[0] / 256;
    const int E  = in_sizes[2];
    const int NR = in_sizes[4] / 128;
    const int NC = in_sizes[6];
    const int* hidx = eidx;
    const int* tidx = eidx + E;

    char* base = (char*)d_ws;
    size_t off0 = 0;
    auto alloc = [&](size_t bytes) -> char* {
        char* r = base + off0;
        off0 = (off0 + bytes + 255) & ~(size_t)255;
        return r;
    };
    float* xrh  = (float*)alloc((size_t)NE * 128 * 4);
    float4* ehv = (float4*)alloc((size_t)NE * 16);
    float4* etv = (float4*)alloc((size_t)NE * 16);
    float2* erv = (float2*)alloc((size_t)NR * 8);
    float* zbuf  = (float*)alloc((size_t)E * 4);
    float* e2buf = (float*)alloc((size_t)E * 4);
    float* sbuf  = (float*)alloc((size_t)E * 4);
    float* e2s   = (float*)alloc((size_t)E * 4);
    float* ws    = (float*)alloc((size_t)E * 4);
    int*   gs    = (int*)alloc((size_t)E * 4);
    float* zc    = (float*)alloc((size_t)NC * 4);
    unsigned short* wtb_hi = (unsigned short*)alloc((size_t)256 * 256 * 2);
    unsigned short* wtb_lo = (unsigned short*)alloc((size_t)256 * 256 * 2);
    unsigned short* hwt_hi = (unsigned short*)alloc((size_t)128 * 128 * 2);
    unsigned short* hwt_lo = (unsigned short*)alloc((size_t)128 * 128 * 2);
    unsigned short* a_hi   = (unsigned short*)alloc((size_t)NE * 256 * 2);
    unsigned short* xrh_hi = (unsigned short*)alloc((size_t)NE * 128 * 2);
    unsigned short* xrt_hi = (unsigned short*)alloc((size_t)NE * 128 * 2);
    int* offb  = (int*)alloc((size_t)NC * 4);
    int* curb  = (int*)alloc((size_t)NC * 4);
    float* xclass = (float*)alloc((size_t)NC * 128 * 4);
    size_t zoff = off0;  // everything below is zero-initialized per launch
    unsigned* m1 = (unsigned*)alloc((size_t)NE * 4);
    float* s1    = (float*)alloc((size_t)NE * 4);
    unsigned* m3 = (unsigned*)alloc((size_t)NE * 4);
    float* s3    = (float*)alloc((size_t)NE * 4);
    int* cntb    = (int*)alloc((size_t)NC * 4);
    float* xeh   = (float*)alloc((size_t)NE * 128 * 4);
    size_t zbytes = off0 - zoff;

    hipMemsetAsync(base + zoff, 0, zbytes, stream);

    k_convW<<<(256 * 256 + 128 * 128 + 255) / 256, 256, 0, stream>>>(
        wh, wt, hww, wtb_hi, wtb_lo, hwt_hi, hwt_lo);
    long n8 = (long)NE * 256 / 8;
    k_convA<<<(int)((n8 + 255) / 256), 256, 0, stream>>>(xe, a_hi, n8);
    k_rel<<<(NR + 3) / 4, 256, 0, stream>>>(remb, ar1, ar2, erv, NR);

    // projection GEMM (128x128 LDS-staged) with fused dots/norm + bf16 mirrors
    k_mm_proj<<<((NE + 127) / 128) * 2, 256, 0, stream>>>(
        a_hi, wtb_hi, wtb_lo, xrh, xrh_hi, xrt_hi, NE,
        ah1, ah2, ah3, ah4, at1, at2, at3, ehv, etv);

    // class-CSR histogram/scan (independent of edge kernels)
    k_hist<<<(E + 255) / 256, 256, 0, stream>>>(cidx, cntb, E);
    k_scan<<<1, 1024, 0, stream>>>(cntb, offb, curb, NC);

    k_edge1<<<(E + 255) / 256, 256, 0, stream>>>(hidx, tidx, rel, tnum, ehv, etv, erv, zbuf, m1, E);
    k_edge2<<<(E + 255) / 256, 256, 0, stream>>>(tnum, zbuf, m1, s1, E);
    k_edge3<<<(E + 255) / 256, 256, 0, stream>>>(hidx, tidx, rel, tnum, zbuf, s1,
                                                 ehv, etv, erv, sbuf, e2buf, E);
    // scatter with fused scalar gathers (ex-k_prep)
    k_scatter<<<(E + 255) / 256, 256, 0, stream>>>(cidx, curb, tidx, e2buf, sbuf,
                                                   e2s, ws, gs, E);
    k_spmm2<<<(NC + 3) / 4, 256, 0, stream>>>(offb, cntb, e2s, ws, gs,
                                              (const unsigned*)xrt_hi, xclass,
                                              ac, ehv, hcls, zc, m3, NC);
    k_class2<<<(NC + 255) / 256, 256, 0, stream>>>(hcls, zc, m3, s3, NC);
    k_class3<<<(NC + 3) / 4, 256, 0, stream>>>(hcls, zc, s3, xclass, xeh, NC);

    k_mm_hw<<<(NE + 127) / 128, 256, 0, stream>>>(
        xrh_hi, hwt_hi, hwt_lo, out, xrh, hwb, xeh, NE);
}

// Round 11
// 403.560 us; speedup vs baseline: 1.6681x; 1.2364x over previous
//
#include <hip/hip_runtime.h>
#include <hip/hip_bf16.h>

#define LRELU(x) ((x) >= 0.f ? (x) : 0.01f * (x))

typedef __attribute__((ext_vector_type(8))) short short8v;
typedef __attribute__((ext_vector_type(4))) float f32x4;

__device__ inline unsigned fenc(float x) {
    unsigned u = __float_as_uint(x);
    return (u & 0x80000000u) ? ~u : (u | 0x80000000u);
}
__device__ inline float fdec(unsigned e) {
    return __uint_as_float((e & 0x80000000u) ? (e ^ 0x80000000u) : ~e);
}

__device__ inline float wred(float v) {
#pragma unroll
    for (int o = 32; o > 0; o >>= 1) v += __shfl_xor(v, o, 64);
    return v;
}
__device__ inline float wredmax(float v) {
#pragma unroll
    for (int o = 32; o > 0; o >>= 1) v = fmaxf(v, __shfl_xor(v, o, 64));
    return v;
}

__device__ inline unsigned short f2bu(float x) {
    __hip_bfloat16 b = __float2bfloat16(x);
    return *reinterpret_cast<unsigned short*>(&b);
}
__device__ inline float bu2f(unsigned short u) {
    return __uint_as_float((unsigned)u << 16);
}

__device__ inline f32x4 mfma16(short8v a, short8v b, f32x4 c) {
    return __builtin_amdgcn_mfma_f32_16x16x32_bf16(a, b, c, 0, 0, 0);
}

// async global->LDS, 16B per lane, dest = (wave-uniform base) + lane*16
__device__ inline void gload16(const void* g, void* l) {
    __builtin_amdgcn_global_load_lds(
        (const __attribute__((address_space(1))) void*)g,
        (__attribute__((address_space(3))) void*)l, 16, 0, 0);
}

// ---- convert W matrices to transposed hi/lo bf16: Wt[n][k] = W[k][n] ----
__global__ __launch_bounds__(256) void k_convW(
    const float* __restrict__ wh, const float* __restrict__ wt,
    const float* __restrict__ hww, unsigned short* __restrict__ wtb_hi,
    unsigned short* __restrict__ wtb_lo, unsigned short* __restrict__ hwt_hi,
    unsigned short* __restrict__ hwt_lo) {
    int id = blockIdx.x * 256 + threadIdx.x;
    if (id < 256 * 256) {
        int n = id >> 8, k = id & 255;
        float v = (n < 128) ? wh[(size_t)k * 128 + n] : wt[(size_t)k * 128 + (n - 128)];
        unsigned short h = f2bu(v);
        float r = v - bu2f(h);
        wtb_hi[(size_t)n * 256 + k] = h;
        wtb_lo[(size_t)n * 256 + k] = f2bu(r);
    } else {
        int id2 = id - 256 * 256;
        if (id2 < 128 * 128) {
            int n = id2 >> 7, k = id2 & 127;
            float v = hww[(size_t)k * 128 + n];
            unsigned short h = f2bu(v);
            float r = v - bu2f(h);
            hwt_hi[(size_t)n * 128 + k] = h;
            hwt_lo[(size_t)n * 128 + k] = f2bu(r);
        }
    }
}

// ---- convert A (x_e) to bf16, row-major [NE][256] ----
__global__ __launch_bounds__(256) void k_convA(const float* __restrict__ x,
                                               unsigned short* __restrict__ hi,
                                               long n8) {
    long i = (long)blockIdx.x * 256 + threadIdx.x;
    if (i >= n8) return;
    const float4* xp = (const float4*)(x + i * 8);
    float4 a = xp[0], b = xp[1];
    float xs[8] = {a.x, a.y, a.z, a.w, b.x, b.y, b.z, b.w};
    short8v vh;
#pragma unroll
    for (int j = 0; j < 8; j++) vh[j] = (short)f2bu(xs[j]);
    *(short8v*)(hi + i * 8) = vh;
}

// ---- relation dot: er2[r] = r_emb[r]·a_r2  (a_r1 path is dead code) ----
__global__ __launch_bounds__(256) void k_rel(const float* __restrict__ remb,
                                             const float* __restrict__ ar2,
                                             float* __restrict__ er2, int NR) {
    int lane = threadIdx.x & 63;
    int r = blockIdx.x * 4 + (threadIdx.x >> 6);
    if (r >= NR) return;
    float v0 = remb[(size_t)r * 128 + lane];
    float v1 = remb[(size_t)r * 128 + 64 + lane];
    float p2 = wred(v0 * ar2[lane] + v1 * ar2[64 + lane]);
    if (lane == 0) er2[r] = p2;
}

// ---- m97-style LDS-staged MFMA GEMM: A bf16, B split hi/lo, 2 mfma/cell ----
// Block 128x128, 4 waves in 2x2 quadrants, acc[4][4], BK=32.
// EPI 0 (proj, KD=256):
//   half0 -> oh0 = bf16(relu(x_e@w_h)); hb[row]=eh2+.25*eh3; eh4o[row]=eh4.
//   half1 -> oh1 = bf16(relu(x_e@w_t)/max(nrm,1e-12)) [pre-normalized];
//            ta[row]=(et2+.25*et3)/max(nrm,1e-12).
// EPI 1 (highway, KD=128): gate=sigmoid(C+bias); o0 = g*xeh + (1-g)*bf16(A).
template <int EPI>
__device__ __forceinline__ void mm_body(
    const unsigned short* __restrict__ Ah,
    const unsigned short* __restrict__ Bh, const unsigned short* __restrict__ Bl,
    unsigned short* __restrict__ oh0, unsigned short* __restrict__ oh1,
    float* __restrict__ o0, const float* __restrict__ bias,
    const float* __restrict__ xeh, int M,
    const float* __restrict__ ah2, const float* __restrict__ ah3,
    const float* __restrict__ ah4, const float* __restrict__ at2,
    const float* __restrict__ at3,
    float* __restrict__ hb, float* __restrict__ eh4o, float* __restrict__ ta) {
    constexpr int KD = (EPI == 0) ? 256 : 128;
    constexpr int NSTEP = KD / 32;
    __shared__ unsigned short As_h[128 * 32];
    __shared__ unsigned short Bs_h[128 * 32];
    __shared__ unsigned short Bs_l[128 * 32];
    __shared__ float pd[(EPI == 0) ? 2 : 1][(EPI == 0) ? 128 : 1][4];

    int bx = blockIdx.x;
    int half = (EPI == 0) ? (bx & 1) : 0;
    int mblk = (EPI == 0) ? (bx >> 1) : bx;
    int row0 = mblk * 128;
    if (row0 + 128 > M) row0 = M - 128;
    int tid = threadIdx.x, w = tid >> 6, l = tid & 63;
    int qr = w >> 1, qc = w & 1;
    int lr = l & 15, hi4 = l >> 4;
    int srow = l >> 2, sslot = l & 3;

    f32x4 acc[4][4];
#pragma unroll
    for (int i = 0; i < 4; i++)
#pragma unroll
        for (int j = 0; j < 4; j++) acc[i][j] = (f32x4){0.f, 0.f, 0.f, 0.f};

    for (int s = 0; s < NSTEP; s++) {
        int k0 = s * 32;
        __syncthreads();
#pragma unroll
        for (int i = 0; i < 6; i++) {            // 24 units of 1KB, 6/wave
            int u = w * 6 + i;
            int arr = u >> 3, ld = u & 7;
            int row = ld * 16 + srow;
            int klog = (sslot ^ ((row >> 1) & 3)) * 8;
            const unsigned short* src;
            unsigned short* dst;
            if (arr == 0)      { src = Ah + (size_t)(row0 + row) * KD; dst = As_h; }
            else if (arr == 1) {
                src = Bh + (size_t)((EPI == 0 ? half * 128 : 0) + row) * KD;
                dst = Bs_h;
            } else {
                src = Bl + (size_t)((EPI == 0 ? half * 128 : 0) + row) * KD;
                dst = Bs_l;
            }
            gload16(src + k0 + klog, dst + ld * 512);
        }
        __syncthreads();

        short8v am_h[4], bn_h[4], bn_l[4];
#pragma unroll
        for (int mr = 0; mr < 4; mr++) {
            int r = qr * 64 + mr * 16 + lr;
            int ko = (hi4 ^ ((r >> 1) & 3)) * 8;
            am_h[mr] = *(const short8v*)&As_h[r * 32 + ko];
        }
#pragma unroll
        for (int nc = 0; nc < 4; nc++) {
            int n = qc * 64 + nc * 16 + lr;
            int ko = (hi4 ^ ((n >> 1) & 3)) * 8;
            bn_h[nc] = *(const short8v*)&Bs_h[n * 32 + ko];
            bn_l[nc] = *(const short8v*)&Bs_l[n * 32 + ko];
        }
#pragma unroll
        for (int mr = 0; mr < 4; mr++)
#pragma unroll
            for (int nc = 0; nc < 4; nc++) {
                acc[mr][nc] = mfma16(am_h[mr], bn_h[nc], acc[mr][nc]);
                acc[mr][nc] = mfma16(am_h[mr], bn_l[nc], acc[mr][nc]);
            }
    }

    if constexpr (EPI == 0) {
        const float* v1 = half ? at2 : ah2;
        const float* v2 = half ? at3 : ah3;
        // pass A: dots (and, for half0, the bf16 store)
#pragma unroll
        for (int mr = 0; mr < 4; mr++)
#pragma unroll
            for (int rr = 0; rr < 4; rr++) {
                int rl = qr * 64 + mr * 16 + hi4 * 4 + rr;
                int row = row0 + rl;
                float d0 = 0.f, d1 = 0.f, d2 = 0.f;
#pragma unroll
                for (int nc = 0; nc < 4; nc++) {
                    float v = fmaxf(acc[mr][nc][rr], 0.f);
                    int col = qc * 64 + nc * 16 + lr;
                    if (half == 0) oh0[(size_t)row * 128 + col] = f2bu(v);
                    d0 = fmaf(v, v1[col], d0);
                    d1 = fmaf(v, v2[col], d1);
                    d2 = half ? fmaf(v, v, d2) : fmaf(v, ah4[col], d2);
                }
#pragma unroll
                for (int o = 1; o <= 8; o <<= 1) {
                    d0 += __shfl_xor(d0, o, 64);
                    d1 += __shfl_xor(d1, o, 64);
                    d2 += __shfl_xor(d2, o, 64);
                }
                if (lr == 0) {
                    pd[qc][rl][0] = d0; pd[qc][rl][1] = d1; pd[qc][rl][2] = d2;
                }
            }
        __syncthreads();
        if (half == 0) {
            if (qc == 0 && lr == 0) {
#pragma unroll
                for (int mr = 0; mr < 4; mr++)
#pragma unroll
                    for (int rr = 0; rr < 4; rr++) {
                        int rl = qr * 64 + mr * 16 + hi4 * 4 + rr;
                        int row = row0 + rl;
                        float s0 = pd[0][rl][0] + pd[1][rl][0];
                        float s1 = pd[0][rl][1] + pd[1][rl][1];
                        float s2 = pd[0][rl][2] + pd[1][rl][2];
                        hb[row] = s0 + 0.25f * s1;
                        eh4o[row] = s2;
                    }
            }
        } else {
            // pass B: normalized bf16 store + ta
#pragma unroll
            for (int mr = 0; mr < 4; mr++)
#pragma unroll
                for (int rr = 0; rr < 4; rr++) {
                    int rl = qr * 64 + mr * 16 + hi4 * 4 + rr;
                    int row = row0 + rl;
                    float n2 = pd[0][rl][2] + pd[1][rl][2];
                    float inv = 1.f / fmaxf(sqrtf(n2), 1e-12f);
#pragma unroll
                    for (int nc = 0; nc < 4; nc++) {
                        float v = fmaxf(acc[mr][nc][rr], 0.f);
                        int col = qc * 64 + nc * 16 + lr;
                        oh1[(size_t)row * 128 + col] = f2bu(v * inv);
                    }
                    if (qc == 0 && lr == 0) {
                        float s0 = pd[0][rl][0] + pd[1][rl][0];
                        float s1 = pd[0][rl][1] + pd[1][rl][1];
                        ta[row] = (s0 + 0.25f * s1) * inv;
                    }
                }
        }
    } else {
#pragma unroll
        for (int mr = 0; mr < 4; mr++)
#pragma unroll
            for (int rr = 0; rr < 4; rr++) {
                int row = row0 + qr * 64 + mr * 16 + hi4 * 4 + rr;
#pragma unroll
                for (int nc = 0; nc < 4; nc++) {
                    int col = qc * 64 + nc * 16 + lr;
                    float a = acc[mr][nc][rr] + bias[col];
                    float g = 1.f / (1.f + expf(-a));
                    size_t o = (size_t)row * 128 + col;
                    float af = bu2f(Ah[o]);
                    o0[o] = g * xeh[o] + (1.f - g) * af;
                }
            }
    }
}

__global__ __launch_bounds__(256) void k_mm_proj(
    const unsigned short* Ah, const unsigned short* Bh, const unsigned short* Bl,
    unsigned short* oh0, unsigned short* oh1, int M,
    const float* ah2, const float* ah3, const float* ah4,
    const float* at2, const float* at3,
    float* hb, float* eh4o, float* ta) {
    mm_body<0>(Ah, Bh, Bl, oh0, oh1, nullptr, nullptr, nullptr, M,
               ah2, ah3, ah4, at2, at3, hb, eh4o, ta);
}

__global__ __launch_bounds__(256) void k_mm_hw(
    const unsigned short* Ah, const unsigned short* Bh, const unsigned short* Bl,
    float* o0, const float* bias, const float* xeh, int M) {
    mm_body<1>(Ah, Bh, Bl, nullptr, nullptr, o0, bias, xeh, M,
               nullptr, nullptr, nullptr, nullptr, nullptr,
               nullptr, nullptr, nullptr);
}

// ---- counting sort by class_index ----
__global__ __launch_bounds__(256) void k_hist(const int* __restrict__ cidx,
                                              int* __restrict__ cnt, int E) {
    int i = blockIdx.x * 256 + threadIdx.x;
    if (i >= E) return;
    atomicAdd(&cnt[cidx[i]], 1);
}

__global__ __launch_bounds__(1024) void k_scan(const int* __restrict__ cnt,
                                               int* __restrict__ off,
                                               int* __restrict__ cur, int NC) {
    __shared__ int wt[16];
    __shared__ int sbase;
    int tid = threadIdx.x, w = tid >> 6, lane = tid & 63;
    if (tid == 0) sbase = 0;
    __syncthreads();
    for (int c0 = 0; c0 < NC; c0 += 1024) {
        int c = c0 + tid;
        int v = (c < NC) ? cnt[c] : 0;
        int x = v;
#pragma unroll
        for (int o = 1; o < 64; o <<= 1) {
            int t = __shfl_up(x, o, 64);
            if (lane >= o) x += t;
        }
        if (lane == 63) wt[w] = x;
        __syncthreads();
        int pre = 0, tot = 0;
#pragma unroll
        for (int i = 0; i < 16; i++) {
            int t = wt[i];
            tot += t;
            if (i < w) pre += t;
        }
        int excl = sbase + pre + x - v;
        if (c < NC) { off[c] = excl; cur[c] = excl; }
        __syncthreads();
        if (tid == 0) sbase += tot;
        __syncthreads();
    }
}

// ---- fused level-2 logit + scatter to class-sorted order ----
// z2 = lrelu(ta[t] + hb[h] + 0.5*er2[rel]);  g = tidx[tidx[i]]
__global__ __launch_bounds__(256) void k_edgescatter(
    const int* __restrict__ cidx, int* __restrict__ cur,
    const int* __restrict__ hidx, const int* __restrict__ tidx,
    const int* __restrict__ rel, const float* __restrict__ ta,
    const float* __restrict__ hb, const float* __restrict__ er2,
    float* __restrict__ e2s, int* __restrict__ gs, int E) {
    int i = blockIdx.x * 256 + threadIdx.x;
    if (i >= E) return;
    int pos = atomicAdd(&cur[cidx[i]], 1);
    int te = tidx[i];
    int g = tidx[te];
    float z2 = ta[te] + hb[hidx[i]] + 0.5f * er2[rel[i]];
    e2s[pos] = LRELU(z2);
    gs[pos] = g;
}

// ---- fused level-2 softmax + spmm + class-dot, one wave/class ----
// rows gathered from PRE-NORMALIZED bf16 xrtn; no per-edge weight needed.
__global__ __launch_bounds__(256) void k_spmm2(
    const int* __restrict__ off, const int* __restrict__ cnt,
    const float* __restrict__ e2s, const int* __restrict__ gs,
    const unsigned* __restrict__ xrtn_b, float* __restrict__ xclass,
    const float* __restrict__ ac, const float* __restrict__ eh4,
    const int* __restrict__ hclass, float* __restrict__ zc,
    unsigned* __restrict__ m3, int NC) {
    int lane = threadIdx.x & 63;
    int c = blockIdx.x * 4 + (threadIdx.x >> 6);
    if (c >= NC) return;
    int n = cnt[c];
    float a0 = 0.f, a1 = 0.f;
    if (n > 0) {
        int base = off[c];
        float m = -3.4e38f, s = 0.f;
        for (int j = lane; j < n; j += 64) {
            float z = e2s[base + j];
            if (z > m) { s = s * __expf(m - z) + 1.f; m = z; }
            else s += __expf(z - m);
        }
        float M = wredmax(m);
        s = wred(s * __expf(m - M));
        float inv = 1.f / (s + 1e-16f);
        for (int j0 = 0; j0 < n; j0 += 64) {
            int lim = n - j0;
            if (lim > 64) lim = 64;
            float wv = 0.f;
            int g = 0;
            if (lane < lim) {
                int p = base + j0 + lane;
                wv = __expf(e2s[p] - M) * inv;
                g = gs[p];
            }
            int jj = 0;
            for (; jj + 8 <= lim; jj += 8) {  // 8 rows in flight, 256B each
                float w0 = __shfl(wv, jj + 0), w1 = __shfl(wv, jj + 1);
                float w2 = __shfl(wv, jj + 2), w3 = __shfl(wv, jj + 3);
                float w4 = __shfl(wv, jj + 4), w5 = __shfl(wv, jj + 5);
                float w6 = __shfl(wv, jj + 6), w7 = __shfl(wv, jj + 7);
                unsigned u0 = xrtn_b[(size_t)__shfl(g, jj + 0) * 64 + lane];
                unsigned u1 = xrtn_b[(size_t)__shfl(g, jj + 1) * 64 + lane];
                unsigned u2 = xrtn_b[(size_t)__shfl(g, jj + 2) * 64 + lane];
                unsigned u3 = xrtn_b[(size_t)__shfl(g, jj + 3) * 64 + lane];
                unsigned u4 = xrtn_b[(size_t)__shfl(g, jj + 4) * 64 + lane];
                unsigned u5 = xrtn_b[(size_t)__shfl(g, jj + 5) * 64 + lane];
                unsigned u6 = xrtn_b[(size_t)__shfl(g, jj + 6) * 64 + lane];
                unsigned u7 = xrtn_b[(size_t)__shfl(g, jj + 7) * 64 + lane];
                a0 = fmaf(w0, bu2f((unsigned short)(u0 & 0xffff)), a0);
                a1 = fmaf(w0, bu2f((unsigned short)(u0 >> 16)), a1);
                a0 = fmaf(w1, bu2f((unsigned short)(u1 & 0xffff)), a0);
                a1 = fmaf(w1, bu2f((unsigned short)(u1 >> 16)), a1);
                a0 = fmaf(w2, bu2f((unsigned short)(u2 & 0xffff)), a0);
                a1 = fmaf(w2, bu2f((unsigned short)(u2 >> 16)), a1);
                a0 = fmaf(w3, bu2f((unsigned short)(u3 & 0xffff)), a0);
                a1 = fmaf(w3, bu2f((unsigned short)(u3 >> 16)), a1);
                a0 = fmaf(w4, bu2f((unsigned short)(u4 & 0xffff)), a0);
                a1 = fmaf(w4, bu2f((unsigned short)(u4 >> 16)), a1);
                a0 = fmaf(w5, bu2f((unsigned short)(u5 & 0xffff)), a0);
                a1 = fmaf(w5, bu2f((unsigned short)(u5 >> 16)), a1);
                a0 = fmaf(w6, bu2f((unsigned short)(u6 & 0xffff)), a0);
                a1 = fmaf(w6, bu2f((unsigned short)(u6 >> 16)), a1);
                a0 = fmaf(w7, bu2f((unsigned short)(u7 & 0xffff)), a0);
                a1 = fmaf(w7, bu2f((unsigned short)(u7 >> 16)), a1);
            }
            for (; jj < lim; jj++) {
                float wj = __shfl(wv, jj);
                unsigned u = xrtn_b[(size_t)__shfl(g, jj) * 64 + lane];
                a0 = fmaf(wj, bu2f((unsigned short)(u & 0xffff)), a0);
                a1 = fmaf(wj, bu2f((unsigned short)(u >> 16)), a1);
            }
        }
    }
    *(float2*)&xclass[(size_t)c * 128 + 2 * lane] = make_float2(a0, a1);
    // fused class-level dot: e_c = xclass[c]·ac + eh4[hclass[c]]
    float p = wred(a0 * ac[2 * lane] + a1 * ac[2 * lane + 1]);
    if (lane == 0) {
        int hc = hclass[c];
        float z = LRELU(p + eh4[hc]);
        zc[c] = z;
        atomicMax(&m3[hc], fenc(z));
    }
}

// ---- level 3: class -> head entity ----
__global__ __launch_bounds__(256) void k_class2(const int* __restrict__ hclass,
                                                float* __restrict__ zc,
                                                const unsigned* __restrict__ m3,
                                                float* __restrict__ s3, int NC) {
    int c = blockIdx.x * 256 + threadIdx.x;
    if (c >= NC) return;
    int hc = hclass[c];
    float ex = expf(zc[c] - fdec(m3[hc]));
    zc[c] = ex;
    atomicAdd(&s3[hc], ex);
}

__global__ __launch_bounds__(256) void k_class3(
    const int* __restrict__ hclass, const float* __restrict__ zc,
    const float* __restrict__ s3, const float* __restrict__ xclass,
    float* __restrict__ xeh, int NC) {
    int lane = threadIdx.x & 63;
    int c = blockIdx.x * 4 + (threadIdx.x >> 6);
    if (c >= NC) return;
    int hc = hclass[c];
    float gama = zc[c] / (s3[hc] + 1e-16f);
    float v0 = xclass[(size_t)c * 128 + lane], v1 = xclass[(size_t)c * 128 + 64 + lane];
    atomicAdd(&xeh[(size_t)hc * 128 + lane], gama * v0);
    atomicAdd(&xeh[(size_t)hc * 128 + 64 + lane], gama * v1);
}

extern "C" void kernel_launch(void* const* d_in, const int* in_sizes, int n_in,
                              void* d_out, int out_size, void* d_ws, size_t ws_size,
                              hipStream_t stream) {
    (void)n_in; (void)out_size; (void)ws_size;
    const float* xe   = (const float*)d_in[0];
    const int*   eidx = (const int*)d_in[1];
    const int*   rel  = (const int*)d_in[2];
    const float* remb = (const float*)d_in[4];
    const int*   cidx = (const int*)d_in[5];
    const int*   hcls = (const int*)d_in[6];
    const float* ah2  = (const float*)d_in[8];
    const float* ah3  = (const float*)d_in[9];
    const float* ah4  = (const float*)d_in[10];
    const float* at2  = (const float*)d_in[12];
    const float* at3  = (const float*)d_in[13];
    const float* ar2  = (const float*)d_in[15];
    const float* ac   = (const float*)d_in[16];
    const float* wh   = (const float*)d_in[17];
    const float* wt   = (const float*)d_in[18];
    const float* hww  = (const float*)d_in[19];
    const float* hwb  = (const float*)d_in[20];
    float* out = (float*)d_out;

    const int NE = in_sizes[0] / 256;
    const int E  = in_sizes[2];
    const int NR = in_sizes[4] / 128;
    const int NC = in_sizes[6];
    const int* hidx = eidx;
    const int* tidx = eidx + E;

    char* base = (char*)d_ws;
    size_t off0 = 0;
    auto alloc = [&](size_t bytes) -> char* {
        char* r = base + off0;
        off0 = (off0 + bytes + 255) & ~(size_t)255;
        return r;
    };
    float* hb   = (float*)alloc((size_t)NE * 4);
    float* eh4b = (float*)alloc((size_t)NE * 4);
    float* ta   = (float*)alloc((size_t)NE * 4);
    float* er2b = (float*)alloc((size_t)NR * 4);
    float* e2s  = (float*)alloc((size_t)E * 4);
    int*   gs   = (int*)alloc((size_t)E * 4);
    float* zc   = (float*)alloc((size_t)NC * 4);
    unsigned short* wtb_hi = (unsigned short*)alloc((size_t)256 * 256 * 2);
    unsigned short* wtb_lo = (unsigned short*)alloc((size_t)256 * 256 * 2);
    unsigned short* hwt_hi = (unsigned short*)alloc((size_t)128 * 128 * 2);
    unsigned short* hwt_lo = (unsigned short*)alloc((size_t)128 * 128 * 2);
    unsigned short* a_hi   = (unsigned short*)alloc((size_t)NE * 256 * 2);
    unsigned short* xrh_hi = (unsigned short*)alloc((size_t)NE * 128 * 2);
    unsigned short* xrtn   = (unsigned short*)alloc((size_t)NE * 128 * 2);
    int* offb = (int*)alloc((size_t)NC * 4);
    int* curb = (int*)alloc((size_t)NC * 4);
    float* xclass = (float*)alloc((size_t)NC * 128 * 4);
    size_t zoff = off0;  // everything below is zero-initialized per launch
    unsigned* m3 = (unsigned*)alloc((size_t)NE * 4);
    float* s3    = (float*)alloc((size_t)NE * 4);
    int* cntb    = (int*)alloc((size_t)NC * 4);
    float* xeh   = (float*)alloc((size_t)NE * 128 * 4);
    size_t zbytes = off0 - zoff;

    hipMemsetAsync(base + zoff, 0, zbytes, stream);

    k_convW<<<(256 * 256 + 128 * 128 + 255) / 256, 256, 0, stream>>>(
        wh, wt, hww, wtb_hi, wtb_lo, hwt_hi, hwt_lo);
    long n8 = (long)NE * 256 / 8;
    k_convA<<<(int)((n8 + 255) / 256), 256, 0, stream>>>(xe, a_hi, n8);
    k_rel<<<(NR + 3) / 4, 256, 0, stream>>>(remb, ar2, er2b, NR);

    // projection GEMM: bf16 mirrors (xrt pre-normalized) + fused dots
    k_mm_proj<<<((NE + 127) / 128) * 2, 256, 0, stream>>>(
        a_hi, wtb_hi, wtb_lo, xrh_hi, xrtn, NE,
        ah2, ah3, ah4, at2, at3, hb, eh4b, ta);

    // class-CSR histogram/scan
    k_hist<<<(E + 255) / 256, 256, 0, stream>>>(cidx, cntb, E);
    k_scan<<<1, 1024, 0, stream>>>(cntb, offb, curb, NC);

    // fused level-2 logit + scatter (level-1 softmax is dead code: the
    // F.normalize cancels alpha exactly for alpha*nrm > 1e-12)
    k_edgescatter<<<(E + 255) / 256, 256, 0, stream>>>(
        cidx, curb, hidx, tidx, rel, ta, hb, er2b, e2s, gs, E);

    k_spmm2<<<(NC + 3) / 4, 256, 0, stream>>>(offb, cntb, e2s, gs,
                                              (const unsigned*)xrtn, xclass,
                                              ac, eh4b, hcls, zc, m3, NC);
    k_class2<<<(NC + 255) / 256, 256, 0, stream>>>(hcls, zc, m3, s3, NC);
    k_class3<<<(NC + 3) / 4, 256, 0, stream>>>(hcls, zc, s3, xclass, xeh, NC);

    k_mm_hw<<<(NE + 127) / 128, 256, 0, stream>>>(
        xrh_hi, hwt_hi, hwt_lo, out, hwb, xeh, NE);
}

// Round 12
// 384.683 us; speedup vs baseline: 1.7500x; 1.0491x over previous
//
#include <hip/hip_runtime.h>
#include <hip/hip_bf16.h>

#define LRELU(x) ((x) >= 0.f ? (x) : 0.01f * (x))

typedef __attribute__((ext_vector_type(8))) short short8v;
typedef __attribute__((ext_vector_type(4))) float f32x4;

__device__ inline unsigned fenc(float x) {
    unsigned u = __float_as_uint(x);
    return (u & 0x80000000u) ? ~u : (u | 0x80000000u);
}
__device__ inline float fdec(unsigned e) {
    return __uint_as_float((e & 0x80000000u) ? (e ^ 0x80000000u) : ~e);
}

__device__ inline float wred(float v) {
#pragma unroll
    for (int o = 32; o > 0; o >>= 1) v += __shfl_xor(v, o, 64);
    return v;
}
__device__ inline float wredmax(float v) {
#pragma unroll
    for (int o = 32; o > 0; o >>= 1) v = fmaxf(v, __shfl_xor(v, o, 64));
    return v;
}

__device__ inline unsigned short f2bu(float x) {
    __hip_bfloat16 b = __float2bfloat16(x);
    return *reinterpret_cast<unsigned short*>(&b);
}
__device__ inline float bu2f(unsigned short u) {
    return __uint_as_float((unsigned)u << 16);
}

__device__ inline f32x4 mfma16(short8v a, short8v b, f32x4 c) {
    return __builtin_amdgcn_mfma_f32_16x16x32_bf16(a, b, c, 0, 0, 0);
}

// async global->LDS, 16B per lane, dest = (wave-uniform base) + lane*16
__device__ inline void gload16(const void* g, void* l) {
    __builtin_amdgcn_global_load_lds(
        (const __attribute__((address_space(1))) void*)g,
        (__attribute__((address_space(3))) void*)l, 16, 0, 0);
}

// ---- convert W matrices to transposed hi/lo bf16: Wt[n][k] = W[k][n] ----
__global__ __launch_bounds__(256) void k_convW(
    const float* __restrict__ wh, const float* __restrict__ wt,
    const float* __restrict__ hww, unsigned short* __restrict__ wtb_hi,
    unsigned short* __restrict__ wtb_lo, unsigned short* __restrict__ hwt_hi,
    unsigned short* __restrict__ hwt_lo) {
    int id = blockIdx.x * 256 + threadIdx.x;
    if (id < 256 * 256) {
        int n = id >> 8, k = id & 255;
        float v = (n < 128) ? wh[(size_t)k * 128 + n] : wt[(size_t)k * 128 + (n - 128)];
        unsigned short h = f2bu(v);
        float r = v - bu2f(h);
        wtb_hi[(size_t)n * 256 + k] = h;
        wtb_lo[(size_t)n * 256 + k] = f2bu(r);
    } else {
        int id2 = id - 256 * 256;
        if (id2 < 128 * 128) {
            int n = id2 >> 7, k = id2 & 127;
            float v = hww[(size_t)k * 128 + n];
            unsigned short h = f2bu(v);
            float r = v - bu2f(h);
            hwt_hi[(size_t)n * 128 + k] = h;
            hwt_lo[(size_t)n * 128 + k] = f2bu(r);
        }
    }
}

// ---- convert A (x_e) to bf16, row-major [NE][256] ----
__global__ __launch_bounds__(256) void k_convA(const float* __restrict__ x,
                                               unsigned short* __restrict__ hi,
                                               long n8) {
    long i = (long)blockIdx.x * 256 + threadIdx.x;
    if (i >= n8) return;
    const float4* xp = (const float4*)(x + i * 8);
    float4 a = xp[0], b = xp[1];
    float xs[8] = {a.x, a.y, a.z, a.w, b.x, b.y, b.z, b.w};
    short8v vh;
#pragma unroll
    for (int j = 0; j < 8; j++) vh[j] = (short)f2bu(xs[j]);
    *(short8v*)(hi + i * 8) = vh;
}

// ---- relation dot: er2[r] = r_emb[r]·a_r2 ----
__global__ __launch_bounds__(256) void k_rel(const float* __restrict__ remb,
                                             const float* __restrict__ ar2,
                                             float* __restrict__ er2, int NR) {
    int lane = threadIdx.x & 63;
    int r = blockIdx.x * 4 + (threadIdx.x >> 6);
    if (r >= NR) return;
    float v0 = remb[(size_t)r * 128 + lane];
    float v1 = remb[(size_t)r * 128 + 64 + lane];
    float p2 = wred(v0 * ar2[lane] + v1 * ar2[64 + lane]);
    if (lane == 0) er2[r] = p2;
}

// ---- m97-style LDS-staged MFMA GEMM: A bf16, B split hi/lo, 2 mfma/cell ----
// Block 128x128, 4 waves in 2x2 quadrants, acc[4][4], BK=32.
// EPI 0 (proj, KD=256): UNNORMALIZED bf16 stores in pass A (no acc live
//   across the barrier -> low VGPR); qc==0 epilogue (pd only):
//   half0 -> hb=eh2+.25*eh3, eh4o; half1 -> inv=1/max(nrm,1e-12),
//   ta=(et2+.25*et3)*inv, invn=inv (normalization applied in spmm2 via ws).
// EPI 1 (highway, KD=128): gate=sigmoid(C+bias); o0 = g*xeh + (1-g)*bf16(A).
template <int EPI>
__device__ __forceinline__ void mm_body(
    const unsigned short* __restrict__ Ah,
    const unsigned short* __restrict__ Bh, const unsigned short* __restrict__ Bl,
    unsigned short* __restrict__ oh0, unsigned short* __restrict__ oh1,
    float* __restrict__ o0, const float* __restrict__ bias,
    const float* __restrict__ xeh, int M,
    const float* __restrict__ ah2, const float* __restrict__ ah3,
    const float* __restrict__ ah4, const float* __restrict__ at2,
    const float* __restrict__ at3,
    float* __restrict__ hb, float* __restrict__ eh4o,
    float* __restrict__ ta, float* __restrict__ invn) {
    constexpr int KD = (EPI == 0) ? 256 : 128;
    constexpr int NSTEP = KD / 32;
    __shared__ unsigned short As_h[128 * 32];
    __shared__ unsigned short Bs_h[128 * 32];
    __shared__ unsigned short Bs_l[128 * 32];
    __shared__ float pd[(EPI == 0) ? 2 : 1][(EPI == 0) ? 128 : 1][4];

    int bx = blockIdx.x;
    int half = (EPI == 0) ? (bx & 1) : 0;
    int mblk = (EPI == 0) ? (bx >> 1) : bx;
    int row0 = mblk * 128;
    if (row0 + 128 > M) row0 = M - 128;
    int tid = threadIdx.x, w = tid >> 6, l = tid & 63;
    int qr = w >> 1, qc = w & 1;
    int lr = l & 15, hi4 = l >> 4;
    int srow = l >> 2, sslot = l & 3;

    f32x4 acc[4][4];
#pragma unroll
    for (int i = 0; i < 4; i++)
#pragma unroll
        for (int j = 0; j < 4; j++) acc[i][j] = (f32x4){0.f, 0.f, 0.f, 0.f};

    for (int s = 0; s < NSTEP; s++) {
        int k0 = s * 32;
        __syncthreads();
#pragma unroll
        for (int i = 0; i < 6; i++) {            // 24 units of 1KB, 6/wave
            int u = w * 6 + i;
            int arr = u >> 3, ld = u & 7;
            int row = ld * 16 + srow;
            int klog = (sslot ^ ((row >> 1) & 3)) * 8;
            const unsigned short* src;
            unsigned short* dst;
            if (arr == 0)      { src = Ah + (size_t)(row0 + row) * KD; dst = As_h; }
            else if (arr == 1) {
                src = Bh + (size_t)((EPI == 0 ? half * 128 : 0) + row) * KD;
                dst = Bs_h;
            } else {
                src = Bl + (size_t)((EPI == 0 ? half * 128 : 0) + row) * KD;
                dst = Bs_l;
            }
            gload16(src + k0 + klog, dst + ld * 512);
        }
        __syncthreads();

        short8v am_h[4], bn_h[4], bn_l[4];
#pragma unroll
        for (int mr = 0; mr < 4; mr++) {
            int r = qr * 64 + mr * 16 + lr;
            int ko = (hi4 ^ ((r >> 1) & 3)) * 8;
            am_h[mr] = *(const short8v*)&As_h[r * 32 + ko];
        }
#pragma unroll
        for (int nc = 0; nc < 4; nc++) {
            int n = qc * 64 + nc * 16 + lr;
            int ko = (hi4 ^ ((n >> 1) & 3)) * 8;
            bn_h[nc] = *(const short8v*)&Bs_h[n * 32 + ko];
            bn_l[nc] = *(const short8v*)&Bs_l[n * 32 + ko];
        }
#pragma unroll
        for (int mr = 0; mr < 4; mr++)
#pragma unroll
            for (int nc = 0; nc < 4; nc++) {
                acc[mr][nc] = mfma16(am_h[mr], bn_h[nc], acc[mr][nc]);
                acc[mr][nc] = mfma16(am_h[mr], bn_l[nc], acc[mr][nc]);
            }
    }

    if constexpr (EPI == 0) {
        unsigned short* OH = half ? oh1 : oh0;
        const float* v1 = half ? at2 : ah2;
        const float* v2 = half ? at3 : ah3;
        // pass A: unnormalized bf16 store + dots (acc dead after this)
#pragma unroll
        for (int mr = 0; mr < 4; mr++)
#pragma unroll
            for (int rr = 0; rr < 4; rr++) {
                int rl = qr * 64 + mr * 16 + hi4 * 4 + rr;
                int row = row0 + rl;
                float d0 = 0.f, d1 = 0.f, d2 = 0.f;
#pragma unroll
                for (int nc = 0; nc < 4; nc++) {
                    float v = fmaxf(acc[mr][nc][rr], 0.f);
                    int col = qc * 64 + nc * 16 + lr;
                    OH[(size_t)row * 128 + col] = f2bu(v);
                    d0 = fmaf(v, v1[col], d0);
                    d1 = fmaf(v, v2[col], d1);
                    d2 = half ? fmaf(v, v, d2) : fmaf(v, ah4[col], d2);
                }
#pragma unroll
                for (int o = 1; o <= 8; o <<= 1) {
                    d0 += __shfl_xor(d0, o, 64);
                    d1 += __shfl_xor(d1, o, 64);
                    d2 += __shfl_xor(d2, o, 64);
                }
                if (lr == 0) {
                    pd[qc][rl][0] = d0; pd[qc][rl][1] = d1; pd[qc][rl][2] = d2;
                }
            }
        __syncthreads();
        if (qc == 0 && lr == 0) {
#pragma unroll
            for (int mr = 0; mr < 4; mr++)
#pragma unroll
                for (int rr = 0; rr < 4; rr++) {
                    int rl = qr * 64 + mr * 16 + hi4 * 4 + rr;
                    int row = row0 + rl;
                    float s0 = pd[0][rl][0] + pd[1][rl][0];
                    float s1 = pd[0][rl][1] + pd[1][rl][1];
                    float s2 = pd[0][rl][2] + pd[1][rl][2];
                    if (half == 0) {
                        hb[row] = s0 + 0.25f * s1;
                        eh4o[row] = s2;
                    } else {
                        float inv = 1.f / fmaxf(sqrtf(s2), 1e-12f);
                        ta[row] = (s0 + 0.25f * s1) * inv;
                        invn[row] = inv;
                    }
                }
        }
    } else {
#pragma unroll
        for (int mr = 0; mr < 4; mr++)
#pragma unroll
            for (int rr = 0; rr < 4; rr++) {
                int row = row0 + qr * 64 + mr * 16 + hi4 * 4 + rr;
#pragma unroll
                for (int nc = 0; nc < 4; nc++) {
                    int col = qc * 64 + nc * 16 + lr;
                    float a = acc[mr][nc][rr] + bias[col];
                    float g = 1.f / (1.f + expf(-a));
                    size_t o = (size_t)row * 128 + col;
                    float af = bu2f(Ah[o]);
                    o0[o] = g * xeh[o] + (1.f - g) * af;
                }
            }
    }
}

__global__ __launch_bounds__(256) void k_mm_proj(
    const unsigned short* Ah, const unsigned short* Bh, const unsigned short* Bl,
    unsigned short* oh0, unsigned short* oh1, int M,
    const float* ah2, const float* ah3, const float* ah4,
    const float* at2, const float* at3,
    float* hb, float* eh4o, float* ta, float* invn) {
    mm_body<0>(Ah, Bh, Bl, oh0, oh1, nullptr, nullptr, nullptr, M,
               ah2, ah3, ah4, at2, at3, hb, eh4o, ta, invn);
}

__global__ __launch_bounds__(256) void k_mm_hw(
    const unsigned short* Ah, const unsigned short* Bh, const unsigned short* Bl,
    float* o0, const float* bias, const float* xeh, int M) {
    mm_body<1>(Ah, Bh, Bl, nullptr, nullptr, o0, bias, xeh, M,
               nullptr, nullptr, nullptr, nullptr, nullptr,
               nullptr, nullptr, nullptr, nullptr);
}

// ---- counting sort by class_index ----
__global__ __launch_bounds__(256) void k_hist(const int* __restrict__ cidx,
                                              int* __restrict__ cnt, int E) {
    int i = blockIdx.x * 256 + threadIdx.x;
    if (i >= E) return;
    atomicAdd(&cnt[cidx[i]], 1);
}

__global__ __launch_bounds__(1024) void k_scan(const int* __restrict__ cnt,
                                               int* __restrict__ off,
                                               int* __restrict__ cur, int NC) {
    __shared__ int wt[16];
    __shared__ int sbase;
    int tid = threadIdx.x, w = tid >> 6, lane = tid & 63;
    if (tid == 0) sbase = 0;
    __syncthreads();
    for (int c0 = 0; c0 < NC; c0 += 1024) {
        int c = c0 + tid;
        int v = (c < NC) ? cnt[c] : 0;
        int x = v;
#pragma unroll
        for (int o = 1; o < 64; o <<= 1) {
            int t = __shfl_up(x, o, 64);
            if (lane >= o) x += t;
        }
        if (lane == 63) wt[w] = x;
        __syncthreads();
        int pre = 0, tot = 0;
#pragma unroll
        for (int i = 0; i < 16; i++) {
            int t = wt[i];
            tot += t;
            if (i < w) pre += t;
        }
        int excl = sbase + pre + x - v;
        if (c < NC) { off[c] = excl; cur[c] = excl; }
        __syncthreads();
        if (tid == 0) sbase += tot;
        __syncthreads();
    }
}

// ---- fused level-2 logit + scatter to class-sorted order ----
// z2 = lrelu(ta[te] + hb[h] + 0.5*er2[rel]); g = tidx[te]; ws = invn[g]
__global__ __launch_bounds__(256) void k_edgescatter(
    const int* __restrict__ cidx, int* __restrict__ cur,
    const int* __restrict__ hidx, const int* __restrict__ tidx,
    const int* __restrict__ rel, const float* __restrict__ ta,
    const float* __restrict__ hb, const float* __restrict__ er2,
    const float* __restrict__ invn, float* __restrict__ e2s,
    float* __restrict__ ws, int* __restrict__ gs, int E) {
    int i = blockIdx.x * 256 + threadIdx.x;
    if (i >= E) return;
    int pos = atomicAdd(&cur[cidx[i]], 1);
    int te = tidx[i];
    int g = tidx[te];
    float z2 = ta[te] + hb[hidx[i]] + 0.5f * er2[rel[i]];
    e2s[pos] = LRELU(z2);
    ws[pos] = invn[g];
    gs[pos] = g;
}

// ---- fused level-2 softmax + spmm + class-dot, one wave/class ----
// rows gathered from unnormalized bf16 xrt; per-edge ws = 1/nrm[g].
__global__ __launch_bounds__(256) void k_spmm2(
    const int* __restrict__ off, const int* __restrict__ cnt,
    const float* __restrict__ e2s, const float* __restrict__ ws,
    const int* __restrict__ gs, const unsigned* __restrict__ xrt_b,
    float* __restrict__ xclass, const float* __restrict__ ac,
    const float* __restrict__ eh4, const int* __restrict__ hclass,
    float* __restrict__ zc, unsigned* __restrict__ m3, int NC) {
    int lane = threadIdx.x & 63;
    int c = blockIdx.x * 4 + (threadIdx.x >> 6);
    if (c >= NC) return;
    int n = cnt[c];
    float a0 = 0.f, a1 = 0.f;
    if (n > 0) {
        int base = off[c];
        float m = -3.4e38f, s = 0.f;
        for (int j = lane; j < n; j += 64) {
            float z = e2s[base + j];
            if (z > m) { s = s * __expf(m - z) + 1.f; m = z; }
            else s += __expf(z - m);
        }
        float M = wredmax(m);
        s = wred(s * __expf(m - M));
        float inv = 1.f / (s + 1e-16f);
        for (int j0 = 0; j0 < n; j0 += 64) {
            int lim = n - j0;
            if (lim > 64) lim = 64;
            float wv = 0.f;
            int g = 0;
            if (lane < lim) {
                int p = base + j0 + lane;
                wv = __expf(e2s[p] - M) * inv * ws[p];
                g = gs[p];
            }
            int jj = 0;
            for (; jj + 8 <= lim; jj += 8) {  // 8 rows in flight, 256B each
                float w0 = __shfl(wv, jj + 0), w1 = __shfl(wv, jj + 1);
                float w2 = __shfl(wv, jj + 2), w3 = __shfl(wv, jj + 3);
                float w4 = __shfl(wv, jj + 4), w5 = __shfl(wv, jj + 5);
                float w6 = __shfl(wv, jj + 6), w7 = __shfl(wv, jj + 7);
                unsigned u0 = xrt_b[(size_t)__shfl(g, jj + 0) * 64 + lane];
                unsigned u1 = xrt_b[(size_t)__shfl(g, jj + 1) * 64 + lane];
                unsigned u2 = xrt_b[(size_t)__shfl(g, jj + 2) * 64 + lane];
                unsigned u3 = xrt_b[(size_t)__shfl(g, jj + 3) * 64 + lane];
                unsigned u4 = xrt_b[(size_t)__shfl(g, jj + 4) * 64 + lane];
                unsigned u5 = xrt_b[(size_t)__shfl(g, jj + 5) * 64 + lane];
                unsigned u6 = xrt_b[(size_t)__shfl(g, jj + 6) * 64 + lane];
                unsigned u7 = xrt_b[(size_t)__shfl(g, jj + 7) * 64 + lane];
                a0 = fmaf(w0, bu2f((unsigned short)(u0 & 0xffff)), a0);
                a1 = fmaf(w0, bu2f((unsigned short)(u0 >> 16)), a1);
                a0 = fmaf(w1, bu2f((unsigned short)(u1 & 0xffff)), a0);
                a1 = fmaf(w1, bu2f((unsigned short)(u1 >> 16)), a1);
                a0 = fmaf(w2, bu2f((unsigned short)(u2 & 0xffff)), a0);
                a1 = fmaf(w2, bu2f((unsigned short)(u2 >> 16)), a1);
                a0 = fmaf(w3, bu2f((unsigned short)(u3 & 0xffff)), a0);
                a1 = fmaf(w3, bu2f((unsigned short)(u3 >> 16)), a1);
                a0 = fmaf(w4, bu2f((unsigned short)(u4 & 0xffff)), a0);
                a1 = fmaf(w4, bu2f((unsigned short)(u4 >> 16)), a1);
                a0 = fmaf(w5, bu2f((unsigned short)(u5 & 0xffff)), a0);
                a1 = fmaf(w5, bu2f((unsigned short)(u5 >> 16)), a1);
                a0 = fmaf(w6, bu2f((unsigned short)(u6 & 0xffff)), a0);
                a1 = fmaf(w6, bu2f((unsigned short)(u6 >> 16)), a1);
                a0 = fmaf(w7, bu2f((unsigned short)(u7 & 0xffff)), a0);
                a1 = fmaf(w7, bu2f((unsigned short)(u7 >> 16)), a1);
            }
            for (; jj < lim; jj++) {
                float wj = __shfl(wv, jj);
                unsigned u = xrt_b[(size_t)__shfl(g, jj) * 64 + lane];
                a0 = fmaf(wj, bu2f((unsigned short)(u & 0xffff)), a0);
                a1 = fmaf(wj, bu2f((unsigned short)(u >> 16)), a1);
            }
        }
    }
    *(float2*)&xclass[(size_t)c * 128 + 2 * lane] = make_float2(a0, a1);
    // fused class-level dot: e_c = xclass[c]·ac + eh4[hclass[c]]
    float p = wred(a0 * ac[2 * lane] + a1 * ac[2 * lane + 1]);
    if (lane == 0) {
        int hc = hclass[c];
        float z = LRELU(p + eh4[hc]);
        zc[c] = z;
        atomicMax(&m3[hc], fenc(z));
    }
}

// ---- level 3: class -> head entity ----
__global__ __launch_bounds__(256) void k_class2(const int* __restrict__ hclass,
                                                float* __restrict__ zc,
                                                const unsigned* __restrict__ m3,
                                                float* __restrict__ s3, int NC) {
    int c = blockIdx.x * 256 + threadIdx.x;
    if (c >= NC) return;
    int hc = hclass[c];
    float ex = expf(zc[c] - fdec(m3[hc]));
    zc[c] = ex;
    atomicAdd(&s3[hc], ex);
}

__global__ __launch_bounds__(256) void k_class3(
    const int* __restrict__ hclass, const float* __restrict__ zc,
    const float* __restrict__ s3, const float* __restrict__ xclass,
    float* __restrict__ xeh, int NC) {
    int lane = threadIdx.x & 63;
    int c = blockIdx.x * 4 + (threadIdx.x >> 6);
    if (c >= NC) return;
    int hc = hclass[c];
    float gama = zc[c] / (s3[hc] + 1e-16f);
    float v0 = xclass[(size_t)c * 128 + lane], v1 = xclass[(size_t)c * 128 + 64 + lane];
    atomicAdd(&xeh[(size_t)hc * 128 + lane], gama * v0);
    atomicAdd(&xeh[(size_t)hc * 128 + 64 + lane], gama * v1);
}

extern "C" void kernel_launch(void* const* d_in, const int* in_sizes, int n_in,
                              void* d_out, int out_size, void* d_ws, size_t ws_size,
                              hipStream_t stream) {
    (void)n_in; (void)out_size; (void)ws_size;
    const float* xe   = (const float*)d_in[0];
    const int*   eidx = (const int*)d_in[1];
    const int*   rel  = (const int*)d_in[2];
    const float* remb = (const float*)d_in[4];
    const int*   cidx = (const int*)d_in[5];
    const int*   hcls = (const int*)d_in[6];
    const float* ah2  = (const float*)d_in[8];
    const float* ah3  = (const float*)d_in[9];
    const float* ah4  = (const float*)d_in[10];
    const float* at2  = (const float*)d_in[12];
    const float* at3  = (const float*)d_in[13];
    const float* ar2  = (const float*)d_in[15];
    const float* ac   = (const float*)d_in[16];
    const float* wh   = (const float*)d_in[17];
    const float* wt   = (const float*)d_in[18];
    const float* hww  = (const float*)d_in[19];
    const float* hwb  = (const float*)d_in[20];
    float* out = (float*)d_out;

    const int NE = in_sizes[0] / 256;
    const int E  = in_sizes[2];
    const int NR = in_sizes[4] / 128;
    const int NC = in_sizes[6];
    const int* hidx = eidx;
    const int* tidx = eidx + E;

    char* base = (char*)d_ws;
    size_t off0 = 0;
    auto alloc = [&](size_t bytes) -> char* {
        char* r = base + off0;
        off0 = (off0 + bytes + 255) & ~(size_t)255;
        return r;
    };
    float* hb   = (float*)alloc((size_t)NE * 4);
    float* eh4b = (float*)alloc((size_t)NE * 4);
    float* ta   = (float*)alloc((size_t)NE * 4);
    float* invn = (float*)alloc((size_t)NE * 4);
    float* er2b = (float*)alloc((size_t)NR * 4);
    float* e2s  = (float*)alloc((size_t)E * 4);
    float* ws   = (float*)alloc((size_t)E * 4);
    int*   gs   = (int*)alloc((size_t)E * 4);
    float* zc   = (float*)alloc((size_t)NC * 4);
    unsigned short* wtb_hi = (unsigned short*)alloc((size_t)256 * 256 * 2);
    unsigned short* wtb_lo = (unsigned short*)alloc((size_t)256 * 256 * 2);
    unsigned short* hwt_hi = (unsigned short*)alloc((size_t)128 * 128 * 2);
    unsigned short* hwt_lo = (unsigned short*)alloc((size_t)128 * 128 * 2);
    unsigned short* a_hi   = (unsigned short*)alloc((size_t)NE * 256 * 2);
    unsigned short* xrh_hi = (unsigned short*)alloc((size_t)NE * 128 * 2);
    unsigned short* xrt_hi = (unsigned short*)alloc((size_t)NE * 128 * 2);
    int* offb = (int*)alloc((size_t)NC * 4);
    int* curb = (int*)alloc((size_t)NC * 4);
    float* xclass = (float*)alloc((size_t)NC * 128 * 4);
    size_t zoff = off0;  // everything below is zero-initialized per launch
    unsigned* m3 = (unsigned*)alloc((size_t)NE * 4);
    float* s3    = (float*)alloc((size_t)NE * 4);
    int* cntb    = (int*)alloc((size_t)NC * 4);
    float* xeh   = (float*)alloc((size_t)NE * 128 * 4);
    size_t zbytes = off0 - zoff;

    hipMemsetAsync(base + zoff, 0, zbytes, stream);

    k_convW<<<(256 * 256 + 128 * 128 + 255) / 256, 256, 0, stream>>>(
        wh, wt, hww, wtb_hi, wtb_lo, hwt_hi, hwt_lo);
    long n8 = (long)NE * 256 / 8;
    k_convA<<<(int)((n8 + 255) / 256), 256, 0, stream>>>(xe, a_hi, n8);
    k_rel<<<(NR + 3) / 4, 256, 0, stream>>>(remb, ar2, er2b, NR);

    // projection GEMM: unnormalized bf16 mirrors + fused dots/norm scalars
    k_mm_proj<<<((NE + 127) / 128) * 2, 256, 0, stream>>>(
        a_hi, wtb_hi, wtb_lo, xrh_hi, xrt_hi, NE,
        ah2, ah3, ah4, at2, at3, hb, eh4b, ta, invn);

    // class-CSR histogram/scan
    k_hist<<<(E + 255) / 256, 256, 0, stream>>>(cidx, cntb, E);
    k_scan<<<1, 1024, 0, stream>>>(cntb, offb, curb, NC);

    // fused level-2 logit + scatter (level-1 softmax cancels vs F.normalize)
    k_edgescatter<<<(E + 255) / 256, 256, 0, stream>>>(
        cidx, curb, hidx, tidx, rel, ta, hb, er2b, invn, e2s, ws, gs, E);

    k_spmm2<<<(NC + 3) / 4, 256, 0, stream>>>(offb, cntb, e2s, ws, gs,
                                              (const unsigned*)xrt_hi, xclass,
                                              ac, eh4b, hcls, zc, m3, NC);
    k_class2<<<(NC + 255) / 256, 256, 0, stream>>>(hcls, zc, m3, s3, NC);
    k_class3<<<(NC + 3) / 4, 256, 0, stream>>>(hcls, zc, s3, xclass, xeh, NC);

    k_mm_hw<<<(NE + 127) / 128, 256, 0, stream>>>(
        xrh_hi, hwt_hi, hwt_lo, out, hwb, xeh, NE);
}

// Round 13
// 343.582 us; speedup vs baseline: 1.9593x; 1.1196x over previous
//
#include <hip/hip_runtime.h>
#include <hip/hip_bf16.h>

#define LRELU(x) ((x) >= 0.f ? (x) : 0.01f * (x))

typedef __attribute__((ext_vector_type(8))) short short8v;
typedef __attribute__((ext_vector_type(4))) float f32x4;

__device__ inline unsigned fenc(float x) {
    unsigned u = __float_as_uint(x);
    return (u & 0x80000000u) ? ~u : (u | 0x80000000u);
}
__device__ inline float fdec(unsigned e) {
    return __uint_as_float((e & 0x80000000u) ? (e ^ 0x80000000u) : ~e);
}

__device__ inline float wred(float v) {
#pragma unroll
    for (int o = 32; o > 0; o >>= 1) v += __shfl_xor(v, o, 64);
    return v;
}
__device__ inline float wredmax(float v) {
#pragma unroll
    for (int o = 32; o > 0; o >>= 1) v = fmaxf(v, __shfl_xor(v, o, 64));
    return v;
}

__device__ inline unsigned short f2bu(float x) {
    __hip_bfloat16 b = __float2bfloat16(x);
    return *reinterpret_cast<unsigned short*>(&b);
}
__device__ inline float bu2f(unsigned short u) {
    return __uint_as_float((unsigned)u << 16);
}

__device__ inline f32x4 mfma16(short8v a, short8v b, f32x4 c) {
    return __builtin_amdgcn_mfma_f32_16x16x32_bf16(a, b, c, 0, 0, 0);
}

// async global->LDS, 16B per lane, dest = (wave-uniform base) + lane*16
__device__ inline void gload16(const void* g, void* l) {
    __builtin_amdgcn_global_load_lds(
        (const __attribute__((address_space(1))) void*)g,
        (__attribute__((address_space(3))) void*)l, 16, 0, 0);
}

// ---- convert W matrices to transposed hi/lo bf16: Wt[n][k] = W[k][n] ----
__global__ __launch_bounds__(256) void k_convW(
    const float* __restrict__ wh, const float* __restrict__ wt,
    const float* __restrict__ hww, unsigned short* __restrict__ wtb_hi,
    unsigned short* __restrict__ wtb_lo, unsigned short* __restrict__ hwt_hi,
    unsigned short* __restrict__ hwt_lo) {
    int id = blockIdx.x * 256 + threadIdx.x;
    if (id < 256 * 256) {
        int n = id >> 8, k = id & 255;
        float v = (n < 128) ? wh[(size_t)k * 128 + n] : wt[(size_t)k * 128 + (n - 128)];
        unsigned short h = f2bu(v);
        float r = v - bu2f(h);
        wtb_hi[(size_t)n * 256 + k] = h;
        wtb_lo[(size_t)n * 256 + k] = f2bu(r);
    } else {
        int id2 = id - 256 * 256;
        if (id2 < 128 * 128) {
            int n = id2 >> 7, k = id2 & 127;
            float v = hww[(size_t)k * 128 + n];
            unsigned short h = f2bu(v);
            float r = v - bu2f(h);
            hwt_hi[(size_t)n * 128 + k] = h;
            hwt_lo[(size_t)n * 128 + k] = f2bu(r);
        }
    }
}

// ---- convert A (x_e) to bf16, row-major [NE][256] ----
__global__ __launch_bounds__(256) void k_convA(const float* __restrict__ x,
                                               unsigned short* __restrict__ hi,
                                               long n8) {
    long i = (long)blockIdx.x * 256 + threadIdx.x;
    if (i >= n8) return;
    const float4* xp = (const float4*)(x + i * 8);
    float4 a = xp[0], b = xp[1];
    float xs[8] = {a.x, a.y, a.z, a.w, b.x, b.y, b.z, b.w};
    short8v vh;
#pragma unroll
    for (int j = 0; j < 8; j++) vh[j] = (short)f2bu(xs[j]);
    *(short8v*)(hi + i * 8) = vh;
}

// ---- relation dot: er2[r] = r_emb[r]·a_r2 ----
__global__ __launch_bounds__(256) void k_rel(const float* __restrict__ remb,
                                             const float* __restrict__ ar2,
                                             float* __restrict__ er2, int NR) {
    int lane = threadIdx.x & 63;
    int r = blockIdx.x * 4 + (threadIdx.x >> 6);
    if (r >= NR) return;
    float v0 = remb[(size_t)r * 128 + lane];
    float v1 = remb[(size_t)r * 128 + 64 + lane];
    float p2 = wred(v0 * ar2[lane] + v1 * ar2[64 + lane]);
    if (lane == 0) er2[r] = p2;
}

// ---- m97-style LDS-staged MFMA GEMM: A bf16, B split hi/lo, 2 mfma/cell ----
// Block 128x128; ROW-WAVE tiling: wave w owns rows w*32..w*32+31, ALL 128
// cols -> acc[2][8]; every per-row reduction is a 16-lane shfl (no pd / no
// epilogue barrier; acc never lives across a barrier).
// EPI 0 (proj, KD=256): half0 -> oh0 = bf16(relu(x_e@w_h)),
//   hb=eh2+.25*eh3, eh4o; half1 -> oh1 = bf16(relu(x_e@w_t)*inv)
//   [PRE-NORMALIZED], ta=(et2+.25*et3)*inv, inv=1/max(nrm,1e-12).
// EPI 1 (highway, KD=128): gate=sigmoid(C+bias); o0 = g*xeh + (1-g)*bf16(A).
template <int EPI>
__device__ __forceinline__ void mm_body(
    const unsigned short* __restrict__ Ah,
    const unsigned short* __restrict__ Bh, const unsigned short* __restrict__ Bl,
    unsigned short* __restrict__ oh0, unsigned short* __restrict__ oh1,
    float* __restrict__ o0, const float* __restrict__ bias,
    const float* __restrict__ xeh, int M,
    const float* __restrict__ ah2, const float* __restrict__ ah3,
    const float* __restrict__ ah4, const float* __restrict__ at2,
    const float* __restrict__ at3,
    float* __restrict__ hb, float* __restrict__ eh4o, float* __restrict__ ta) {
    constexpr int KD = (EPI == 0) ? 256 : 128;
    constexpr int NSTEP = KD / 32;
    __shared__ unsigned short As_h[128 * 32];
    __shared__ unsigned short Bs_h[128 * 32];
    __shared__ unsigned short Bs_l[128 * 32];

    int bx = blockIdx.x;
    int half = (EPI == 0) ? (bx & 1) : 0;
    int mblk = (EPI == 0) ? (bx >> 1) : bx;
    int row0 = mblk * 128;
    if (row0 + 128 > M) row0 = M - 128;
    int tid = threadIdx.x, w = tid >> 6, l = tid & 63;
    int lr = l & 15, hi4 = l >> 4;
    int srow = l >> 2, sslot = l & 3;

    f32x4 acc[2][8];
#pragma unroll
    for (int i = 0; i < 2; i++)
#pragma unroll
        for (int j = 0; j < 8; j++) acc[i][j] = (f32x4){0.f, 0.f, 0.f, 0.f};

    for (int s = 0; s < NSTEP; s++) {
        int k0 = s * 32;
        __syncthreads();
#pragma unroll
        for (int i = 0; i < 6; i++) {            // 24 units of 1KB, 6/wave
            int u = w * 6 + i;
            int arr = u >> 3, ld = u & 7;
            int row = ld * 16 + srow;
            int klog = (sslot ^ ((row >> 1) & 3)) * 8;
            const unsigned short* src;
            unsigned short* dst;
            if (arr == 0)      { src = Ah + (size_t)(row0 + row) * KD; dst = As_h; }
            else if (arr == 1) {
                src = Bh + (size_t)((EPI == 0 ? half * 128 : 0) + row) * KD;
                dst = Bs_h;
            } else {
                src = Bl + (size_t)((EPI == 0 ? half * 128 : 0) + row) * KD;
                dst = Bs_l;
            }
            gload16(src + k0 + klog, dst + ld * 512);
        }
        __syncthreads();

        short8v am_h[2];
#pragma unroll
        for (int mr = 0; mr < 2; mr++) {
            int r = w * 32 + mr * 16 + lr;
            int ko = (hi4 ^ ((r >> 1) & 3)) * 8;
            am_h[mr] = *(const short8v*)&As_h[r * 32 + ko];
        }
#pragma unroll
        for (int ncc = 0; ncc < 8; ncc += 4) {   // split B loads: cap VGPR
            short8v bn_h[4], bn_l[4];
#pragma unroll
            for (int j = 0; j < 4; j++) {
                int n = (ncc + j) * 16 + lr;
                int ko = (hi4 ^ ((n >> 1) & 3)) * 8;
                bn_h[j] = *(const short8v*)&Bs_h[n * 32 + ko];
                bn_l[j] = *(const short8v*)&Bs_l[n * 32 + ko];
            }
#pragma unroll
            for (int mr = 0; mr < 2; mr++)
#pragma unroll
                for (int j = 0; j < 4; j++) {
                    acc[mr][ncc + j] = mfma16(am_h[mr], bn_h[j], acc[mr][ncc + j]);
                    acc[mr][ncc + j] = mfma16(am_h[mr], bn_l[j], acc[mr][ncc + j]);
                }
        }
    }

    if constexpr (EPI == 0) {
        unsigned short* OH = half ? oh1 : oh0;
        const float* v1 = half ? at2 : ah2;
        const float* v2 = half ? at3 : ah3;
#pragma unroll
        for (int mr = 0; mr < 2; mr++)
#pragma unroll
            for (int rr = 0; rr < 4; rr++) {
                int row = row0 + w * 32 + mr * 16 + hi4 * 4 + rr;
                float d0 = 0.f, d1 = 0.f, d2 = 0.f;
#pragma unroll
                for (int nc = 0; nc < 8; nc++) {
                    float v = fmaxf(acc[mr][nc][rr], 0.f);
                    int col = nc * 16 + lr;
                    d0 = fmaf(v, v1[col], d0);
                    d1 = fmaf(v, v2[col], d1);
                    d2 = half ? fmaf(v, v, d2) : fmaf(v, ah4[col], d2);
                }
#pragma unroll
                for (int o = 1; o <= 8; o <<= 1) {   // reduce within 16-lane group
                    d0 += __shfl_xor(d0, o, 64);
                    d1 += __shfl_xor(d1, o, 64);
                    d2 += __shfl_xor(d2, o, 64);
                }
                float inv = 1.f;
                if (half) inv = 1.f / fmaxf(sqrtf(d2), 1e-12f);
#pragma unroll
                for (int nc = 0; nc < 8; nc++) {
                    float v = fmaxf(acc[mr][nc][rr], 0.f);
                    OH[(size_t)row * 128 + nc * 16 + lr] = f2bu(half ? v * inv : v);
                }
                if (lr == 0) {
                    if (half == 0) {
                        hb[row] = d0 + 0.25f * d1;
                        eh4o[row] = d2;
                    } else {
                        ta[row] = (d0 + 0.25f * d1) * inv;
                    }
                }
            }
    } else {
#pragma unroll
        for (int mr = 0; mr < 2; mr++)
#pragma unroll
            for (int rr = 0; rr < 4; rr++) {
                int row = row0 + w * 32 + mr * 16 + hi4 * 4 + rr;
#pragma unroll
                for (int nc = 0; nc < 8; nc++) {
                    int col = nc * 16 + lr;
                    float a = acc[mr][nc][rr] + bias[col];
                    float g = 1.f / (1.f + expf(-a));
                    size_t o = (size_t)row * 128 + col;
                    float af = bu2f(Ah[o]);
                    o0[o] = g * xeh[o] + (1.f - g) * af;
                }
            }
    }
}

__global__ __launch_bounds__(256) void k_mm_proj(
    const unsigned short* Ah, const unsigned short* Bh, const unsigned short* Bl,
    unsigned short* oh0, unsigned short* oh1, int M,
    const float* ah2, const float* ah3, const float* ah4,
    const float* at2, const float* at3,
    float* hb, float* eh4o, float* ta) {
    mm_body<0>(Ah, Bh, Bl, oh0, oh1, nullptr, nullptr, nullptr, M,
               ah2, ah3, ah4, at2, at3, hb, eh4o, ta);
}

__global__ __launch_bounds__(256) void k_mm_hw(
    const unsigned short* Ah, const unsigned short* Bh, const unsigned short* Bl,
    float* o0, const float* bias, const float* xeh, int M) {
    mm_body<1>(Ah, Bh, Bl, nullptr, nullptr, o0, bias, xeh, M,
               nullptr, nullptr, nullptr, nullptr, nullptr,
               nullptr, nullptr, nullptr);
}

// ---- counting sort by class_index ----
__global__ __launch_bounds__(256) void k_hist(const int* __restrict__ cidx,
                                              int* __restrict__ cnt, int E) {
    int i = blockIdx.x * 256 + threadIdx.x;
    if (i >= E) return;
    atomicAdd(&cnt[cidx[i]], 1);
}

__global__ __launch_bounds__(1024) void k_scan(const int* __restrict__ cnt,
                                               int* __restrict__ off,
                                               int* __restrict__ cur, int NC) {
    __shared__ int wt[16];
    __shared__ int sbase;
    int tid = threadIdx.x, w = tid >> 6, lane = tid & 63;
    if (tid == 0) sbase = 0;
    __syncthreads();
    for (int c0 = 0; c0 < NC; c0 += 1024) {
        int c = c0 + tid;
        int v = (c < NC) ? cnt[c] : 0;
        int x = v;
#pragma unroll
        for (int o = 1; o < 64; o <<= 1) {
            int t = __shfl_up(x, o, 64);
            if (lane >= o) x += t;
        }
        if (lane == 63) wt[w] = x;
        __syncthreads();
        int pre = 0, tot = 0;
#pragma unroll
        for (int i = 0; i < 16; i++) {
            int t = wt[i];
            tot += t;
            if (i < w) pre += t;
        }
        int excl = sbase + pre + x - v;
        if (c < NC) { off[c] = excl; cur[c] = excl; }
        __syncthreads();
        if (tid == 0) sbase += tot;
        __syncthreads();
    }
}

// ---- fused level-2 logit + scatter to class-sorted order ----
// z2 = lrelu(ta[te] + hb[h] + 0.5*er2[rel]); g = tidx[te]
// (xrt rows are pre-normalized, so no per-edge scale is needed)
__global__ __launch_bounds__(256) void k_edgescatter(
    const int* __restrict__ cidx, int* __restrict__ cur,
    const int* __restrict__ hidx, const int* __restrict__ tidx,
    const int* __restrict__ rel, const float* __restrict__ ta,
    const float* __restrict__ hb, const float* __restrict__ er2,
    float* __restrict__ e2s, int* __restrict__ gs, int E) {
    int i = blockIdx.x * 256 + threadIdx.x;
    if (i >= E) return;
    int pos = atomicAdd(&cur[cidx[i]], 1);
    int te = tidx[i];
    int g = tidx[te];
    float z2 = ta[te] + hb[hidx[i]] + 0.5f * er2[rel[i]];
    e2s[pos] = LRELU(z2);
    gs[pos] = g;
}

// ---- fused level-2 softmax + spmm + class-dot, one wave/class ----
// rows gathered from PRE-NORMALIZED bf16 xrtn.
__global__ __launch_bounds__(256) void k_spmm2(
    const int* __restrict__ off, const int* __restrict__ cnt,
    const float* __restrict__ e2s, const int* __restrict__ gs,
    const unsigned* __restrict__ xrtn_b, float* __restrict__ xclass,
    const float* __restrict__ ac, const float* __restrict__ eh4,
    const int* __restrict__ hclass, float* __restrict__ zc,
    unsigned* __restrict__ m3, int NC) {
    int lane = threadIdx.x & 63;
    int c = blockIdx.x * 4 + (threadIdx.x >> 6);
    if (c >= NC) return;
    int n = cnt[c];
    float a0 = 0.f, a1 = 0.f;
    if (n > 0) {
        int base = off[c];
        float m = -3.4e38f, s = 0.f;
        for (int j = lane; j < n; j += 64) {
            float z = e2s[base + j];
            if (z > m) { s = s * __expf(m - z) + 1.f; m = z; }
            else s += __expf(z - m);
        }
        float M = wredmax(m);
        s = wred(s * __expf(m - M));
        float inv = 1.f / (s + 1e-16f);
        for (int j0 = 0; j0 < n; j0 += 64) {
            int lim = n - j0;
            if (lim > 64) lim = 64;
            float wv = 0.f;
            int g = 0;
            if (lane < lim) {
                int p = base + j0 + lane;
                wv = __expf(e2s[p] - M) * inv;
                g = gs[p];
            }
            int jj = 0;
            for (; jj + 8 <= lim; jj += 8) {  // 8 rows in flight, 256B each
                float w0 = __shfl(wv, jj + 0), w1 = __shfl(wv, jj + 1);
                float w2 = __shfl(wv, jj + 2), w3 = __shfl(wv, jj + 3);
                float w4 = __shfl(wv, jj + 4), w5 = __shfl(wv, jj + 5);
                float w6 = __shfl(wv, jj + 6), w7 = __shfl(wv, jj + 7);
                unsigned u0 = xrtn_b[(size_t)__shfl(g, jj + 0) * 64 + lane];
                unsigned u1 = xrtn_b[(size_t)__shfl(g, jj + 1) * 64 + lane];
                unsigned u2 = xrtn_b[(size_t)__shfl(g, jj + 2) * 64 + lane];
                unsigned u3 = xrtn_b[(size_t)__shfl(g, jj + 3) * 64 + lane];
                unsigned u4 = xrtn_b[(size_t)__shfl(g, jj + 4) * 64 + lane];
                unsigned u5 = xrtn_b[(size_t)__shfl(g, jj + 5) * 64 + lane];
                unsigned u6 = xrtn_b[(size_t)__shfl(g, jj + 6) * 64 + lane];
                unsigned u7 = xrtn_b[(size_t)__shfl(g, jj + 7) * 64 + lane];
                a0 = fmaf(w0, bu2f((unsigned short)(u0 & 0xffff)), a0);
                a1 = fmaf(w0, bu2f((unsigned short)(u0 >> 16)), a1);
                a0 = fmaf(w1, bu2f((unsigned short)(u1 & 0xffff)), a0);
                a1 = fmaf(w1, bu2f((unsigned short)(u1 >> 16)), a1);
                a0 = fmaf(w2, bu2f((unsigned short)(u2 & 0xffff)), a0);
                a1 = fmaf(w2, bu2f((unsigned short)(u2 >> 16)), a1);
                a0 = fmaf(w3, bu2f((unsigned short)(u3 & 0xffff)), a0);
                a1 = fmaf(w3, bu2f((unsigned short)(u3 >> 16)), a1);
                a0 = fmaf(w4, bu2f((unsigned short)(u4 & 0xffff)), a0);
                a1 = fmaf(w4, bu2f((unsigned short)(u4 >> 16)), a1);
                a0 = fmaf(w5, bu2f((unsigned short)(u5 & 0xffff)), a0);
                a1 = fmaf(w5, bu2f((unsigned short)(u5 >> 16)), a1);
                a0 = fmaf(w6, bu2f((unsigned short)(u6 & 0xffff)), a0);
                a1 = fmaf(w6, bu2f((unsigned short)(u6 >> 16)), a1);
                a0 = fmaf(w7, bu2f((unsigned short)(u7 & 0xffff)), a0);
                a1 = fmaf(w7, bu2f((unsigned short)(u7 >> 16)), a1);
            }
            for (; jj < lim; jj++) {
                float wj = __shfl(wv, jj);
                unsigned u = xrtn_b[(size_t)__shfl(g, jj) * 64 + lane];
                a0 = fmaf(wj, bu2f((unsigned short)(u & 0xffff)), a0);
                a1 = fmaf(wj, bu2f((unsigned short)(u >> 16)), a1);
            }
        }
    }
    *(float2*)&xclass[(size_t)c * 128 + 2 * lane] = make_float2(a0, a1);
    // fused class-level dot: e_c = xclass[c]·ac + eh4[hclass[c]]
    float p = wred(a0 * ac[2 * lane] + a1 * ac[2 * lane + 1]);
    if (lane == 0) {
        int hc = hclass[c];
        float z = LRELU(p + eh4[hc]);
        zc[c] = z;
        atomicMax(&m3[hc], fenc(z));
    }
}

// ---- level 3: class -> head entity ----
__global__ __launch_bounds__(256) void k_class2(const int* __restrict__ hclass,
                                                float* __restrict__ zc,
                                                const unsigned* __restrict__ m3,
                                                float* __restrict__ s3, int NC) {
    int c = blockIdx.x * 256 + threadIdx.x;
    if (c >= NC) return;
    int hc = hclass[c];
    float ex = expf(zc[c] - fdec(m3[hc]));
    zc[c] = ex;
    atomicAdd(&s3[hc], ex);
}

__global__ __launch_bounds__(256) void k_class3(
    const int* __restrict__ hclass, const float* __restrict__ zc,
    const float* __restrict__ s3, const float* __restrict__ xclass,
    float* __restrict__ xeh, int NC) {
    int lane = threadIdx.x & 63;
    int c = blockIdx.x * 4 + (threadIdx.x >> 6);
    if (c >= NC) return;
    int hc = hclass[c];
    float gama = zc[c] / (s3[hc] + 1e-16f);
    float v0 = xclass[(size_t)c * 128 + lane], v1 = xclass[(size_t)c * 128 + 64 + lane];
    atomicAdd(&xeh[(size_t)hc * 128 + lane], gama * v0);
    atomicAdd(&xeh[(size_t)hc * 128 + 64 + lane], gama * v1);
}

extern "C" void kernel_launch(void* const* d_in, const int* in_sizes, int n_in,
                              void* d_out, int out_size, void* d_ws, size_t ws_size,
                              hipStream_t stream) {
    (void)n_in; (void)out_size; (void)ws_size;
    const float* xe   = (const float*)d_in[0];
    const int*   eidx = (const int*)d_in[1];
    const int*   rel  = (const int*)d_in[2];
    const float* remb = (const float*)d_in[4];
    const int*   cidx = (const int*)d_in[5];
    const int*   hcls = (const int*)d_in[6];
    const float* ah2  = (const float*)d_in[8];
    const float* ah3  = (const float*)d_in[9];
    const float* ah4  = (const float*)d_in[10];
    const float* at2  = (const float*)d_in[12];
    const float* at3  = (const float*)d_in[13];
    const float* ar2  = (const float*)d_in[15];
    const float* ac   = (const float*)d_in[16];
    const float* wh   = (const float*)d_in[17];
    const float* wt   = (const float*)d_in[18];
    const float* hww  = (const float*)d_in[19];
    const float* hwb  = (const float*)d_in[20];
    float* out = (float*)d_out;

    const int NE = in_sizes[0] / 256;
    const int E  = in_sizes[2];
    const int NR = in_sizes[4] / 128;
    const int NC = in_sizes[6];
    const int* hidx = eidx;
    const int* tidx = eidx + E;

    char* base = (char*)d_ws;
    size_t off0 = 0;
    auto alloc = [&](size_t bytes) -> char* {
        char* r = base + off0;
        off0 = (off0 + bytes + 255) & ~(size_t)255;
        return r;
    };
    float* hb   = (float*)alloc((size_t)NE * 4);
    float* eh4b = (float*)alloc((size_t)NE * 4);
    float* ta   = (float*)alloc((size_t)NE * 4);
    float* er2b = (float*)alloc((size_t)NR * 4);
    float* e2s  = (float*)alloc((size_t)E * 4);
    int*   gs   = (int*)alloc((size_t)E * 4);
    float* zc   = (float*)alloc((size_t)NC * 4);
    unsigned short* wtb_hi = (unsigned short*)alloc((size_t)256 * 256 * 2);
    unsigned short* wtb_lo = (unsigned short*)alloc((size_t)256 * 256 * 2);
    unsigned short* hwt_hi = (unsigned short*)alloc((size_t)128 * 128 * 2);
    unsigned short* hwt_lo = (unsigned short*)alloc((size_t)128 * 128 * 2);
    unsigned short* a_hi   = (unsigned short*)alloc((size_t)NE * 256 * 2);
    unsigned short* xrh_hi = (unsigned short*)alloc((size_t)NE * 128 * 2);
    unsigned short* xrtn   = (unsigned short*)alloc((size_t)NE * 128 * 2);
    int* offb = (int*)alloc((size_t)NC * 4);
    int* curb = (int*)alloc((size_t)NC * 4);
    float* xclass = (float*)alloc((size_t)NC * 128 * 4);
    size_t zoff = off0;  // everything below is zero-initialized per launch
    unsigned* m3 = (unsigned*)alloc((size_t)NE * 4);
    float* s3    = (float*)alloc((size_t)NE * 4);
    int* cntb    = (int*)alloc((size_t)NC * 4);
    float* xeh   = (float*)alloc((size_t)NE * 128 * 4);
    size_t zbytes = off0 - zoff;

    hipMemsetAsync(base + zoff, 0, zbytes, stream);

    k_convW<<<(256 * 256 + 128 * 128 + 255) / 256, 256, 0, stream>>>(
        wh, wt, hww, wtb_hi, wtb_lo, hwt_hi, hwt_lo);
    long n8 = (long)NE * 256 / 8;
    k_convA<<<(int)((n8 + 255) / 256), 256, 0, stream>>>(xe, a_hi, n8);
    k_rel<<<(NR + 3) / 4, 256, 0, stream>>>(remb, ar2, er2b, NR);

    // projection GEMM: row-wave tiling, pre-normalized xrt, fused dots
    k_mm_proj<<<((NE + 127) / 128) * 2, 256, 0, stream>>>(
        a_hi, wtb_hi, wtb_lo, xrh_hi, xrtn, NE,
        ah2, ah3, ah4, at2, at3, hb, eh4b, ta);

    // class-CSR histogram/scan
    k_hist<<<(E + 255) / 256, 256, 0, stream>>>(cidx, cntb, E);
    k_scan<<<1, 1024, 0, stream>>>(cntb, offb, curb, NC);

    // fused level-2 logit + scatter (level-1 softmax cancels vs F.normalize)
    k_edgescatter<<<(E + 255) / 256, 256, 0, stream>>>(
        cidx, curb, hidx, tidx, rel, ta, hb, er2b, e2s, gs, E);

    k_spmm2<<<(NC + 3) / 4, 256, 0, stream>>>(offb, cntb, e2s, gs,
                                              (const unsigned*)xrtn, xclass,
                                              ac, eh4b, hcls, zc, m3, NC);
    k_class2<<<(NC + 255) / 256, 256, 0, stream>>>(hcls, zc, m3, s3, NC);
    k_class3<<<(NC + 3) / 4, 256, 0, stream>>>(hcls, zc, s3, xclass, xeh, NC);

    k_mm_hw<<<(NE + 127) / 128, 256, 0, stream>>>(
        xrh_hi, hwt_hi, hwt_lo, out, hwb, xeh, NE);
}

// Round 14
// 317.114 us; speedup vs baseline: 2.1229x; 1.0835x over previous
//
#include <hip/hip_runtime.h>
#include <hip/hip_bf16.h>

#define LRELU(x) ((x) >= 0.f ? (x) : 0.01f * (x))

typedef __attribute__((ext_vector_type(8))) short short8v;
typedef __attribute__((ext_vector_type(4))) float f32x4;

__device__ inline unsigned fenc(float x) {
    unsigned u = __float_as_uint(x);
    return (u & 0x80000000u) ? ~u : (u | 0x80000000u);
}
__device__ inline float fdec(unsigned e) {
    return __uint_as_float((e & 0x80000000u) ? (e ^ 0x80000000u) : ~e);
}

__device__ inline float wred(float v) {
#pragma unroll
    for (int o = 32; o > 0; o >>= 1) v += __shfl_xor(v, o, 64);
    return v;
}
__device__ inline float wredmax(float v) {
#pragma unroll
    for (int o = 32; o > 0; o >>= 1) v = fmaxf(v, __shfl_xor(v, o, 64));
    return v;
}

__device__ inline unsigned short f2bu(float x) {
    __hip_bfloat16 b = __float2bfloat16(x);
    return *reinterpret_cast<unsigned short*>(&b);
}
__device__ inline float bu2f(unsigned short u) {
    return __uint_as_float((unsigned)u << 16);
}

__device__ inline f32x4 mfma16(short8v a, short8v b, f32x4 c) {
    return __builtin_amdgcn_mfma_f32_16x16x32_bf16(a, b, c, 0, 0, 0);
}

// async global->LDS, 16B per lane, dest = (wave-uniform base) + lane*16
__device__ inline void gload16(const void* g, void* l) {
    __builtin_amdgcn_global_load_lds(
        (const __attribute__((address_space(1))) void*)g,
        (__attribute__((address_space(3))) void*)l, 16, 0, 0);
}

// ---- convert W matrices to transposed hi/lo bf16: Wt[n][k] = W[k][n] ----
__global__ __launch_bounds__(256) void k_convW(
    const float* __restrict__ wh, const float* __restrict__ wt,
    const float* __restrict__ hww, unsigned short* __restrict__ wtb_hi,
    unsigned short* __restrict__ wtb_lo, unsigned short* __restrict__ hwt_hi,
    unsigned short* __restrict__ hwt_lo) {
    int id = blockIdx.x * 256 + threadIdx.x;
    if (id < 256 * 256) {
        int n = id >> 8, k = id & 255;
        float v = (n < 128) ? wh[(size_t)k * 128 + n] : wt[(size_t)k * 128 + (n - 128)];
        unsigned short h = f2bu(v);
        float r = v - bu2f(h);
        wtb_hi[(size_t)n * 256 + k] = h;
        wtb_lo[(size_t)n * 256 + k] = f2bu(r);
    } else {
        int id2 = id - 256 * 256;
        if (id2 < 128 * 128) {
            int n = id2 >> 7, k = id2 & 127;
            float v = hww[(size_t)k * 128 + n];
            unsigned short h = f2bu(v);
            float r = v - bu2f(h);
            hwt_hi[(size_t)n * 128 + k] = h;
            hwt_lo[(size_t)n * 128 + k] = f2bu(r);
        }
    }
}

// ---- convert A (x_e) to bf16, row-major [NE][256] ----
__global__ __launch_bounds__(256) void k_convA(const float* __restrict__ x,
                                               unsigned short* __restrict__ hi,
                                               long n8) {
    long i = (long)blockIdx.x * 256 + threadIdx.x;
    if (i >= n8) return;
    const float4* xp = (const float4*)(x + i * 8);
    float4 a = xp[0], b = xp[1];
    float xs[8] = {a.x, a.y, a.z, a.w, b.x, b.y, b.z, b.w};
    short8v vh;
#pragma unroll
    for (int j = 0; j < 8; j++) vh[j] = (short)f2bu(xs[j]);
    *(short8v*)(hi + i * 8) = vh;
}

// ---- relation dot: er2[r] = r_emb[r]·a_r2 ----
__global__ __launch_bounds__(256) void k_rel(const float* __restrict__ remb,
                                             const float* __restrict__ ar2,
                                             float* __restrict__ er2, int NR) {
    int lane = threadIdx.x & 63;
    int r = blockIdx.x * 4 + (threadIdx.x >> 6);
    if (r >= NR) return;
    float v0 = remb[(size_t)r * 128 + lane];
    float v1 = remb[(size_t)r * 128 + 64 + lane];
    float p2 = wred(v0 * ar2[lane] + v1 * ar2[64 + lane]);
    if (lane == 0) er2[r] = p2;
}

// ---- pack per-entity {ta, g=tidx[n]} for single 8B gathers in edgescatter ----
__global__ __launch_bounds__(256) void k_pack(const float* __restrict__ ta,
                                              const int* __restrict__ tidx,
                                              float2* __restrict__ pta, int NE) {
    int n = blockIdx.x * 256 + threadIdx.x;
    if (n >= NE) return;
    pta[n] = make_float2(ta[n], __int_as_float(tidx[n]));
}

// ---- 2-phase double-buffered LDS-staged MFMA GEMM (T3 minimum recipe) ----
// Block 128x128; row-wave tiling (wave w: rows w*32..+31, all 128 cols,
// acc[2][8]). Per step: STAGE(next buf) -> ds_read+MFMA(cur) -> barrier.
// Loads for step s+1 fly under step s's compute; one barrier/step.
// EPI 0 (proj, KD=256): half0 -> oh0=bf16(relu(xe@wh)), hb, eh4o;
//   half1 -> oh1=bf16(relu(xe@wt)*inv) pre-normalized, ta.
// EPI 1 (highway, KD=128): gate=sigmoid(C+bias); o0 = g*xeh + (1-g)*bf16(A).
template <int EPI>
__device__ __forceinline__ void mm_body(
    const unsigned short* __restrict__ Ah,
    const unsigned short* __restrict__ Bh, const unsigned short* __restrict__ Bl,
    unsigned short* __restrict__ oh0, unsigned short* __restrict__ oh1,
    float* __restrict__ o0, const float* __restrict__ bias,
    const float* __restrict__ xeh, int M,
    const float* __restrict__ ah2, const float* __restrict__ ah3,
    const float* __restrict__ ah4, const float* __restrict__ at2,
    const float* __restrict__ at3,
    float* __restrict__ hb, float* __restrict__ eh4o, float* __restrict__ ta) {
    constexpr int KD = (EPI == 0) ? 256 : 128;
    constexpr int NSTEP = KD / 32;
    __shared__ unsigned short As_h[2][128 * 32];
    __shared__ unsigned short Bs_h[2][128 * 32];
    __shared__ unsigned short Bs_l[2][128 * 32];

    int bx = blockIdx.x;
    int half = (EPI == 0) ? (bx & 1) : 0;
    int mblk = (EPI == 0) ? (bx >> 1) : bx;
    int row0 = mblk * 128;
    if (row0 + 128 > M) row0 = M - 128;
    int tid = threadIdx.x, w = tid >> 6, l = tid & 63;
    int lr = l & 15, hi4 = l >> 4;
    int srow = l >> 2, sslot = l & 3;

    f32x4 acc[2][8];
#pragma unroll
    for (int i = 0; i < 2; i++)
#pragma unroll
        for (int j = 0; j < 8; j++) acc[i][j] = (f32x4){0.f, 0.f, 0.f, 0.f};

    auto stage = [&](int s, int b) {
        int k0 = s * 32;
#pragma unroll
        for (int i = 0; i < 6; i++) {            // 24 units of 1KB, 6/wave
            int u = w * 6 + i;
            int arr = u >> 3, ld = u & 7;
            int row = ld * 16 + srow;
            int klog = (sslot ^ ((row >> 1) & 3)) * 8;
            const unsigned short* src;
            unsigned short* dst;
            if (arr == 0)      { src = Ah + (size_t)(row0 + row) * KD; dst = As_h[b]; }
            else if (arr == 1) {
                src = Bh + (size_t)((EPI == 0 ? half * 128 : 0) + row) * KD;
                dst = Bs_h[b];
            } else {
                src = Bl + (size_t)((EPI == 0 ? half * 128 : 0) + row) * KD;
                dst = Bs_l[b];
            }
            gload16(src + k0 + klog, dst + ld * 512);
        }
    };

    stage(0, 0);
    __syncthreads();                              // buf0 ready
    for (int s = 0; s < NSTEP; s++) {
        int b = s & 1;
        if (s + 1 < NSTEP) stage(s + 1, b ^ 1);  // loads fly under compute

        short8v am_h[2];
#pragma unroll
        for (int mr = 0; mr < 2; mr++) {
            int r = w * 32 + mr * 16 + lr;
            int ko = (hi4 ^ ((r >> 1) & 3)) * 8;
            am_h[mr] = *(const short8v*)&As_h[b][r * 32 + ko];
        }
#pragma unroll
        for (int ncc = 0; ncc < 8; ncc += 4) {   // split B loads: cap VGPR
            short8v bn_h[4], bn_l[4];
#pragma unroll
            for (int j = 0; j < 4; j++) {
                int n = (ncc + j) * 16 + lr;
                int ko = (hi4 ^ ((n >> 1) & 3)) * 8;
                bn_h[j] = *(const short8v*)&Bs_h[b][n * 32 + ko];
                bn_l[j] = *(const short8v*)&Bs_l[b][n * 32 + ko];
            }
#pragma unroll
            for (int mr = 0; mr < 2; mr++)
#pragma unroll
                for (int j = 0; j < 4; j++) {
                    acc[mr][ncc + j] = mfma16(am_h[mr], bn_h[j], acc[mr][ncc + j]);
                    acc[mr][ncc + j] = mfma16(am_h[mr], bn_l[j], acc[mr][ncc + j]);
                }
        }
        __syncthreads();  // drains next-buf loads + protects buffer swap
    }

    if constexpr (EPI == 0) {
        unsigned short* OH = half ? oh1 : oh0;
        const float* v1 = half ? at2 : ah2;
        const float* v2 = half ? at3 : ah3;
#pragma unroll
        for (int mr = 0; mr < 2; mr++)
#pragma unroll
            for (int rr = 0; rr < 4; rr++) {
                int row = row0 + w * 32 + mr * 16 + hi4 * 4 + rr;
                float d0 = 0.f, d1 = 0.f, d2 = 0.f;
#pragma unroll
                for (int nc = 0; nc < 8; nc++) {
                    float v = fmaxf(acc[mr][nc][rr], 0.f);
                    int col = nc * 16 + lr;
                    d0 = fmaf(v, v1[col], d0);
                    d1 = fmaf(v, v2[col], d1);
                    d2 = half ? fmaf(v, v, d2) : fmaf(v, ah4[col], d2);
                }
#pragma unroll
                for (int o = 1; o <= 8; o <<= 1) {   // reduce within 16-lane group
                    d0 += __shfl_xor(d0, o, 64);
                    d1 += __shfl_xor(d1, o, 64);
                    d2 += __shfl_xor(d2, o, 64);
                }
                float inv = 1.f;
                if (half) inv = 1.f / fmaxf(sqrtf(d2), 1e-12f);
#pragma unroll
                for (int nc = 0; nc < 8; nc++) {
                    float v = fmaxf(acc[mr][nc][rr], 0.f);
                    OH[(size_t)row * 128 + nc * 16 + lr] = f2bu(half ? v * inv : v);
                }
                if (lr == 0) {
                    if (half == 0) {
                        hb[row] = d0 + 0.25f * d1;
                        eh4o[row] = d2;
                    } else {
                        ta[row] = (d0 + 0.25f * d1) * inv;
                    }
                }
            }
    } else {
#pragma unroll
        for (int mr = 0; mr < 2; mr++)
#pragma unroll
            for (int rr = 0; rr < 4; rr++) {
                int row = row0 + w * 32 + mr * 16 + hi4 * 4 + rr;
#pragma unroll
                for (int nc = 0; nc < 8; nc++) {
                    int col = nc * 16 + lr;
                    float a = acc[mr][nc][rr] + bias[col];
                    float g = 1.f / (1.f + expf(-a));
                    size_t o = (size_t)row * 128 + col;
                    float af = bu2f(Ah[o]);
                    o0[o] = g * xeh[o] + (1.f - g) * af;
                }
            }
    }
}

__global__ __launch_bounds__(256) void k_mm_proj(
    const unsigned short* Ah, const unsigned short* Bh, const unsigned short* Bl,
    unsigned short* oh0, unsigned short* oh1, int M,
    const float* ah2, const float* ah3, const float* ah4,
    const float* at2, const float* at3,
    float* hb, float* eh4o, float* ta) {
    mm_body<0>(Ah, Bh, Bl, oh0, oh1, nullptr, nullptr, nullptr, M,
               ah2, ah3, ah4, at2, at3, hb, eh4o, ta);
}

__global__ __launch_bounds__(256) void k_mm_hw(
    const unsigned short* Ah, const unsigned short* Bh, const unsigned short* Bl,
    float* o0, const float* bias, const float* xeh, int M) {
    mm_body<1>(Ah, Bh, Bl, nullptr, nullptr, o0, bias, xeh, M,
               nullptr, nullptr, nullptr, nullptr, nullptr,
               nullptr, nullptr, nullptr);
}

// ---- counting sort by class_index ----
__global__ __launch_bounds__(256) void k_hist(const int* __restrict__ cidx,
                                              int* __restrict__ cnt, int E) {
    int i = blockIdx.x * 256 + threadIdx.x;
    if (i >= E) return;
    atomicAdd(&cnt[cidx[i]], 1);
}

__global__ __launch_bounds__(1024) void k_scan(const int* __restrict__ cnt,
                                               int* __restrict__ off,
                                               int* __restrict__ cur, int NC) {
    __shared__ int wt[16];
    __shared__ int sbase;
    int tid = threadIdx.x, w = tid >> 6, lane = tid & 63;
    if (tid == 0) sbase = 0;
    __syncthreads();
    for (int c0 = 0; c0 < NC; c0 += 1024) {
        int c = c0 + tid;
        int v = (c < NC) ? cnt[c] : 0;
        int x = v;
#pragma unroll
        for (int o = 1; o < 64; o <<= 1) {
            int t = __shfl_up(x, o, 64);
            if (lane >= o) x += t;
        }
        if (lane == 63) wt[w] = x;
        __syncthreads();
        int pre = 0, tot = 0;
#pragma unroll
        for (int i = 0; i < 16; i++) {
            int t = wt[i];
            tot += t;
            if (i < w) pre += t;
        }
        int excl = sbase + pre + x - v;
        if (c < NC) { off[c] = excl; cur[c] = excl; }
        __syncthreads();
        if (tid == 0) sbase += tot;
        __syncthreads();
    }
}

// ---- fused level-2 logit + scatter (packed 8B gather + packed 8B write) ----
// z2 = lrelu(pta[te].ta + hb[h] + 0.5*er2[rel]); g = pta[te].g
__global__ __launch_bounds__(256) void k_edgescatter(
    const int* __restrict__ cidx, int* __restrict__ cur,
    const int* __restrict__ hidx, const int* __restrict__ tidx,
    const int* __restrict__ rel, const float2* __restrict__ pta,
    const float* __restrict__ hb, const float* __restrict__ er2,
    float2* __restrict__ e2gs, int E) {
    int i = blockIdx.x * 256 + threadIdx.x;
    if (i >= E) return;
    int pos = atomicAdd(&cur[cidx[i]], 1);
    float2 p = pta[tidx[i]];
    float z2 = p.x + hb[hidx[i]] + 0.5f * er2[rel[i]];
    e2gs[pos] = make_float2(LRELU(z2), p.y);
}

// ---- fused level-2 softmax + spmm + class-dot, one wave/class ----
// rows gathered from PRE-NORMALIZED bf16 xrtn; e2gs = {logit, g} pairs.
__global__ __launch_bounds__(256) void k_spmm2(
    const int* __restrict__ off, const int* __restrict__ cnt,
    const float2* __restrict__ e2gs, const unsigned* __restrict__ xrtn_b,
    float* __restrict__ xclass, const float* __restrict__ ac,
    const float* __restrict__ eh4, const int* __restrict__ hclass,
    float* __restrict__ zc, unsigned* __restrict__ m3, int NC) {
    int lane = threadIdx.x & 63;
    int c = blockIdx.x * 4 + (threadIdx.x >> 6);
    if (c >= NC) return;
    int n = cnt[c];
    float a0 = 0.f, a1 = 0.f;
    if (n > 0) {
        int base = off[c];
        float m = -3.4e38f, s = 0.f;
        for (int j = lane; j < n; j += 64) {
            float z = e2gs[base + j].x;
            if (z > m) { s = s * __expf(m - z) + 1.f; m = z; }
            else s += __expf(z - m);
        }
        float M = wredmax(m);
        s = wred(s * __expf(m - M));
        float inv = 1.f / (s + 1e-16f);
        for (int j0 = 0; j0 < n; j0 += 64) {
            int lim = n - j0;
            if (lim > 64) lim = 64;
            float wv = 0.f;
            int g = 0;
            if (lane < lim) {
                float2 pg = e2gs[base + j0 + lane];
                wv = __expf(pg.x - M) * inv;
                g = __float_as_int(pg.y);
            }
            int jj = 0;
            for (; jj + 8 <= lim; jj += 8) {  // 8 rows in flight, 256B each
                float w0 = __shfl(wv, jj + 0), w1 = __shfl(wv, jj + 1);
                float w2 = __shfl(wv, jj + 2), w3 = __shfl(wv, jj + 3);
                float w4 = __shfl(wv, jj + 4), w5 = __shfl(wv, jj + 5);
                float w6 = __shfl(wv, jj + 6), w7 = __shfl(wv, jj + 7);
                unsigned u0 = xrtn_b[(size_t)__shfl(g, jj + 0) * 64 + lane];
                unsigned u1 = xrtn_b[(size_t)__shfl(g, jj + 1) * 64 + lane];
                unsigned u2 = xrtn_b[(size_t)__shfl(g, jj + 2) * 64 + lane];
                unsigned u3 = xrtn_b[(size_t)__shfl(g, jj + 3) * 64 + lane];
                unsigned u4 = xrtn_b[(size_t)__shfl(g, jj + 4) * 64 + lane];
                unsigned u5 = xrtn_b[(size_t)__shfl(g, jj + 5) * 64 + lane];
                unsigned u6 = xrtn_b[(size_t)__shfl(g, jj + 6) * 64 + lane];
                unsigned u7 = xrtn_b[(size_t)__shfl(g, jj + 7) * 64 + lane];
                a0 = fmaf(w0, bu2f((unsigned short)(u0 & 0xffff)), a0);
                a1 = fmaf(w0, bu2f((unsigned short)(u0 >> 16)), a1);
                a0 = fmaf(w1, bu2f((unsigned short)(u1 & 0xffff)), a0);
                a1 = fmaf(w1, bu2f((unsigned short)(u1 >> 16)), a1);
                a0 = fmaf(w2, bu2f((unsigned short)(u2 & 0xffff)), a0);
                a1 = fmaf(w2, bu2f((unsigned short)(u2 >> 16)), a1);
                a0 = fmaf(w3, bu2f((unsigned short)(u3 & 0xffff)), a0);
                a1 = fmaf(w3, bu2f((unsigned short)(u3 >> 16)), a1);
                a0 = fmaf(w4, bu2f((unsigned short)(u4 & 0xffff)), a0);
                a1 = fmaf(w4, bu2f((unsigned short)(u4 >> 16)), a1);
                a0 = fmaf(w5, bu2f((unsigned short)(u5 & 0xffff)), a0);
                a1 = fmaf(w5, bu2f((unsigned short)(u5 >> 16)), a1);
                a0 = fmaf(w6, bu2f((unsigned short)(u6 & 0xffff)), a0);
                a1 = fmaf(w6, bu2f((unsigned short)(u6 >> 16)), a1);
                a0 = fmaf(w7, bu2f((unsigned short)(u7 & 0xffff)), a0);
                a1 = fmaf(w7, bu2f((unsigned short)(u7 >> 16)), a1);
            }
            for (; jj < lim; jj++) {
                float wj = __shfl(wv, jj);
                unsigned u = xrtn_b[(size_t)__shfl(g, jj) * 64 + lane];
                a0 = fmaf(wj, bu2f((unsigned short)(u & 0xffff)), a0);
                a1 = fmaf(wj, bu2f((unsigned short)(u >> 16)), a1);
            }
        }
    }
    *(float2*)&xclass[(size_t)c * 128 + 2 * lane] = make_float2(a0, a1);
    // fused class-level dot: e_c = xclass[c]·ac + eh4[hclass[c]]
    float p = wred(a0 * ac[2 * lane] + a1 * ac[2 * lane + 1]);
    if (lane == 0) {
        int hc = hclass[c];
        float z = LRELU(p + eh4[hc]);
        zc[c] = z;
        atomicMax(&m3[hc], fenc(z));
    }
}

// ---- level 3: class -> head entity ----
__global__ __launch_bounds__(256) void k_class2(const int* __restrict__ hclass,
                                                float* __restrict__ zc,
                                                const unsigned* __restrict__ m3,
                                                float* __restrict__ s3, int NC) {
    int c = blockIdx.x * 256 + threadIdx.x;
    if (c >= NC) return;
    int hc = hclass[c];
    float ex = expf(zc[c] - fdec(m3[hc]));
    zc[c] = ex;
    atomicAdd(&s3[hc], ex);
}

__global__ __launch_bounds__(256) void k_class3(
    const int* __restrict__ hclass, const float* __restrict__ zc,
    const float* __restrict__ s3, const float* __restrict__ xclass,
    float* __restrict__ xeh, int NC) {
    int lane = threadIdx.x & 63;
    int c = blockIdx.x * 4 + (threadIdx.x >> 6);
    if (c >= NC) return;
    int hc = hclass[c];
    float gama = zc[c] / (s3[hc] + 1e-16f);
    float v0 = xclass[(size_t)c * 128 + lane], v1 = xclass[(size_t)c * 128 + 64 + lane];
    atomicAdd(&xeh[(size_t)hc * 128 + lane], gama * v0);
    atomicAdd(&xeh[(size_t)hc * 128 + 64 + lane], gama * v1);
}

extern "C" void kernel_launch(void* const* d_in, const int* in_sizes, int n_in,
                              void* d_out, int out_size, void* d_ws, size_t ws_size,
                              hipStream_t stream) {
    (void)n_in; (void)out_size; (void)ws_size;
    const float* xe   = (const float*)d_in[0];
    const int*   eidx = (const int*)d_in[1];
    const int*   rel  = (const int*)d_in[2];
    const float* remb = (const float*)d_in[4];
    const int*   cidx = (const int*)d_in[5];
    const int*   hcls = (const int*)d_in[6];
    const float* ah2  = (const float*)d_in[8];
    const float* ah3  = (const float*)d_in[9];
    const float* ah4  = (const float*)d_in[10];
    const float* at2  = (const float*)d_in[12];
    const float* at3  = (const float*)d_in[13];
    const float* ar2  = (const float*)d_in[15];
    const float* ac   = (const float*)d_in[16];
    const float* wh   = (const float*)d_in[17];
    const float* wt   = (const float*)d_in[18];
    const float* hww  = (const float*)d_in[19];
    const float* hwb  = (const float*)d_in[20];
    float* out = (float*)d_out;

    const int NE = in_sizes[0] / 256;
    const int E  = in_sizes[2];
    const int NR = in_sizes[4] / 128;
    const int NC = in_sizes[6];
    const int* hidx = eidx;
    const int* tidx = eidx + E;

    char* base = (char*)d_ws;
    size_t off0 = 0;
    auto alloc = [&](size_t bytes) -> char* {
        char* r = base + off0;
        off0 = (off0 + bytes + 255) & ~(size_t)255;
        return r;
    };
    float* hb   = (float*)alloc((size_t)NE * 4);
    float* eh4b = (float*)alloc((size_t)NE * 4);
    float* ta   = (float*)alloc((size_t)NE * 4);
    float2* pta = (float2*)alloc((size_t)NE * 8);
    float* er2b = (float*)alloc((size_t)NR * 4);
    float2* e2gs = (float2*)alloc((size_t)E * 8);
    float* zc   = (float*)alloc((size_t)NC * 4);
    unsigned short* wtb_hi = (unsigned short*)alloc((size_t)256 * 256 * 2);
    unsigned short* wtb_lo = (unsigned short*)alloc((size_t)256 * 256 * 2);
    unsigned short* hwt_hi = (unsigned short*)alloc((size_t)128 * 128 * 2);
    unsigned short* hwt_lo = (unsigned short*)alloc((size_t)128 * 128 * 2);
    unsigned short* a_hi   = (unsigned short*)alloc((size_t)NE * 256 * 2);
    unsigned short* xrh_hi = (unsigned short*)alloc((size_t)NE * 128 * 2);
    unsigned short* xrtn   = (unsigned short*)alloc((size_t)NE * 128 * 2);
    int* offb = (int*)alloc((size_t)NC * 4);
    int* curb = (int*)alloc((size_t)NC * 4);
    float* xclass = (float*)alloc((size_t)NC * 128 * 4);
    size_t zoff = off0;  // everything below is zero-initialized per launch
    unsigned* m3 = (unsigned*)alloc((size_t)NE * 4);
    float* s3    = (float*)alloc((size_t)NE * 4);
    int* cntb    = (int*)alloc((size_t)NC * 4);
    float* xeh   = (float*)alloc((size_t)NE * 128 * 4);
    size_t zbytes = off0 - zoff;

    hipMemsetAsync(base + zoff, 0, zbytes, stream);

    k_convW<<<(256 * 256 + 128 * 128 + 255) / 256, 256, 0, stream>>>(
        wh, wt, hww, wtb_hi, wtb_lo, hwt_hi, hwt_lo);
    long n8 = (long)NE * 256 / 8;
    k_convA<<<(int)((n8 + 255) / 256), 256, 0, stream>>>(xe, a_hi, n8);
    k_rel<<<(NR + 3) / 4, 256, 0, stream>>>(remb, ar2, er2b, NR);

    // projection GEMM: 2-phase double-buffered staging, pre-normalized xrt
    k_mm_proj<<<((NE + 127) / 128) * 2, 256, 0, stream>>>(
        a_hi, wtb_hi, wtb_lo, xrh_hi, xrtn, NE,
        ah2, ah3, ah4, at2, at3, hb, eh4b, ta);

    // class-CSR histogram/scan
    k_hist<<<(E + 255) / 256, 256, 0, stream>>>(cidx, cntb, E);
    k_scan<<<1, 1024, 0, stream>>>(cntb, offb, curb, NC);

    // pack per-entity {ta, tidx[n]} records
    k_pack<<<(NE + 255) / 256, 256, 0, stream>>>(ta, tidx, pta, NE);

    // fused level-2 logit + scatter (level-1 softmax cancels vs F.normalize)
    k_edgescatter<<<(E + 255) / 256, 256, 0, stream>>>(
        cidx, curb, hidx, tidx, rel, pta, hb, er2b, e2gs, E);

    k_spmm2<<<(NC + 3) / 4, 256, 0, stream>>>(offb, cntb, e2gs,
                                              (const unsigned*)xrtn, xclass,
                                              ac, eh4b, hcls, zc, m3, NC);
    k_class2<<<(NC + 255) / 256, 256, 0, stream>>>(hcls, zc, m3, s3, NC);
    k_class3<<<(NC + 3) / 4, 256, 0, stream>>>(hcls, zc, s3, xclass, xeh, NC);

    k_mm_hw<<<(NE + 127) / 128, 256, 0, stream>>>(
        xrh_hi, hwt_hi, hwt_lo, out, hwb, xeh, NE);
}

// Round 15
// 297.790 us; speedup vs baseline: 2.2606x; 1.0649x over previous
//
#include <hip/hip_runtime.h>
#include <hip/hip_bf16.h>

#define LRELU(x) ((x) >= 0.f ? (x) : 0.01f * (x))

typedef __attribute__((ext_vector_type(8))) short short8v;
typedef __attribute__((ext_vector_type(4))) float f32x4;

__device__ inline unsigned fenc(float x) {
    unsigned u = __float_as_uint(x);
    return (u & 0x80000000u) ? ~u : (u | 0x80000000u);
}
__device__ inline float fdec(unsigned e) {
    return __uint_as_float((e & 0x80000000u) ? (e ^ 0x80000000u) : ~e);
}

__device__ inline float wred(float v) {
#pragma unroll
    for (int o = 32; o > 0; o >>= 1) v += __shfl_xor(v, o, 64);
    return v;
}
__device__ inline float wredmax(float v) {
#pragma unroll
    for (int o = 32; o > 0; o >>= 1) v = fmaxf(v, __shfl_xor(v, o, 64));
    return v;
}

__device__ inline unsigned short f2bu(float x) {
    __hip_bfloat16 b = __float2bfloat16(x);
    return *reinterpret_cast<unsigned short*>(&b);
}
__device__ inline float bu2f(unsigned short u) {
    return __uint_as_float((unsigned)u << 16);
}

__device__ inline f32x4 mfma16(short8v a, short8v b, f32x4 c) {
    return __builtin_amdgcn_mfma_f32_16x16x32_bf16(a, b, c, 0, 0, 0);
}

// async global->LDS, 16B per lane, dest = (wave-uniform base) + lane*16
__device__ inline void gload16(const void* g, void* l) {
    __builtin_amdgcn_global_load_lds(
        (const __attribute__((address_space(1))) void*)g,
        (__attribute__((address_space(3))) void*)l, 16, 0, 0);
}

// ---- convert W matrices to transposed hi/lo bf16: Wt[n][k] = W[k][n] ----
__global__ __launch_bounds__(256) void k_convW(
    const float* __restrict__ wh, const float* __restrict__ wt,
    const float* __restrict__ hww, unsigned short* __restrict__ wtb_hi,
    unsigned short* __restrict__ wtb_lo, unsigned short* __restrict__ hwt_hi,
    unsigned short* __restrict__ hwt_lo) {
    int id = blockIdx.x * 256 + threadIdx.x;
    if (id < 256 * 256) {
        int n = id >> 8, k = id & 255;
        float v = (n < 128) ? wh[(size_t)k * 128 + n] : wt[(size_t)k * 128 + (n - 128)];
        unsigned short h = f2bu(v);
        float r = v - bu2f(h);
        wtb_hi[(size_t)n * 256 + k] = h;
        wtb_lo[(size_t)n * 256 + k] = f2bu(r);
    } else {
        int id2 = id - 256 * 256;
        if (id2 < 128 * 128) {
            int n = id2 >> 7, k = id2 & 127;
            float v = hww[(size_t)k * 128 + n];
            unsigned short h = f2bu(v);
            float r = v - bu2f(h);
            hwt_hi[(size_t)n * 128 + k] = h;
            hwt_lo[(size_t)n * 128 + k] = f2bu(r);
        }
    }
}

// ---- relation dot: er2[r] = r_emb[r]·a_r2 ----
__global__ __launch_bounds__(256) void k_rel(const float* __restrict__ remb,
                                             const float* __restrict__ ar2,
                                             float* __restrict__ er2, int NR) {
    int lane = threadIdx.x & 63;
    int r = blockIdx.x * 4 + (threadIdx.x >> 6);
    if (r >= NR) return;
    float v0 = remb[(size_t)r * 128 + lane];
    float v1 = remb[(size_t)r * 128 + 64 + lane];
    float p2 = wred(v0 * ar2[lane] + v1 * ar2[64 + lane]);
    if (lane == 0) er2[r] = p2;
}

// ---- 2-phase double-buffered LDS-staged MFMA GEMM ----
// Block 128x128; row-wave tiling (wave w: rows w*32..+31, all 128 cols,
// acc[2][8]). Per step: issue next A f32 loads (EPI0) + B gloads -> MFMA(cur)
// -> cvt+ds_write next A (T14 write-late) -> barrier.
// EPI 0 (proj, KD=256, A = x_e f32 converted in-kernel):
//   half0 -> oh0=bf16(relu(xe@wh)), hb, eh4o;
//   half1 -> oh1=bf16(relu(xe@wt)*inv) pre-normalized, pta={ta, tidx[row]}.
// EPI 1 (highway, KD=128, A bf16): gate=sigmoid(C+bias); o0=g*xeh+(1-g)*bf16(A).
template <int EPI>
__device__ __forceinline__ void mm_body(
    const float* __restrict__ Af32, const unsigned short* __restrict__ Ah,
    const unsigned short* __restrict__ Bh, const unsigned short* __restrict__ Bl,
    unsigned short* __restrict__ oh0, unsigned short* __restrict__ oh1,
    float* __restrict__ o0, const float* __restrict__ bias,
    const float* __restrict__ xeh, int M,
    const float* __restrict__ ah2, const float* __restrict__ ah3,
    const float* __restrict__ ah4, const float* __restrict__ at2,
    const float* __restrict__ at3,
    float* __restrict__ hb, float* __restrict__ eh4o,
    float2* __restrict__ pta, const int* __restrict__ tidxg) {
    constexpr int KD = (EPI == 0) ? 256 : 128;
    constexpr int NSTEP = KD / 32;
    __shared__ unsigned short As_h[2][128 * 32];
    __shared__ unsigned short Bs_h[2][128 * 32];
    __shared__ unsigned short Bs_l[2][128 * 32];

    int bx = blockIdx.x;
    int half = (EPI == 0) ? (bx & 1) : 0;
    int mblk = (EPI == 0) ? (bx >> 1) : bx;
    int row0 = mblk * 128;
    if (row0 + 128 > M) row0 = M - 128;
    int tid = threadIdx.x, w = tid >> 6, l = tid & 63;
    int lr = l & 15, hi4 = l >> 4;
    int srow = l >> 2, sslot = l & 3;

    // per-thread A staging assignment (EPI 0): 2 granules of 8 f32
    int arow0 = tid >> 2, aslot0 = tid & 3;
    int arow1 = (256 + tid) >> 2, aslot1 = tid & 3;
    int agr0 = (aslot0 ^ ((arow0 >> 1) & 3)) * 8;
    int agr1 = (aslot1 ^ ((arow1 >> 1) & 3)) * 8;
    float4 a0a, a0b, a1a, a1b;

    f32x4 acc[2][8];
#pragma unroll
    for (int i = 0; i < 2; i++)
#pragma unroll
        for (int j = 0; j < 8; j++) acc[i][j] = (f32x4){0.f, 0.f, 0.f, 0.f};

    auto loadA = [&](int s) {  // EPI 0: issue f32 loads for step s
        int k0 = s * 32;
        const float* p0 = Af32 + (size_t)(row0 + arow0) * KD + k0 + agr0;
        const float* p1 = Af32 + (size_t)(row0 + arow1) * KD + k0 + agr1;
        a0a = *(const float4*)p0;
        a0b = *(const float4*)(p0 + 4);
        a1a = *(const float4*)p1;
        a1b = *(const float4*)(p1 + 4);
    };
    auto writeA = [&](int b) {  // EPI 0: cvt + ds_write into buf b
        short8v v0, v1;
        float x0[8] = {a0a.x, a0a.y, a0a.z, a0a.w, a0b.x, a0b.y, a0b.z, a0b.w};
        float x1[8] = {a1a.x, a1a.y, a1a.z, a1a.w, a1b.x, a1b.y, a1b.z, a1b.w};
#pragma unroll
        for (int j = 0; j < 8; j++) {
            v0[j] = (short)f2bu(x0[j]);
            v1[j] = (short)f2bu(x1[j]);
        }
        *(short8v*)&As_h[b][arow0 * 32 + aslot0 * 8] = v0;
        *(short8v*)&As_h[b][arow1 * 32 + aslot1 * 8] = v1;
    };
    auto stageB = [&](int s, int b) {
        int k0 = s * 32;
        constexpr int NU = (EPI == 0) ? 4 : 6;   // EPI0: 16 units; EPI1: 24
#pragma unroll
        for (int i = 0; i < NU; i++) {
            int u = w * NU + i;
            int arr = u >> 3, ld = u & 7;
            int row = ld * 16 + srow;
            int klog = (sslot ^ ((row >> 1) & 3)) * 8;
            const unsigned short* src;
            unsigned short* dst;
            if constexpr (EPI == 0) {
                src = (arr == 0 ? Bh : Bl) + (size_t)(half * 128 + row) * KD;
                dst = (arr == 0 ? Bs_h[b] : Bs_l[b]);
            } else {
                if (arr == 0)      { src = Ah + (size_t)(row0 + row) * KD; dst = As_h[b]; }
                else if (arr == 1) { src = Bh + (size_t)row * KD;          dst = Bs_h[b]; }
                else               { src = Bl + (size_t)row * KD;          dst = Bs_l[b]; }
            }
            gload16(src + k0 + klog, dst + ld * 512);
        }
    };

    if constexpr (EPI == 0) {
        loadA(0);
        stageB(0, 0);
        writeA(0);
    } else {
        stageB(0, 0);
    }
    __syncthreads();                              // buf0 ready
    for (int s = 0; s < NSTEP; s++) {
        int b = s & 1;
        if (s + 1 < NSTEP) {
            if constexpr (EPI == 0) loadA(s + 1);  // issue early (T14)
            stageB(s + 1, b ^ 1);
        }

        short8v am_h[2];
#pragma unroll
        for (int mr = 0; mr < 2; mr++) {
            int r = w * 32 + mr * 16 + lr;
            int ko = (hi4 ^ ((r >> 1) & 3)) * 8;
            am_h[mr] = *(const short8v*)&As_h[b][r * 32 + ko];
        }
#pragma unroll
        for (int ncc = 0; ncc < 8; ncc += 4) {   // split B loads: cap VGPR
            short8v bn_h[4], bn_l[4];
#pragma unroll
            for (int j = 0; j < 4; j++) {
                int n = (ncc + j) * 16 + lr;
                int ko = (hi4 ^ ((n >> 1) & 3)) * 8;
                bn_h[j] = *(const short8v*)&Bs_h[b][n * 32 + ko];
                bn_l[j] = *(const short8v*)&Bs_l[b][n * 32 + ko];
            }
#pragma unroll
            for (int mr = 0; mr < 2; mr++)
#pragma unroll
                for (int j = 0; j < 4; j++) {
                    acc[mr][ncc + j] = mfma16(am_h[mr], bn_h[j], acc[mr][ncc + j]);
                    acc[mr][ncc + j] = mfma16(am_h[mr], bn_l[j], acc[mr][ncc + j]);
                }
        }
        if constexpr (EPI == 0) {
            if (s + 1 < NSTEP) writeA(b ^ 1);    // write late, under MFMA shadow
        }
        __syncthreads();  // drains next-buf loads/writes + protects swap
    }

    if constexpr (EPI == 0) {
        unsigned short* OH = half ? oh1 : oh0;
        const float* v1 = half ? at2 : ah2;
        const float* v2 = half ? at3 : ah3;
#pragma unroll
        for (int mr = 0; mr < 2; mr++)
#pragma unroll
            for (int rr = 0; rr < 4; rr++) {
                int row = row0 + w * 32 + mr * 16 + hi4 * 4 + rr;
                float d0 = 0.f, d1 = 0.f, d2 = 0.f;
#pragma unroll
                for (int nc = 0; nc < 8; nc++) {
                    float v = fmaxf(acc[mr][nc][rr], 0.f);
                    int col = nc * 16 + lr;
                    d0 = fmaf(v, v1[col], d0);
                    d1 = fmaf(v, v2[col], d1);
                    d2 = half ? fmaf(v, v, d2) : fmaf(v, ah4[col], d2);
                }
#pragma unroll
                for (int o = 1; o <= 8; o <<= 1) {   // reduce within 16-lane group
                    d0 += __shfl_xor(d0, o, 64);
                    d1 += __shfl_xor(d1, o, 64);
                    d2 += __shfl_xor(d2, o, 64);
                }
                float inv = 1.f;
                if (half) inv = 1.f / fmaxf(sqrtf(d2), 1e-12f);
#pragma unroll
                for (int nc = 0; nc < 8; nc++) {
                    float v = fmaxf(acc[mr][nc][rr], 0.f);
                    OH[(size_t)row * 128 + nc * 16 + lr] = f2bu(half ? v * inv : v);
                }
                if (lr == 0) {
                    if (half == 0) {
                        hb[row] = d0 + 0.25f * d1;
                        eh4o[row] = d2;
                    } else {
                        float tav = (d0 + 0.25f * d1) * inv;
                        pta[row] = make_float2(tav, __int_as_float(tidxg[row]));
                    }
                }
            }
    } else {
#pragma unroll
        for (int mr = 0; mr < 2; mr++)
#pragma unroll
            for (int rr = 0; rr < 4; rr++) {
                int row = row0 + w * 32 + mr * 16 + hi4 * 4 + rr;
#pragma unroll
                for (int nc = 0; nc < 8; nc++) {
                    int col = nc * 16 + lr;
                    float a = acc[mr][nc][rr] + bias[col];
                    float g = 1.f / (1.f + expf(-a));
                    size_t o = (size_t)row * 128 + col;
                    float af = bu2f(Ah[o]);
                    o0[o] = g * xeh[o] + (1.f - g) * af;
                }
            }
    }
}

__global__ __launch_bounds__(256) void k_mm_proj(
    const float* Af32, const unsigned short* Bh, const unsigned short* Bl,
    unsigned short* oh0, unsigned short* oh1, int M,
    const float* ah2, const float* ah3, const float* ah4,
    const float* at2, const float* at3,
    float* hb, float* eh4o, float2* pta, const int* tidxg) {
    mm_body<0>(Af32, nullptr, Bh, Bl, oh0, oh1, nullptr, nullptr, nullptr, M,
               ah2, ah3, ah4, at2, at3, hb, eh4o, pta, tidxg);
}

__global__ __launch_bounds__(256) void k_mm_hw(
    const unsigned short* Ah, const unsigned short* Bh, const unsigned short* Bl,
    float* o0, const float* bias, const float* xeh, int M) {
    mm_body<1>(nullptr, Ah, Bh, Bl, nullptr, nullptr, o0, bias, xeh, M,
               nullptr, nullptr, nullptr, nullptr, nullptr,
               nullptr, nullptr, nullptr, nullptr);
}

// ---- counting sort by class_index ----
__global__ __launch_bounds__(256) void k_hist(const int* __restrict__ cidx,
                                              int* __restrict__ cnt, int E) {
    int i = blockIdx.x * 256 + threadIdx.x;
    if (i >= E) return;
    atomicAdd(&cnt[cidx[i]], 1);
}

__global__ __launch_bounds__(1024) void k_scan(const int* __restrict__ cnt,
                                               int* __restrict__ off,
                                               int* __restrict__ cur, int NC) {
    __shared__ int wt[16];
    __shared__ int sbase;
    int tid = threadIdx.x, w = tid >> 6, lane = tid & 63;
    if (tid == 0) sbase = 0;
    __syncthreads();
    for (int c0 = 0; c0 < NC; c0 += 1024) {
        int c = c0 + tid;
        int v = (c < NC) ? cnt[c] : 0;
        int x = v;
#pragma unroll
        for (int o = 1; o < 64; o <<= 1) {
            int t = __shfl_up(x, o, 64);
            if (lane >= o) x += t;
        }
        if (lane == 63) wt[w] = x;
        __syncthreads();
        int pre = 0, tot = 0;
#pragma unroll
        for (int i = 0; i < 16; i++) {
            int t = wt[i];
            tot += t;
            if (i < w) pre += t;
        }
        int excl = sbase + pre + x - v;
        if (c < NC) { off[c] = excl; cur[c] = excl; }
        __syncthreads();
        if (tid == 0) sbase += tot;
        __syncthreads();
    }
}

// ---- fused level-2 logit + scatter (packed 8B gather + packed 8B write) ----
// z2 = lrelu(pta[te].ta + hb[h] + 0.5*er2[rel]); g = pta[te].g
__global__ __launch_bounds__(256) void k_edgescatter(
    const int* __restrict__ cidx, int* __restrict__ cur,
    const int* __restrict__ hidx, const int* __restrict__ tidx,
    const int* __restrict__ rel, const float2* __restrict__ pta,
    const float* __restrict__ hb, const float* __restrict__ er2,
    float2* __restrict__ e2gs, int E) {
    int i = blockIdx.x * 256 + threadIdx.x;
    if (i >= E) return;
    int pos = atomicAdd(&cur[cidx[i]], 1);
    float2 p = pta[tidx[i]];
    float z2 = p.x + hb[hidx[i]] + 0.5f * er2[rel[i]];
    e2gs[pos] = make_float2(LRELU(z2), p.y);
}

// ---- fused level-2 softmax + spmm + class-dot, one wave/class ----
// rows gathered from PRE-NORMALIZED bf16 xrtn; e2gs = {logit, g} pairs.
__global__ __launch_bounds__(256) void k_spmm2(
    const int* __restrict__ off, const int* __restrict__ cnt,
    const float2* __restrict__ e2gs, const unsigned* __restrict__ xrtn_b,
    float* __restrict__ xclass, const float* __restrict__ ac,
    const float* __restrict__ eh4, const int* __restrict__ hclass,
    float* __restrict__ zc, unsigned* __restrict__ m3, int NC) {
    int lane = threadIdx.x & 63;
    int c = blockIdx.x * 4 + (threadIdx.x >> 6);
    if (c >= NC) return;
    int n = cnt[c];
    float a0 = 0.f, a1 = 0.f;
    if (n > 0) {
        int base = off[c];
        float m = -3.4e38f, s = 0.f;
        for (int j = lane; j < n; j += 64) {
            float z = e2gs[base + j].x;
            if (z > m) { s = s * __expf(m - z) + 1.f; m = z; }
            else s += __expf(z - m);
        }
        float M = wredmax(m);
        s = wred(s * __expf(m - M));
        float inv = 1.f / (s + 1e-16f);
        for (int j0 = 0; j0 < n; j0 += 64) {
            int lim = n - j0;
            if (lim > 64) lim = 64;
            float wv = 0.f;
            int g = 0;
            if (lane < lim) {
                float2 pg = e2gs[base + j0 + lane];
                wv = __expf(pg.x - M) * inv;
                g = __float_as_int(pg.y);
            }
            int jj = 0;
            for (; jj + 8 <= lim; jj += 8) {  // 8 rows in flight, 256B each
                float w0 = __shfl(wv, jj + 0), w1 = __shfl(wv, jj + 1);
                float w2 = __shfl(wv, jj + 2), w3 = __shfl(wv, jj + 3);
                float w4 = __shfl(wv, jj + 4), w5 = __shfl(wv, jj + 5);
                float w6 = __shfl(wv, jj + 6), w7 = __shfl(wv, jj + 7);
                unsigned u0 = xrtn_b[(size_t)__shfl(g, jj + 0) * 64 + lane];
                unsigned u1 = xrtn_b[(size_t)__shfl(g, jj + 1) * 64 + lane];
                unsigned u2 = xrtn_b[(size_t)__shfl(g, jj + 2) * 64 + lane];
                unsigned u3 = xrtn_b[(size_t)__shfl(g, jj + 3) * 64 + lane];
                unsigned u4 = xrtn_b[(size_t)__shfl(g, jj + 4) * 64 + lane];
                unsigned u5 = xrtn_b[(size_t)__shfl(g, jj + 5) * 64 + lane];
                unsigned u6 = xrtn_b[(size_t)__shfl(g, jj + 6) * 64 + lane];
                unsigned u7 = xrtn_b[(size_t)__shfl(g, jj + 7) * 64 + lane];
                a0 = fmaf(w0, bu2f((unsigned short)(u0 & 0xffff)), a0);
                a1 = fmaf(w0, bu2f((unsigned short)(u0 >> 16)), a1);
                a0 = fmaf(w1, bu2f((unsigned short)(u1 & 0xffff)), a0);
                a1 = fmaf(w1, bu2f((unsigned short)(u1 >> 16)), a1);
                a0 = fmaf(w2, bu2f((unsigned short)(u2 & 0xffff)), a0);
                a1 = fmaf(w2, bu2f((unsigned short)(u2 >> 16)), a1);
                a0 = fmaf(w3, bu2f((unsigned short)(u3 & 0xffff)), a0);
                a1 = fmaf(w3, bu2f((unsigned short)(u3 >> 16)), a1);
                a0 = fmaf(w4, bu2f((unsigned short)(u4 & 0xffff)), a0);
                a1 = fmaf(w4, bu2f((unsigned short)(u4 >> 16)), a1);
                a0 = fmaf(w5, bu2f((unsigned short)(u5 & 0xffff)), a0);
                a1 = fmaf(w5, bu2f((unsigned short)(u5 >> 16)), a1);
                a0 = fmaf(w6, bu2f((unsigned short)(u6 & 0xffff)), a0);
                a1 = fmaf(w6, bu2f((unsigned short)(u6 >> 16)), a1);
                a0 = fmaf(w7, bu2f((unsigned short)(u7 & 0xffff)), a0);
                a1 = fmaf(w7, bu2f((unsigned short)(u7 >> 16)), a1);
            }
            for (; jj < lim; jj++) {
                float wj = __shfl(wv, jj);
                unsigned u = xrtn_b[(size_t)__shfl(g, jj) * 64 + lane];
                a0 = fmaf(wj, bu2f((unsigned short)(u & 0xffff)), a0);
                a1 = fmaf(wj, bu2f((unsigned short)(u >> 16)), a1);
            }
        }
    }
    *(float2*)&xclass[(size_t)c * 128 + 2 * lane] = make_float2(a0, a1);
    // fused class-level dot: e_c = xclass[c]·ac + eh4[hclass[c]]
    float p = wred(a0 * ac[2 * lane] + a1 * ac[2 * lane + 1]);
    if (lane == 0) {
        int hc = hclass[c];
        float z = LRELU(p + eh4[hc]);
        zc[c] = z;
        atomicMax(&m3[hc], fenc(z));
    }
}

// ---- level 3: class -> head entity ----
__global__ __launch_bounds__(256) void k_class2(const int* __restrict__ hclass,
                                                float* __restrict__ zc,
                                                const unsigned* __restrict__ m3,
                                                float* __restrict__ s3, int NC) {
    int c = blockIdx.x * 256 + threadIdx.x;
    if (c >= NC) return;
    int hc = hclass[c];
    float ex = expf(zc[c] - fdec(m3[hc]));
    zc[c] = ex;
    atomicAdd(&s3[hc], ex);
}

__global__ __launch_bounds__(256) void k_class3(
    const int* __restrict__ hclass, const float* __restrict__ zc,
    const float* __restrict__ s3, const float* __restrict__ xclass,
    float* __restrict__ xeh, int NC) {
    int lane = threadIdx.x & 63;
    int c = blockIdx.x * 4 + (threadIdx.x >> 6);
    if (c >= NC) return;
    int hc = hclass[c];
    float gama = zc[c] / (s3[hc] + 1e-16f);
    float v0 = xclass[(size_t)c * 128 + lane], v1 = xclass[(size_t)c * 128 + 64 + lane];
    atomicAdd(&xeh[(size_t)hc * 128 + lane], gama * v0);
    atomicAdd(&xeh[(size_t)hc * 128 + 64 + lane], gama * v1);
}

extern "C" void kernel_launch(void* const* d_in, const int* in_sizes, int n_in,
                              void* d_out, int out_size, void* d_ws, size_t ws_size,
                              hipStream_t stream) {
    (void)n_in; (void)out_size; (void)ws_size;
    const float* xe   = (const float*)d_in[0];
    const int*   eidx = (const int*)d_in[1];
    const int*   rel  = (const int*)d_in[2];
    const float* remb = (const float*)d_in[4];
    const int*   cidx = (const int*)d_in[5];
    const int*   hcls = (const int*)d_in[6];
    const float* ah2  = (const float*)d_in[8];
    const float* ah3  = (const float*)d_in[9];
    const float* ah4  = (const float*)d_in[10];
    const float* at2  = (const float*)d_in[12];
    const float* at3  = (const float*)d_in[13];
    const float* ar2  = (const float*)d_in[15];
    const float* ac   = (const float*)d_in[16];
    const float* wh   = (const float*)d_in[17];
    const float* wt   = (const float*)d_in[18];
    const float* hww  = (const float*)d_in[19];
    const float* hwb  = (const float*)d_in[20];
    float* out = (float*)d_out;

    const int NE = in_sizes[0] / 256;
    const int E  = in_sizes[2];
    const int NR = in_sizes[4] / 128;
    const int NC = in_sizes[6];
    const int* hidx = eidx;
    const int* tidx = eidx + E;

    char* base = (char*)d_ws;
    size_t off0 = 0;
    auto alloc = [&](size_t bytes) -> char* {
        char* r = base + off0;
        off0 = (off0 + bytes + 255) & ~(size_t)255;
        return r;
    };
    float* hb   = (float*)alloc((size_t)NE * 4);
    float* eh4b = (float*)alloc((size_t)NE * 4);
    float2* pta = (float2*)alloc((size_t)NE * 8);
    float* er2b = (float*)alloc((size_t)NR * 4);
    float2* e2gs = (float2*)alloc((size_t)E * 8);
    float* zc   = (float*)alloc((size_t)NC * 4);
    unsigned short* wtb_hi = (unsigned short*)alloc((size_t)256 * 256 * 2);
    unsigned short* wtb_lo = (unsigned short*)alloc((size_t)256 * 256 * 2);
    unsigned short* hwt_hi = (unsigned short*)alloc((size_t)128 * 128 * 2);
    unsigned short* hwt_lo = (unsigned short*)alloc((size_t)128 * 128 * 2);
    unsigned short* xrh_hi = (unsigned short*)alloc((size_t)NE * 128 * 2);
    unsigned short* xrtn   = (unsigned short*)alloc((size_t)NE * 128 * 2);
    int* offb = (int*)alloc((size_t)NC * 4);
    int* curb = (int*)alloc((size_t)NC * 4);
    float* xclass = (float*)alloc((size_t)NC * 128 * 4);
    size_t zoff = off0;  // everything below is zero-initialized per launch
    unsigned* m3 = (unsigned*)alloc((size_t)NE * 4);
    float* s3    = (float*)alloc((size_t)NE * 4);
    int* cntb    = (int*)alloc((size_t)NC * 4);
    float* xeh   = (float*)alloc((size_t)NE * 128 * 4);
    size_t zbytes = off0 - zoff;

    hipMemsetAsync(base + zoff, 0, zbytes, stream);

    k_convW<<<(256 * 256 + 128 * 128 + 255) / 256, 256, 0, stream>>>(
        wh, wt, hww, wtb_hi, wtb_lo, hwt_hi, hwt_lo);
    k_rel<<<(NR + 3) / 4, 256, 0, stream>>>(remb, ar2, er2b, NR);

    // projection GEMM: reads x_e f32 directly (T14 reg-staged A), writes
    // bf16 mirrors (xrt pre-normalized) + fused dots + packed pta records
    k_mm_proj<<<((NE + 127) / 128) * 2, 256, 0, stream>>>(
        xe, wtb_hi, wtb_lo, xrh_hi, xrtn, NE,
        ah2, ah3, ah4, at2, at3, hb, eh4b, pta, tidx);

    // class-CSR histogram/scan
    k_hist<<<(E + 255) / 256, 256, 0, stream>>>(cidx, cntb, E);
    k_scan<<<1, 1024, 0, stream>>>(cntb, offb, curb, NC);

    // fused level-2 logit + scatter (level-1 softmax cancels vs F.normalize)
    k_edgescatter<<<(E + 255) / 256, 256, 0, stream>>>(
        cidx, curb, hidx, tidx, rel, pta, hb, er2b, e2gs, E);

    k_spmm2<<<(NC + 3) / 4, 256, 0, stream>>>(offb, cntb, e2gs,
                                              (const unsigned*)xrtn, xclass,
                                              ac, eh4b, hcls, zc, m3, NC);
    k_class2<<<(NC + 255) / 256, 256, 0, stream>>>(hcls, zc, m3, s3, NC);
    k_class3<<<(NC + 3) / 4, 256, 0, stream>>>(hcls, zc, s3, xclass, xeh, NC);

    k_mm_hw<<<(NE + 127) / 128, 256, 0, stream>>>(
        xrh_hi, hwt_hi, hwt_lo, out, hwb, xeh, NE);
}